// Round 5
// baseline (2697.870 us; speedup 1.0000x reference)
//
#include <hip/hip_runtime.h>
#include <math.h>

// FISTA data-consistency with masked multi-coil 2D FFT operator.
// B=4, C=16, H=W=384.
// Register FFT: 384 = 6 (regs) x 64 (lanes); DIF leaves bit-reversed-permuted
// frequencies; mask is pre-permuted; DIT consumes permuted order (free).
// Loop: iter-1 elementwise (y0=0); 19 rounds of p1/p2/p3; out fused in last p3.
// R3 lesson: do NOT fuse p3+p1 (VGPR 144 -> 11% occupancy, csm streamed 2x).
// R4 lessons: 64B tile chunks double FETCH (use 128B = 16 cols); precision
// margin 3.5x -> no fp16 anywhere, don't degrade twiddles further.

#define NN 384
#define BB 4
#define CC 16
#define NITER 20
#define LNPAD 432   // old LDS path (precompute only)

__device__ __forceinline__ int LID(int i) { return i + (i >> 3); }

__device__ __forceinline__ float2 cmulf(float2 a, float2 b) {
  return make_float2(a.x * b.x - a.y * b.y, a.x * b.y + a.y * b.x);
}

template<int DIR>
__device__ __forceinline__ void dft4(float2* v) {
  float ax = v[0].x + v[2].x, ay = v[0].y + v[2].y;
  float bx = v[0].x - v[2].x, by = v[0].y - v[2].y;
  float cx = v[1].x + v[3].x, cy = v[1].y + v[3].y;
  float dx = v[1].x - v[3].x, dy = v[1].y - v[3].y;
  float dix, diy;
  if (DIR < 0) { dix = dy; diy = -dx; }
  else         { dix = -dy; diy = dx; }
  v[0] = make_float2(ax + cx, ay + cy);
  v[2] = make_float2(ax - cx, ay - cy);
  v[1] = make_float2(bx + dix, by + diy);
  v[3] = make_float2(bx - dix, by - diy);
}

// DFT-3 with sign: X1 = m + i*s*S3*d, X2 = m - i*s*S3*d; m = a - u/2,
// u = b + c, d = b - c. Verified: delta inputs reproduce W3^k both signs.
template<int SIGN>
__device__ __forceinline__ void dft3(float2 a, float2 b, float2 c,
                                     float2& X0, float2& X1, float2& X2) {
  const float S3 = 0.86602540378443864676f;
  float ux = b.x + c.x, uy = b.y + c.y;
  float dx = b.x - c.x, dy = b.y - c.y;
  float mx = a.x - 0.5f * ux, my = a.y - 0.5f * uy;
  float ex = S3 * dx, ey = S3 * dy;
  X0 = make_float2(a.x + ux, a.y + uy);
  if (SIGN < 0) {
    X1 = make_float2(mx + ey, my - ex);
    X2 = make_float2(mx - ey, my + ex);
  } else {
    X1 = make_float2(mx - ey, my + ex);
    X2 = make_float2(mx + ey, my - ex);
  }
}

// Fast DFT-6 = radix-2 split into two DFT-3 (E on even, O on odd);
// X[k] = E[k] + W6^{sk} O[k], X[k+3] = E[k] - W6^{sk} O[k].
// W6^{s} = (0.5, s*S3), W6^{2s} = (-0.5, s*S3). Verified on impulses.
template<int SIGN>
__device__ __forceinline__ void dft6(float2* v) {
  const float S3 = 0.86602540378443864676f;
  float2 E0, E1, E2, O0, O1, O2;
  dft3<SIGN>(v[0], v[2], v[4], E0, E1, E2);
  dft3<SIGN>(v[1], v[3], v[5], O0, O1, O2);
  const float ss = (SIGN < 0) ? -S3 : S3;
  float2 T1 = cmulf(O1, make_float2(0.5f, ss));
  float2 T2 = cmulf(O2, make_float2(-0.5f, ss));
  v[0] = make_float2(E0.x + O0.x, E0.y + O0.y);
  v[1] = make_float2(E1.x + T1.x, E1.y + T1.y);
  v[2] = make_float2(E2.x + T2.x, E2.y + T2.y);
  v[3] = make_float2(E0.x - O0.x, E0.y - O0.y);
  v[4] = make_float2(E1.x - T1.x, E1.y - T1.y);
  v[5] = make_float2(E2.x - T2.x, E2.y - T2.y);
}

// ---------------- register FFT machinery (iteration path) ------------------

// radix-2 DIF FFT-64 across lanes; natural in -> bit-reversed out.
// Rolling twiddle: tw_h = exp(i*SIGN*pi*(t&(h-1))/h); tw_{h/2} = +-tw_h^2
// (sign = -1 iff t&(h/2)); only ONE __sincosf for the whole transform.
template<int SIGN>
__device__ __forceinline__ void dif64(float2 v[6], int t) {
  float ang = (float)SIGN * (3.14159265358979323846f / 32.0f) * (float)(t & 31);
  float2 tw; __sincosf(ang, &tw.y, &tw.x);
#pragma unroll
  for (int hs = 5; hs >= 0; --hs) {
    int h = 1 << hs;
    bool hi = (t & h) != 0;
    float cs = tw.x, sn = tw.y;
#pragma unroll
    for (int r = 0; r < 6; ++r) {
      float2 o;
      o.x = __shfl_xor(v[r].x, h);
      o.y = __shfl_xor(v[r].y, h);
      float dx = o.x - v[r].x, dy = o.y - v[r].y;
      float2 twv = make_float2(dx * cs - dy * sn, dx * sn + dy * cs);
      v[r] = hi ? twv : make_float2(v[r].x + o.x, v[r].y + o.y);
    }
    if (hs > 0) {
      float sqx = tw.x * tw.x - tw.y * tw.y;
      float sqy = 2.0f * tw.x * tw.y;
      bool neg = (t & (h >> 1)) != 0;
      tw.x = neg ? -sqx : sqx;
      tw.y = neg ? -sqy : sqy;
    }
  }
}

// radix-2 DIT FFT-64 across lanes; bit-reversed in -> natural out.
// Stages h=1 (tw=1) and h=2 (tw in {1, +-i}) need no sincos.
template<int SIGN>
__device__ __forceinline__ void dit64(float2 v[6], int t) {
#pragma unroll
  for (int hs = 0; hs < 6; ++hs) {
    int h = 1 << hs;
    float cs, sn;
    if (hs == 0) { cs = 1.0f; sn = 0.0f; }
    else if (hs == 1) {
      bool o = (t & 1) != 0;
      cs = o ? 0.0f : 1.0f;
      sn = o ? (float)SIGN : 0.0f;
    } else {
      float ang = (float)SIGN * 3.14159265358979323846f / (float)h * (float)(t & (h - 1));
      __sincosf(ang, &sn, &cs);
    }
    bool hi = (t & h) != 0;
#pragma unroll
    for (int r = 0; r < 6; ++r) {
      float2 bt = v[r];
      if (hi) bt = make_float2(v[r].x * cs - v[r].y * sn, v[r].x * sn + v[r].y * cs);
      float2 o;
      o.x = __shfl_xor(bt.x, h);
      o.y = __shfl_xor(bt.y, h);
      v[r] = hi ? make_float2(o.x - bt.x, o.y - bt.y)
                : make_float2(bt.x + o.x, bt.y + o.y);
    }
  }
}

// FWD: natural input (v[k]=x[t+64k]) -> permuted output (s=t+64r holds X[P(s)])
template<int SIGN>
__device__ __forceinline__ void fwd384(float2 v[6], int t) {
  dft6<SIGN>(v);
  float ang = (float)SIGN * 6.28318530717958647692f / 384.0f * (float)t;
  float sn, cs; __sincosf(ang, &sn, &cs);
  float2 w = make_float2(cs, sn), wr = w;
#pragma unroll
  for (int r = 1; r < 6; ++r) { v[r] = cmulf(v[r], wr); wr = cmulf(wr, w); }
  dif64<SIGN>(v, t);
}

// BWD: permuted input -> natural output; unnormalized inverse of fwd384.
template<int SIGN>
__device__ __forceinline__ void bwd384(float2 v[6], int t) {
  dit64<SIGN>(v, t);
  float ang = (float)SIGN * 6.28318530717958647692f / 384.0f * (float)t;
  float sn, cs; __sincosf(ang, &sn, &cs);
  float2 w = make_float2(cs, sn), wr = w;
#pragma unroll
  for (int r = 1; r < 6; ++r) { v[r] = cmulf(v[r], wr); wr = cmulf(wr, w); }
  dft6<SIGN>(v);
}

// ---------------- old LDS fft384 (precompute kernels only) -----------------
template<int R, int NS, int DIR>
__device__ __forceinline__ void fft_stage(const float2* S, float2* D, int t) {
  constexpr int NR = NN / R;
  constexpr float TWOPI = 6.28318530717958647692f;
#pragma unroll
  for (int rep = 0; rep < (NR + 63) / 64; ++rep) {
    int j = t + rep * 64;
    if (j < NR) {
      float2 v[R];
#pragma unroll
      for (int r = 0; r < R; ++r) v[r] = S[LID(j + r * NR)];
      if constexpr (NS > 1) {
        float ang = (float)DIR * (TWOPI / (float)(NS * R)) * (float)(j % NS);
        float sv, cv;
        __sincosf(ang, &sv, &cv);
        float2 w = make_float2(cv, sv);
        float2 wr = w;
#pragma unroll
        for (int r = 1; r < R; ++r) { v[r] = cmulf(v[r], wr); wr = cmulf(wr, w); }
      }
      if constexpr (R == 4) dft4<DIR>(v); else dft6<DIR>(v);
      int base = (j / NS) * (NS * R) + (j % NS);
#pragma unroll
      for (int r = 0; r < R; ++r) D[LID(base + r * NS)] = v[r];
    }
  }
}

template<int DIR>
__device__ __forceinline__ void fft384(float2* A, float2* Bf, int t) {
  fft_stage<4, 1,  DIR>(A,  Bf, t); __syncthreads();
  fft_stage<4, 4,  DIR>(Bf, A,  t); __syncthreads();
  fft_stage<4, 16, DIR>(A,  Bf, t); __syncthreads();
  fft_stage<6, 64, DIR>(Bf, A,  t); __syncthreads();
}

// ---------------- E: iteration 1 (y0 = 0 -> grad = -cst), elementwise ------
__global__ __launch_bounds__(256) void k_e(const float2* __restrict__ cstb,
                                           const float* __restrict__ zk,
                                           const float* __restrict__ lamp,
                                           float2* __restrict__ xbuf,
                                           float2* __restrict__ ybuf) {
  long i = (long)blockIdx.x * 256 + threadIdx.x;
  long b = i / (NN * NN);
  long p = i % (NN * NN);
  float lamv = lamp[0];
  float2 cs = cstb[i];
  float zr = zk[(b * 2 + 0) * (long)(NN * NN) + p];
  float zi = zk[(b * 2 + 1) * (long)(NN * NN) + p];
  float xr = cs.x - lamv * (cs.x - zr);
  float xi = cs.y - lamv * (cs.y - zi);
  xr = fmaxf(xr, 0.f);
  xi = fmaxf(xi, 0.f);
  float2 x = make_float2(xr, xi);
  xbuf[i] = x;
  ybuf[i] = x;   // t1 = 1 -> y1 = x1
}

// ---------------- P1: row FFT of coil*y -> W1 (permuted-x storage) ---------
// grid B*C*384/4, 256 thr; one wave per row; no LDS, no barriers.
__global__ __launch_bounds__(256) void k_p1(const float2* __restrict__ ybuf,
                                            const float* __restrict__ csm,
                                            float2* __restrict__ W1) {
  int t = threadIdx.x & 63;
  int w = threadIdx.x >> 6;
  long gl = (long)blockIdx.x * 4 + w;       // (b*C + c)*384 + y
  int y = (int)(gl % NN);
  long bc = gl / NN;
  long b = bc >> 4, c = bc & 15;
  long rowoff = (long)y * NN;
  const float2* yrow = ybuf + b * (long)(NN * NN) + rowoff;
  const float* crow_re = csm + (b * 2 * CC + c) * (long)(NN * NN) + rowoff;
  const float* crow_im = crow_re + (long)CC * NN * NN;
  float2 v[6];
#pragma unroll
  for (int k = 0; k < 6; ++k) {
    int x = t + 64 * k;
    float2 yv = yrow[x];
    float cre = crow_re[x], cim = crow_im[x];
    v[k] = make_float2(yv.x * cre - yv.y * cim, yv.x * cim + yv.y * cre);
  }
  fwd384<-1>(v, t);
  float2* orow = W1 + gl * NN;
#pragma unroll
  for (int r = 0; r < 6; ++r) orow[t + 64 * r] = v[r];
}

// ---------------- P2: col FFT -> mask -> col IFFT, in-place on W1 ----------
// grid B*C*(N/16), 256 thr. 16-column planar tile (49.3 KB LDS, pad 385):
// 128B global chunks (no line overfetch), stride-1 LDS column gather.
// Each wave owns 4 disjoint columns -> exactly 2 __syncthreads per block.
#define P2PAD 385
__global__ __launch_bounds__(256) void k_p2(float2* __restrict__ W1,
                                            const unsigned char* __restrict__ maskPT) {
  __shared__ float ldsR[16][P2PAD];
  __shared__ float ldsI[16][P2PAD];
  int tid = threadIdx.x;
  int xt = blockIdx.x % (NN / 16);
  long bc = blockIdx.x / (NN / 16);
  long b = bc >> 4;
  int s0 = xt * 16;
  long sbase = bc * (long)(NN * NN);
#pragma unroll
  for (int k = 0; k < 24; ++k) {
    int e = tid + k * 256; int y = e >> 4; int c = e & 15;
    float2 val = W1[sbase + (long)y * NN + s0 + c];
    ldsR[c][y] = val.x; ldsI[c][y] = val.y;
  }
  __syncthreads();
  int w = tid >> 6, t = tid & 63;
  const unsigned char* mb = maskPT + b * (long)(NN * NN);
#pragma unroll
  for (int i = 0; i < 4; ++i) {
    int c = w * 4 + i;
    float2 v[6];
#pragma unroll
    for (int k = 0; k < 6; ++k)
      v[k] = make_float2(ldsR[c][t + 64 * k], ldsI[c][t + 64 * k]);
    fwd384<-1>(v, t);
    const unsigned char* mcol = mb + (long)(s0 + c) * NN;
#pragma unroll
    for (int r = 0; r < 6; ++r) {
      float mv = (float)mcol[t + 64 * r];
      v[r].x *= mv; v[r].y *= mv;
    }
    bwd384<1>(v, t);
#pragma unroll
    for (int k = 0; k < 6; ++k) {
      ldsR[c][t + 64 * k] = v[k].x * (1.0f / NN);
      ldsI[c][t + 64 * k] = v[k].y * (1.0f / NN);
    }
  }
  __syncthreads();
#pragma unroll
  for (int k = 0; k < 24; ++k) {
    int e = tid + k * 256; int y = e >> 4; int c = e & 15;
    W1[sbase + (long)y * NN + s0 + c] = make_float2(ldsR[c][y], ldsI[c][y]);
  }
}

// ---------------- P3: row IFFT + conj(coil) reduce + FISTA update ----------
// grid B*384 blocks, 256 thr; wave w handles coils 4w..4w+3; LDS reduce.
// last!=0: write planar output instead of x/y (final iteration).
__global__ __launch_bounds__(256) void k_p3(const float2* __restrict__ W1,
                                            const float* __restrict__ csm,
                                            const float2* __restrict__ cstb,
                                            const float* __restrict__ zk,
                                            const float* __restrict__ lamp,
                                            float2* __restrict__ xbuf,
                                            float2* __restrict__ ybuf,
                                            float* __restrict__ outp,
                                            float beta, int last) {
  __shared__ float2 part[4][NN];
  int tid = threadIdx.x;
  int w = tid >> 6, t = tid & 63;
  long gl = blockIdx.x;            // b*384 + y
  long b = gl / NN;
  int y = (int)(gl % NN);
  long rowoff = (long)y * NN;
  float2 acc[6];
#pragma unroll
  for (int k = 0; k < 6; ++k) acc[k] = make_float2(0.f, 0.f);
#pragma unroll
  for (int ci = 0; ci < 4; ++ci) {
    int c = w * 4 + ci;
    const float2* row = W1 + ((b * CC + c) * (long)NN + y) * NN;
    float2 v[6];
#pragma unroll
    for (int r = 0; r < 6; ++r) v[r] = row[t + 64 * r];
    bwd384<1>(v, t);
    const float* cre = csm + (b * 2 * CC + c) * (long)(NN * NN) + rowoff;
    const float* cim = cre + (long)CC * NN * NN;
#pragma unroll
    for (int k = 0; k < 6; ++k) {
      int x = t + 64 * k;
      float a = cre[x], bb = cim[x];
      acc[k].x += (a * v[k].x + bb * v[k].y);
      acc[k].y += (a * v[k].y - bb * v[k].x);
    }
  }
#pragma unroll
  for (int k = 0; k < 6; ++k) part[w][t + 64 * k] = acc[k];
  __syncthreads();
  float lamv = lamp[0];
  long pbase = b * (long)(NN * NN) + rowoff;
  for (int e = tid; e < NN; e += 256) {
    float Qx = (part[0][e].x + part[1][e].x + part[2][e].x + part[3][e].x) * (1.0f / NN);
    float Qy = (part[0][e].y + part[1][e].y + part[2][e].y + part[3][e].y) * (1.0f / NN);
    float2 yv = ybuf[pbase + e];
    float2 cs = cstb[pbase + e];
    float zr = zk[(b * 2 + 0) * (long)(NN * NN) + rowoff + e];
    float zi = zk[(b * 2 + 1) * (long)(NN * NN) + rowoff + e];
    float xr = yv.x - (Qx - cs.x);
    float xi = yv.y - (Qy - cs.y);
    xr = xr - lamv * (xr - zr);
    xi = xi - lamv * (xi - zi);
    xr = fmaxf(xr, 0.f);
    xi = fmaxf(xi, 0.f);
    if (last) {
      outp[(b * 2 + 0) * (long)(NN * NN) + rowoff + e] = xr;
      outp[(b * 2 + 1) * (long)(NN * NN) + rowoff + e] = xi;
    } else {
      float2 xo = xbuf[pbase + e];
      xbuf[pbase + e] = make_float2(xr, xi);
      ybuf[pbase + e] = make_float2(xr + beta * (xr - xo.x), xi + beta * (xi - xo.y));
    }
  }
}

// ---------------- mask permutation precompute (one-time) -------------------
// maskPT[b][sx][sy] = mask[b][P(sy)][P(sx)], P(s) = (s>>6) + 6*brev6(s&63)
__global__ __launch_bounds__(256) void k_mpre(const int* __restrict__ mask,
                                              unsigned char* __restrict__ maskPT) {
  long i = (long)blockIdx.x * 256 + threadIdx.x;
  long b = i / (NN * NN);
  int rem = (int)(i % (NN * NN));
  int sx = rem / NN, sy = rem % NN;
  int fx = (sx >> 6) + 6 * (int)(__brev((unsigned)(sx & 63)) >> 26);
  int fy = (sy >> 6) + 6 * (int)(__brev((unsigned)(sy & 63)) >> 26);
  maskPT[i] = (unsigned char)mask[b * (long)(NN * NN) + (long)fy * NN + fx];
}

// ---------------- precompute: cst = (sum_c conj(coil)) * IFFT2(m*b) --------
__global__ __launch_bounds__(256) void k_preA(const float* __restrict__ x0,
                                              const int* __restrict__ mask,
                                              float2* __restrict__ T) {
  __shared__ float2 U[4][LNPAD], V[4][LNPAD];
  int tid = threadIdx.x;
  int line = tid >> 6, t = tid & 63;
  long gl0 = (long)blockIdx.x * 4;
#pragma unroll
  for (int k = 0; k < 6; ++k) {
    int e = tid + k * 256; int l = e / NN; int x = e % NN;
    long gl = gl0 + l;
    long b = gl / NN;
    int y = (int)(gl % NN);
    long pidx = (long)y * NN + x;
    float mv = (float)mask[b * (long)(NN * NN) + pidx];
    float br = x0[(b * 2 + 0) * (long)(NN * NN) + pidx] * mv;
    float bi = x0[(b * 2 + 1) * (long)(NN * NN) + pidx] * mv;
    U[l][LID(x)] = make_float2(br, bi);
  }
  __syncthreads();
  fft384<1>(U[line], V[line], t);
#pragma unroll
  for (int k = 0; k < 6; ++k) {
    int e = tid + k * 256; int l = e / NN; int x = e % NN;
    float2 u = U[l][LID(x)];
    T[(gl0 + l) * NN + x] = make_float2(u.x * (1.0f / NN), u.y * (1.0f / NN));
  }
}

__global__ __launch_bounds__(256) void k_preB(const float2* __restrict__ T,
                                              float2* __restrict__ r0) {
  __shared__ float2 tile[NN][17];
  __shared__ float2 U[4][LNPAD], V[4][LNPAD];
  int tid = threadIdx.x;
  int xt = blockIdx.x % (NN / 16);
  long b = blockIdx.x / (NN / 16);
  int x0c = xt * 16;
  long sbase = b * (long)(NN * NN);
#pragma unroll
  for (int k = 0; k < 24; ++k) {
    int e = tid + k * 256; int y = e >> 4; int c = e & 15;
    tile[y][c] = T[sbase + (long)y * NN + x0c + c];
  }
  __syncthreads();
  int line = tid >> 6, t = tid & 63;
  for (int g = 0; g < 4; ++g) {
#pragma unroll
    for (int k = 0; k < 6; ++k) {
      int e = tid + k * 256; int l = e / NN; int y = e % NN;
      U[l][LID(y)] = tile[y][4 * g + l];
    }
    __syncthreads();
    fft384<1>(U[line], V[line], t);
#pragma unroll
    for (int k = 0; k < 6; ++k) {
      int e = tid + k * 256; int l = e / NN; int y = e % NN;
      float2 u = U[l][LID(y)];
      tile[y][4 * g + l] = make_float2(u.x * (1.0f / NN), u.y * (1.0f / NN));
    }
    __syncthreads();
  }
#pragma unroll
  for (int k = 0; k < 24; ++k) {
    int e = tid + k * 256; int y = e >> 4; int c = e & 15;
    r0[sbase + (long)y * NN + x0c + c] = tile[y][c];
  }
}

__global__ __launch_bounds__(256) void k_preC(const float* __restrict__ csm,
                                              const float2* __restrict__ r0,
                                              float2* __restrict__ cstb) {
  long i = (long)blockIdx.x * 256 + threadIdx.x;
  long b = i / (NN * NN);
  long p = i % (NN * NN);
  float sr = 0.f, si = 0.f;
#pragma unroll
  for (int c = 0; c < CC; ++c) {
    sr += csm[(b * 2 * CC + c) * (long)(NN * NN) + p];
    si -= csm[((b * 2 + 1) * CC + c) * (long)(NN * NN) + p];
  }
  float2 r = r0[i];
  cstb[i] = make_float2(sr * r.x - si * r.y, sr * r.y + si * r.x);
}

extern "C" void kernel_launch(void* const* d_in, const int* in_sizes, int n_in,
                              void* d_out, int out_size, void* d_ws, size_t ws_size,
                              hipStream_t stream) {
  const float* zk  = (const float*)d_in[0];
  const float* x0  = (const float*)d_in[1];
  const float* csm = (const float*)d_in[2];
  const float* lam = (const float*)d_in[3];
  const int*   msk = (const int*)d_in[4];
  float* out = (float*)d_out;

  // ws layout (float2 units): W1 [B*C*N*N] | y | x | cst | maskPT(uchar)
  size_t img = (size_t)BB * NN * NN;
  float2* W1   = (float2*)d_ws;
  float2* ybuf = W1 + (size_t)BB * CC * NN * NN;
  float2* xbuf = ybuf + img;
  float2* cstb = xbuf + img;
  unsigned char* maskPT = (unsigned char*)(cstb + img);
  float2* T  = W1;        // precompute scratch overlays W1
  float2* r0 = W1 + img;

  double tcur = 1.0;
  float betas[NITER];
  for (int i = 0; i < NITER; ++i) {
    double tn = (1.0 + sqrt(1.0 + 4.0 * tcur * tcur)) * 0.5;
    betas[i] = (float)((tcur - 1.0) / tn);
    tcur = tn;
  }

  k_mpre<<<(BB * NN * NN) / 256, 256, 0, stream>>>(msk, maskPT);
  k_preA<<<BB * NN / 4, 256, 0, stream>>>(x0, msk, T);
  k_preB<<<BB * (NN / 16), 256, 0, stream>>>(T, r0);
  k_preC<<<(BB * NN * NN) / 256, 256, 0, stream>>>(csm, r0, cstb);
  // iteration 1 (y0 = 0): pure elementwise
  k_e<<<(BB * NN * NN) / 256, 256, 0, stream>>>(cstb, zk, lam, xbuf, ybuf);
  // iterations 2..20: forward, mask round-trip, adjoint+update
  for (int i = 1; i < NITER; ++i) {
    k_p1<<<BB * CC * NN / 4, 256, 0, stream>>>(ybuf, csm, W1);
    k_p2<<<BB * CC * (NN / 16), 256, 0, stream>>>(W1, maskPT);
    k_p3<<<BB * NN, 256, 0, stream>>>(W1, csm, cstb, zk, lam, xbuf, ybuf, out,
                                      betas[i], (i == NITER - 1) ? 1 : 0);
  }
}

// Round 6
// 2498.416 us; speedup vs baseline: 1.0798x; 1.0798x over previous
//
#include <hip/hip_runtime.h>
#include <math.h>

// FISTA data-consistency with masked multi-coil 2D FFT operator.
// B=4, C=16, H=W=384.
// Register FFT: 384 = 6 (regs) x 64 (lanes); DIF leaves bit-reversed-permuted
// frequencies; mask is pre-permuted; DIT consumes permuted order (free).
// Twiddles: all lane-stage twiddles are 64th roots of unity -> 32-entry
// register table (1 sincosf/kernel) pulled via __shfl; outer W384^rt chain
// hoisted to per-kernel registers. Exact-rounded -> best precision.
// Loop: iter-1 elementwise (y0=0); 19 rounds of p1/p2/p3; out fused in last p3.
// R3: don't fuse p3+p1 (VGPR 144 -> 11% occ). R4: 64B chunks overfetch 2x
// ACROSS XCDs -> fixed by XCD-chunked swizzle, keep 8-col tile for occupancy.

#define NN 384
#define BB 4
#define CC 16
#define NITER 20
#define LNPAD 432   // old LDS path (precompute only)
#define PI_F 3.14159265358979323846f
#define TWOPI_F 6.28318530717958647692f

__device__ __forceinline__ int LID(int i) { return i + (i >> 3); }

__device__ __forceinline__ float2 cmulf(float2 a, float2 b) {
  return make_float2(a.x * b.x - a.y * b.y, a.x * b.y + a.y * b.x);
}

template<int DIR>
__device__ __forceinline__ void dft4(float2* v) {
  float ax = v[0].x + v[2].x, ay = v[0].y + v[2].y;
  float bx = v[0].x - v[2].x, by = v[0].y - v[2].y;
  float cx = v[1].x + v[3].x, cy = v[1].y + v[3].y;
  float dx = v[1].x - v[3].x, dy = v[1].y - v[3].y;
  float dix, diy;
  if (DIR < 0) { dix = dy; diy = -dx; }
  else         { dix = -dy; diy = dx; }
  v[0] = make_float2(ax + cx, ay + cy);
  v[2] = make_float2(ax - cx, ay - cy);
  v[1] = make_float2(bx + dix, by + diy);
  v[3] = make_float2(bx - dix, by - diy);
}

// DFT-3: X1 = m + i*s*S3*d, X2 = m - i*s*S3*d; m = a - u/2, u=b+c, d=b-c.
template<int SIGN>
__device__ __forceinline__ void dft3(float2 a, float2 b, float2 c,
                                     float2& X0, float2& X1, float2& X2) {
  const float S3 = 0.86602540378443864676f;
  float ux = b.x + c.x, uy = b.y + c.y;
  float dx = b.x - c.x, dy = b.y - c.y;
  float mx = a.x - 0.5f * ux, my = a.y - 0.5f * uy;
  float ex = S3 * dx, ey = S3 * dy;
  X0 = make_float2(a.x + ux, a.y + uy);
  if (SIGN < 0) {
    X1 = make_float2(mx + ey, my - ex);
    X2 = make_float2(mx - ey, my + ex);
  } else {
    X1 = make_float2(mx - ey, my + ex);
    X2 = make_float2(mx + ey, my - ex);
  }
}

// Fast DFT-6 = two DFT-3 + trivial W6 twiddles. Verified on impulses.
template<int SIGN>
__device__ __forceinline__ void dft6(float2* v) {
  const float S3 = 0.86602540378443864676f;
  float2 E0, E1, E2, O0, O1, O2;
  dft3<SIGN>(v[0], v[2], v[4], E0, E1, E2);
  dft3<SIGN>(v[1], v[3], v[5], O0, O1, O2);
  const float ss = (SIGN < 0) ? -S3 : S3;
  float2 T1 = cmulf(O1, make_float2(0.5f, ss));
  float2 T2 = cmulf(O2, make_float2(-0.5f, ss));
  v[0] = make_float2(E0.x + O0.x, E0.y + O0.y);
  v[1] = make_float2(E1.x + T1.x, E1.y + T1.y);
  v[2] = make_float2(E2.x + T2.x, E2.y + T2.y);
  v[3] = make_float2(E0.x - O0.x, E0.y - O0.y);
  v[4] = make_float2(E1.x - T1.x, E1.y - T1.y);
  v[5] = make_float2(E2.x - T2.x, E2.y - T2.y);
}

// ---------------- register FFT machinery (iteration path) ------------------
// Stage twiddle for (hs, t): exp(SIGN*i*pi*(t&(h-1))/h) = exp(SIGN*i*pi*j/32),
// j = (t&(h-1)) << (5-hs). Lane j holds (tc,ts) = (cos,sin)(pi*j/32).

// radix-2 DIF FFT-64 across lanes; natural in -> bit-reversed out.
template<int SIGN>
__device__ __forceinline__ void dif64t(float2 v[6], int t, float tc, float ts) {
#pragma unroll
  for (int hs = 5; hs >= 0; --hs) {
    int h = 1 << hs;
    int j = (t & (h - 1)) << (5 - hs);
    float cs = __shfl(tc, j);
    float sn = __shfl(ts, j);
    sn = (SIGN < 0) ? -sn : sn;
    bool hi = (t & h) != 0;
#pragma unroll
    for (int r = 0; r < 6; ++r) {
      float2 o;
      o.x = __shfl_xor(v[r].x, h);
      o.y = __shfl_xor(v[r].y, h);
      float dx = o.x - v[r].x, dy = o.y - v[r].y;
      float2 twv = make_float2(dx * cs - dy * sn, dx * sn + dy * cs);
      v[r] = hi ? twv : make_float2(v[r].x + o.x, v[r].y + o.y);
    }
  }
}

// radix-2 DIT FFT-64 across lanes; bit-reversed in -> natural out.
template<int SIGN>
__device__ __forceinline__ void dit64t(float2 v[6], int t, float tc, float ts) {
#pragma unroll
  for (int hs = 0; hs < 6; ++hs) {
    int h = 1 << hs;
    int j = (t & (h - 1)) << (5 - hs);
    float cs = __shfl(tc, j);
    float sn = __shfl(ts, j);
    sn = (SIGN < 0) ? -sn : sn;
    bool hi = (t & h) != 0;
#pragma unroll
    for (int r = 0; r < 6; ++r) {
      float2 bt = v[r];
      if (hi) bt = make_float2(v[r].x * cs - v[r].y * sn, v[r].x * sn + v[r].y * cs);
      float2 o;
      o.x = __shfl_xor(bt.x, h);
      o.y = __shfl_xor(bt.y, h);
      v[r] = hi ? make_float2(o.x - bt.x, o.y - bt.y)
                : make_float2(bt.x + o.x, bt.y + o.y);
    }
  }
}

// FWD: natural in -> permuted out. w[r-1] = exp(SIGN*2pi*i*r*t/384).
template<int SIGN>
__device__ __forceinline__ void fwd384t(float2 v[6], int t, float tc, float ts,
                                        const float2 w[5]) {
  dft6<SIGN>(v);
#pragma unroll
  for (int r = 1; r < 6; ++r) v[r] = cmulf(v[r], w[r - 1]);
  dif64t<SIGN>(v, t, tc, ts);
}

// BWD: permuted in -> natural out; unnormalized inverse of fwd384t.
template<int SIGN>
__device__ __forceinline__ void bwd384t(float2 v[6], int t, float tc, float ts,
                                        const float2 w[5]) {
  dit64t<SIGN>(v, t, tc, ts);
#pragma unroll
  for (int r = 1; r < 6; ++r) v[r] = cmulf(v[r], w[r - 1]);
  dft6<SIGN>(v);
}

// ---------------- old LDS fft384 (precompute kernels only) -----------------
template<int R, int NS, int DIR>
__device__ __forceinline__ void fft_stage(const float2* S, float2* D, int t) {
  constexpr int NR = NN / R;
#pragma unroll
  for (int rep = 0; rep < (NR + 63) / 64; ++rep) {
    int j = t + rep * 64;
    if (j < NR) {
      float2 v[R];
#pragma unroll
      for (int r = 0; r < R; ++r) v[r] = S[LID(j + r * NR)];
      if constexpr (NS > 1) {
        float ang = (float)DIR * (TWOPI_F / (float)(NS * R)) * (float)(j % NS);
        float sv, cv;
        __sincosf(ang, &sv, &cv);
        float2 w = make_float2(cv, sv);
        float2 wr = w;
#pragma unroll
        for (int r = 1; r < R; ++r) { v[r] = cmulf(v[r], wr); wr = cmulf(wr, w); }
      }
      if constexpr (R == 4) dft4<DIR>(v); else dft6<DIR>(v);
      int base = (j / NS) * (NS * R) + (j % NS);
#pragma unroll
      for (int r = 0; r < R; ++r) D[LID(base + r * NS)] = v[r];
    }
  }
}

template<int DIR>
__device__ __forceinline__ void fft384(float2* A, float2* Bf, int t) {
  fft_stage<4, 1,  DIR>(A,  Bf, t); __syncthreads();
  fft_stage<4, 4,  DIR>(Bf, A,  t); __syncthreads();
  fft_stage<4, 16, DIR>(A,  Bf, t); __syncthreads();
  fft_stage<6, 64, DIR>(Bf, A,  t); __syncthreads();
}

// ---------------- E: iteration 1 (y0 = 0 -> grad = -cst), elementwise ------
__global__ __launch_bounds__(256) void k_e(const float2* __restrict__ cstb,
                                           const float* __restrict__ zk,
                                           const float* __restrict__ lamp,
                                           float2* __restrict__ xbuf,
                                           float2* __restrict__ ybuf) {
  long i = (long)blockIdx.x * 256 + threadIdx.x;
  long b = i / (NN * NN);
  long p = i % (NN * NN);
  float lamv = lamp[0];
  float2 cs = cstb[i];
  float zr = zk[(b * 2 + 0) * (long)(NN * NN) + p];
  float zi = zk[(b * 2 + 1) * (long)(NN * NN) + p];
  float xr = cs.x - lamv * (cs.x - zr);
  float xi = cs.y - lamv * (cs.y - zi);
  xr = fmaxf(xr, 0.f);
  xi = fmaxf(xi, 0.f);
  float2 x = make_float2(xr, xi);
  xbuf[i] = x;
  ybuf[i] = x;   // t1 = 1 -> y1 = x1
}

// ---------------- P1: row FFT of coil*y -> W1 (permuted-x storage) ---------
// grid B*C*384/4, 256 thr; one wave per row; no LDS, no barriers.
__global__ __launch_bounds__(256) void k_p1(const float2* __restrict__ ybuf,
                                            const float* __restrict__ csm,
                                            float2* __restrict__ W1) {
  int t = threadIdx.x & 63;
  int w = threadIdx.x >> 6;
  long gl = (long)blockIdx.x * 4 + w;       // (b*C + c)*384 + y
  int y = (int)(gl % NN);
  long bc = gl / NN;
  long b = bc >> 4, c = bc & 15;
  long rowoff = (long)y * NN;
  // twiddle setup (per kernel)
  float tc, ts; __sincosf((float)(t & 31) * (PI_F / 32.0f), &ts, &tc);
  float2 w0; __sincosf(-(float)t * (TWOPI_F / 384.0f), &w0.y, &w0.x);
  float2 wf[5];
  wf[0] = w0;
#pragma unroll
  for (int r = 1; r < 5; ++r) wf[r] = cmulf(wf[r - 1], w0);
  const float2* yrow = ybuf + b * (long)(NN * NN) + rowoff;
  const float* crow_re = csm + (b * 2 * CC + c) * (long)(NN * NN) + rowoff;
  const float* crow_im = crow_re + (long)CC * NN * NN;
  float2 v[6];
#pragma unroll
  for (int k = 0; k < 6; ++k) {
    int x = t + 64 * k;
    float2 yv = yrow[x];
    float cre = crow_re[x], cim = crow_im[x];
    v[k] = make_float2(yv.x * cre - yv.y * cim, yv.x * cim + yv.y * cre);
  }
  fwd384t<-1>(v, t, tc, ts, wf);
  float2* orow = W1 + gl * NN;
#pragma unroll
  for (int r = 0; r < 6; ++r) orow[t + 64 * r] = v[r];
}

// ---------------- P2: col FFT -> mask -> col IFFT, in-place on W1 ----------
// grid B*C*(N/8)=3072 blocks, 256 thr. 8-col planar tile, pad 392 (=8 mod 32:
// fill/drain exactly 2-way = free). XCD-chunked swizzle keeps a slice's
// xt-range on one XCD so split 64B chunks hit that XCD's L2 (no 2x fetch).
#define P2PAD 392
__global__ __launch_bounds__(256) void k_p2(float2* __restrict__ W1,
                                            const unsigned char* __restrict__ maskPT) {
  __shared__ float ldsR[8][P2PAD];
  __shared__ float ldsI[8][P2PAD];
  int tid = threadIdx.x;
  const int nwg = BB * CC * (NN / 8);            // 3072, divisible by 8
  int l = ((int)blockIdx.x & 7) * (nwg >> 3) + ((int)blockIdx.x >> 3);
  int xt = l % (NN / 8);
  long bc = l / (NN / 8);
  long b = bc >> 4;
  int s0 = xt * 8;
  long sbase = bc * (long)(NN * NN);
  int w = tid >> 6, t = tid & 63;
  // twiddle setup (per kernel): table + outer chains both directions
  float tc, ts; __sincosf((float)(t & 31) * (PI_F / 32.0f), &ts, &tc);
  float2 w0; __sincosf(-(float)t * (TWOPI_F / 384.0f), &w0.y, &w0.x);
  float2 wf[5], wb[5];
  wf[0] = w0;
#pragma unroll
  for (int r = 1; r < 5; ++r) wf[r] = cmulf(wf[r - 1], w0);
#pragma unroll
  for (int r = 0; r < 5; ++r) wb[r] = make_float2(wf[r].x, -wf[r].y);
#pragma unroll
  for (int k = 0; k < 12; ++k) {
    int e = tid + k * 256; int y = e >> 3; int c = e & 7;
    float2 val = W1[sbase + (long)y * NN + s0 + c];
    ldsR[c][y] = val.x; ldsI[c][y] = val.y;
  }
  __syncthreads();
  const unsigned char* mb = maskPT + b * (long)(NN * NN);
#pragma unroll
  for (int i = 0; i < 2; ++i) {
    int c = w * 2 + i;
    float2 v[6];
#pragma unroll
    for (int k = 0; k < 6; ++k)
      v[k] = make_float2(ldsR[c][t + 64 * k], ldsI[c][t + 64 * k]);
    fwd384t<-1>(v, t, tc, ts, wf);
    const unsigned char* mcol = mb + (long)(s0 + c) * NN;
#pragma unroll
    for (int r = 0; r < 6; ++r) {
      float mv = (float)mcol[t + 64 * r];
      v[r].x *= mv; v[r].y *= mv;
    }
    bwd384t<1>(v, t, tc, ts, wb);
#pragma unroll
    for (int k = 0; k < 6; ++k) {
      ldsR[c][t + 64 * k] = v[k].x * (1.0f / NN);
      ldsI[c][t + 64 * k] = v[k].y * (1.0f / NN);
    }
  }
  __syncthreads();
#pragma unroll
  for (int k = 0; k < 12; ++k) {
    int e = tid + k * 256; int y = e >> 3; int c = e & 7;
    W1[sbase + (long)y * NN + s0 + c] = make_float2(ldsR[c][y], ldsI[c][y]);
  }
}

// ---------------- P3: row IFFT + conj(coil) reduce + FISTA update ----------
// grid B*384 blocks, 256 thr; wave w handles coils 4w..4w+3; LDS reduce.
// last!=0: write planar output instead of x/y (final iteration).
__global__ __launch_bounds__(256) void k_p3(const float2* __restrict__ W1,
                                            const float* __restrict__ csm,
                                            const float2* __restrict__ cstb,
                                            const float* __restrict__ zk,
                                            const float* __restrict__ lamp,
                                            float2* __restrict__ xbuf,
                                            float2* __restrict__ ybuf,
                                            float* __restrict__ outp,
                                            float beta, int last) {
  __shared__ float2 part[4][NN];
  int tid = threadIdx.x;
  int w = tid >> 6, t = tid & 63;
  long gl = blockIdx.x;            // b*384 + y
  long b = gl / NN;
  int y = (int)(gl % NN);
  long rowoff = (long)y * NN;
  // twiddle setup (per kernel): inverse direction only
  float tc, ts; __sincosf((float)(t & 31) * (PI_F / 32.0f), &ts, &tc);
  float2 w0; __sincosf((float)t * (TWOPI_F / 384.0f), &w0.y, &w0.x);
  float2 wb[5];
  wb[0] = w0;
#pragma unroll
  for (int r = 1; r < 5; ++r) wb[r] = cmulf(wb[r - 1], w0);
  float2 acc[6];
#pragma unroll
  for (int k = 0; k < 6; ++k) acc[k] = make_float2(0.f, 0.f);
#pragma unroll
  for (int ci = 0; ci < 4; ++ci) {
    int c = w * 4 + ci;
    const float2* row = W1 + ((b * CC + c) * (long)NN + y) * NN;
    float2 v[6];
#pragma unroll
    for (int r = 0; r < 6; ++r) v[r] = row[t + 64 * r];
    bwd384t<1>(v, t, tc, ts, wb);
    const float* cre = csm + (b * 2 * CC + c) * (long)(NN * NN) + rowoff;
    const float* cim = cre + (long)CC * NN * NN;
#pragma unroll
    for (int k = 0; k < 6; ++k) {
      int x = t + 64 * k;
      float a = cre[x], bb = cim[x];
      acc[k].x += (a * v[k].x + bb * v[k].y);
      acc[k].y += (a * v[k].y - bb * v[k].x);
    }
  }
#pragma unroll
  for (int k = 0; k < 6; ++k) part[w][t + 64 * k] = acc[k];
  __syncthreads();
  float lamv = lamp[0];
  long pbase = b * (long)(NN * NN) + rowoff;
  for (int e = tid; e < NN; e += 256) {
    float Qx = (part[0][e].x + part[1][e].x + part[2][e].x + part[3][e].x) * (1.0f / NN);
    float Qy = (part[0][e].y + part[1][e].y + part[2][e].y + part[3][e].y) * (1.0f / NN);
    float2 yv = ybuf[pbase + e];
    float2 cs = cstb[pbase + e];
    float zr = zk[(b * 2 + 0) * (long)(NN * NN) + rowoff + e];
    float zi = zk[(b * 2 + 1) * (long)(NN * NN) + rowoff + e];
    float xr = yv.x - (Qx - cs.x);
    float xi = yv.y - (Qy - cs.y);
    xr = xr - lamv * (xr - zr);
    xi = xi - lamv * (xi - zi);
    xr = fmaxf(xr, 0.f);
    xi = fmaxf(xi, 0.f);
    if (last) {
      outp[(b * 2 + 0) * (long)(NN * NN) + rowoff + e] = xr;
      outp[(b * 2 + 1) * (long)(NN * NN) + rowoff + e] = xi;
    } else {
      float2 xo = xbuf[pbase + e];
      xbuf[pbase + e] = make_float2(xr, xi);
      ybuf[pbase + e] = make_float2(xr + beta * (xr - xo.x), xi + beta * (xi - xo.y));
    }
  }
}

// ---------------- mask permutation precompute (one-time) -------------------
// maskPT[b][sx][sy] = mask[b][P(sy)][P(sx)], P(s) = (s>>6) + 6*brev6(s&63)
__global__ __launch_bounds__(256) void k_mpre(const int* __restrict__ mask,
                                              unsigned char* __restrict__ maskPT) {
  long i = (long)blockIdx.x * 256 + threadIdx.x;
  long b = i / (NN * NN);
  int rem = (int)(i % (NN * NN));
  int sx = rem / NN, sy = rem % NN;
  int fx = (sx >> 6) + 6 * (int)(__brev((unsigned)(sx & 63)) >> 26);
  int fy = (sy >> 6) + 6 * (int)(__brev((unsigned)(sy & 63)) >> 26);
  maskPT[i] = (unsigned char)mask[b * (long)(NN * NN) + (long)fy * NN + fx];
}

// ---------------- precompute: cst = (sum_c conj(coil)) * IFFT2(m*b) --------
__global__ __launch_bounds__(256) void k_preA(const float* __restrict__ x0,
                                              const int* __restrict__ mask,
                                              float2* __restrict__ T) {
  __shared__ float2 U[4][LNPAD], V[4][LNPAD];
  int tid = threadIdx.x;
  int line = tid >> 6, t = tid & 63;
  long gl0 = (long)blockIdx.x * 4;
#pragma unroll
  for (int k = 0; k < 6; ++k) {
    int e = tid + k * 256; int l = e / NN; int x = e % NN;
    long gl = gl0 + l;
    long b = gl / NN;
    int y = (int)(gl % NN);
    long pidx = (long)y * NN + x;
    float mv = (float)mask[b * (long)(NN * NN) + pidx];
    float br = x0[(b * 2 + 0) * (long)(NN * NN) + pidx] * mv;
    float bi = x0[(b * 2 + 1) * (long)(NN * NN) + pidx] * mv;
    U[l][LID(x)] = make_float2(br, bi);
  }
  __syncthreads();
  fft384<1>(U[line], V[line], t);
#pragma unroll
  for (int k = 0; k < 6; ++k) {
    int e = tid + k * 256; int l = e / NN; int x = e % NN;
    float2 u = U[l][LID(x)];
    T[(gl0 + l) * NN + x] = make_float2(u.x * (1.0f / NN), u.y * (1.0f / NN));
  }
}

__global__ __launch_bounds__(256) void k_preB(const float2* __restrict__ T,
                                              float2* __restrict__ r0) {
  __shared__ float2 tile[NN][17];
  __shared__ float2 U[4][LNPAD], V[4][LNPAD];
  int tid = threadIdx.x;
  int xt = blockIdx.x % (NN / 16);
  long b = blockIdx.x / (NN / 16);
  int x0c = xt * 16;
  long sbase = b * (long)(NN * NN);
#pragma unroll
  for (int k = 0; k < 24; ++k) {
    int e = tid + k * 256; int y = e >> 4; int c = e & 15;
    tile[y][c] = T[sbase + (long)y * NN + x0c + c];
  }
  __syncthreads();
  int line = tid >> 6, t = tid & 63;
  for (int g = 0; g < 4; ++g) {
#pragma unroll
    for (int k = 0; k < 6; ++k) {
      int e = tid + k * 256; int l = e / NN; int y = e % NN;
      U[l][LID(y)] = tile[y][4 * g + l];
    }
    __syncthreads();
    fft384<1>(U[line], V[line], t);
#pragma unroll
    for (int k = 0; k < 6; ++k) {
      int e = tid + k * 256; int l = e / NN; int y = e % NN;
      float2 u = U[l][LID(y)];
      tile[y][4 * g + l] = make_float2(u.x * (1.0f / NN), u.y * (1.0f / NN));
    }
    __syncthreads();
  }
#pragma unroll
  for (int k = 0; k < 24; ++k) {
    int e = tid + k * 256; int y = e >> 4; int c = e & 15;
    r0[sbase + (long)y * NN + x0c + c] = tile[y][c];
  }
}

__global__ __launch_bounds__(256) void k_preC(const float* __restrict__ csm,
                                              const float2* __restrict__ r0,
                                              float2* __restrict__ cstb) {
  long i = (long)blockIdx.x * 256 + threadIdx.x;
  long b = i / (NN * NN);
  long p = i % (NN * NN);
  float sr = 0.f, si = 0.f;
#pragma unroll
  for (int c = 0; c < CC; ++c) {
    sr += csm[(b * 2 * CC + c) * (long)(NN * NN) + p];
    si -= csm[((b * 2 + 1) * CC + c) * (long)(NN * NN) + p];
  }
  float2 r = r0[i];
  cstb[i] = make_float2(sr * r.x - si * r.y, sr * r.y + si * r.x);
}

extern "C" void kernel_launch(void* const* d_in, const int* in_sizes, int n_in,
                              void* d_out, int out_size, void* d_ws, size_t ws_size,
                              hipStream_t stream) {
  const float* zk  = (const float*)d_in[0];
  const float* x0  = (const float*)d_in[1];
  const float* csm = (const float*)d_in[2];
  const float* lam = (const float*)d_in[3];
  const int*   msk = (const int*)d_in[4];
  float* out = (float*)d_out;

  // ws layout (float2 units): W1 [B*C*N*N] | y | x | cst | maskPT(uchar)
  size_t img = (size_t)BB * NN * NN;
  float2* W1   = (float2*)d_ws;
  float2* ybuf = W1 + (size_t)BB * CC * NN * NN;
  float2* xbuf = ybuf + img;
  float2* cstb = xbuf + img;
  unsigned char* maskPT = (unsigned char*)(cstb + img);
  float2* T  = W1;        // precompute scratch overlays W1
  float2* r0 = W1 + img;

  double tcur = 1.0;
  float betas[NITER];
  for (int i = 0; i < NITER; ++i) {
    double tn = (1.0 + sqrt(1.0 + 4.0 * tcur * tcur)) * 0.5;
    betas[i] = (float)((tcur - 1.0) / tn);
    tcur = tn;
  }

  k_mpre<<<(BB * NN * NN) / 256, 256, 0, stream>>>(msk, maskPT);
  k_preA<<<BB * NN / 4, 256, 0, stream>>>(x0, msk, T);
  k_preB<<<BB * (NN / 16), 256, 0, stream>>>(T, r0);
  k_preC<<<(BB * NN * NN) / 256, 256, 0, stream>>>(csm, r0, cstb);
  // iteration 1 (y0 = 0): pure elementwise
  k_e<<<(BB * NN * NN) / 256, 256, 0, stream>>>(cstb, zk, lam, xbuf, ybuf);
  // iterations 2..20: forward, mask round-trip, adjoint+update
  for (int i = 1; i < NITER; ++i) {
    k_p1<<<BB * CC * NN / 4, 256, 0, stream>>>(ybuf, csm, W1);
    k_p2<<<BB * CC * (NN / 8), 256, 0, stream>>>(W1, maskPT);
    k_p3<<<BB * NN, 256, 0, stream>>>(W1, csm, cstb, zk, lam, xbuf, ybuf, out,
                                      betas[i], (i == NITER - 1) ? 1 : 0);
  }
}

// Round 7
// 2476.644 us; speedup vs baseline: 1.0893x; 1.0088x over previous
//
#include <hip/hip_runtime.h>
#include <math.h>

// FISTA data-consistency with masked multi-coil 2D FFT operator.
// B=4, C=16, H=W=384.
// Register FFT: 384 = 6 (regs) x 64 (lanes); DIF leaves bit-reversed-permuted
// frequencies; mask is pre-permuted; DIT consumes permuted order (free).
// Twiddles: 32-entry register table (1 sincosf/kernel) pulled via __shfl;
// trivial stages (h=1,2; tw in {1,+-i}) skip the fetch entirely.
// ILP: p2 runs 2 columns per wave THROUGH THE SAME FFT BODY (u,v interleaved)
// to break the shuffle->butterfly dependency chain; p3 interleaves 2 coils.
// Loop: iter-1 elementwise (y0=0); 19 rounds of p1/p2/p3; out fused in last p3.
// R3: don't fuse p3+p1. R4: 64B chunks overfetch 2x across XCDs -> XCD-chunked
// swizzle + 8-col tile. R6: occupancy 35%, VALU 64% -> latency-bound chains.

#define NN 384
#define BB 4
#define CC 16
#define NITER 20
#define LNPAD 432   // old LDS path (precompute only)
#define PI_F 3.14159265358979323846f
#define TWOPI_F 6.28318530717958647692f

__device__ __forceinline__ int LID(int i) { return i + (i >> 3); }

__device__ __forceinline__ float2 cmulf(float2 a, float2 b) {
  return make_float2(a.x * b.x - a.y * b.y, a.x * b.y + a.y * b.x);
}

template<int DIR>
__device__ __forceinline__ void dft4(float2* v) {
  float ax = v[0].x + v[2].x, ay = v[0].y + v[2].y;
  float bx = v[0].x - v[2].x, by = v[0].y - v[2].y;
  float cx = v[1].x + v[3].x, cy = v[1].y + v[3].y;
  float dx = v[1].x - v[3].x, dy = v[1].y - v[3].y;
  float dix, diy;
  if (DIR < 0) { dix = dy; diy = -dx; }
  else         { dix = -dy; diy = dx; }
  v[0] = make_float2(ax + cx, ay + cy);
  v[2] = make_float2(ax - cx, ay - cy);
  v[1] = make_float2(bx + dix, by + diy);
  v[3] = make_float2(bx - dix, by - diy);
}

// DFT-3: X1 = m + i*s*S3*d, X2 = m - i*s*S3*d; m = a - u/2, u=b+c, d=b-c.
template<int SIGN>
__device__ __forceinline__ void dft3(float2 a, float2 b, float2 c,
                                     float2& X0, float2& X1, float2& X2) {
  const float S3 = 0.86602540378443864676f;
  float ux = b.x + c.x, uy = b.y + c.y;
  float dx = b.x - c.x, dy = b.y - c.y;
  float mx = a.x - 0.5f * ux, my = a.y - 0.5f * uy;
  float ex = S3 * dx, ey = S3 * dy;
  X0 = make_float2(a.x + ux, a.y + uy);
  if (SIGN < 0) {
    X1 = make_float2(mx + ey, my - ex);
    X2 = make_float2(mx - ey, my + ex);
  } else {
    X1 = make_float2(mx - ey, my + ex);
    X2 = make_float2(mx + ey, my - ex);
  }
}

// Fast DFT-6 = two DFT-3 + trivial W6 twiddles. Verified on impulses.
template<int SIGN>
__device__ __forceinline__ void dft6(float2* v) {
  const float S3 = 0.86602540378443864676f;
  float2 E0, E1, E2, O0, O1, O2;
  dft3<SIGN>(v[0], v[2], v[4], E0, E1, E2);
  dft3<SIGN>(v[1], v[3], v[5], O0, O1, O2);
  const float ss = (SIGN < 0) ? -S3 : S3;
  float2 T1 = cmulf(O1, make_float2(0.5f, ss));
  float2 T2 = cmulf(O2, make_float2(-0.5f, ss));
  v[0] = make_float2(E0.x + O0.x, E0.y + O0.y);
  v[1] = make_float2(E1.x + T1.x, E1.y + T1.y);
  v[2] = make_float2(E2.x + T2.x, E2.y + T2.y);
  v[3] = make_float2(E0.x - O0.x, E0.y - O0.y);
  v[4] = make_float2(E1.x - T1.x, E1.y - T1.y);
  v[5] = make_float2(E2.x - T2.x, E2.y - T2.y);
}

// ---------------- register FFT machinery (iteration path) ------------------
// Stage twiddle (hs,t): exp(SIGN*i*pi*j/32), j=(t&(h-1))<<(5-hs); lane j of
// the wave holds (tc,ts)=(cos,sin)(pi*j/32). Stages hs<=1 are trivial.

// one dif butterfly step on a 6-reg array
template<int SIGN>
__device__ __forceinline__ void dif_step(float2 v[6], int h, bool hi,
                                         float cs, float sn) {
#pragma unroll
  for (int r = 0; r < 6; ++r) {
    float2 o;
    o.x = __shfl_xor(v[r].x, h);
    o.y = __shfl_xor(v[r].y, h);
    float dx = o.x - v[r].x, dy = o.y - v[r].y;
    float2 twv = make_float2(dx * cs - dy * sn, dx * sn + dy * cs);
    v[r] = hi ? twv : make_float2(v[r].x + o.x, v[r].y + o.y);
  }
}
// trivial dif step: tw = 1 (t even) or +-i (t odd, iq=true)
template<int SIGN>
__device__ __forceinline__ void dif_step_triv(float2 v[6], int h, bool hi, bool iq) {
#pragma unroll
  for (int r = 0; r < 6; ++r) {
    float2 o;
    o.x = __shfl_xor(v[r].x, h);
    o.y = __shfl_xor(v[r].y, h);
    float dx = o.x - v[r].x, dy = o.y - v[r].y;
    float2 twv = iq ? make_float2(-(float)SIGN * dy, (float)SIGN * dx)
                    : make_float2(dx, dy);
    v[r] = hi ? twv : make_float2(v[r].x + o.x, v[r].y + o.y);
  }
}

// radix-2 DIF FFT-64, TWO independent columns interleaved.
template<int SIGN>
__device__ __forceinline__ void dif64t2(float2 u[6], float2 v[6], int t,
                                        float tc, float ts) {
#pragma unroll
  for (int hs = 5; hs >= 2; --hs) {
    int h = 1 << hs;
    int j = (t & (h - 1)) << (5 - hs);
    float cs = __shfl(tc, j);
    float sn = __shfl(ts, j);
    sn = (SIGN < 0) ? -sn : sn;
    bool hi = (t & h) != 0;
    dif_step<SIGN>(u, h, hi, cs, sn);
    dif_step<SIGN>(v, h, hi, cs, sn);
  }
  bool iq = (t & 1) != 0;
  dif_step_triv<SIGN>(u, 2, (t & 2) != 0, iq);
  dif_step_triv<SIGN>(v, 2, (t & 2) != 0, iq);
  dif_step_triv<SIGN>(u, 1, iq, false);
  dif_step_triv<SIGN>(v, 1, iq, false);
}

// single-column variant (p1)
template<int SIGN>
__device__ __forceinline__ void dif64t(float2 v[6], int t, float tc, float ts) {
#pragma unroll
  for (int hs = 5; hs >= 2; --hs) {
    int h = 1 << hs;
    int j = (t & (h - 1)) << (5 - hs);
    float cs = __shfl(tc, j);
    float sn = __shfl(ts, j);
    sn = (SIGN < 0) ? -sn : sn;
    dif_step<SIGN>(v, h, (t & h) != 0, cs, sn);
  }
  bool iq = (t & 1) != 0;
  dif_step_triv<SIGN>(v, 2, (t & 2) != 0, iq);
  dif_step_triv<SIGN>(v, 1, iq, false);
}

// one dit butterfly step
template<int SIGN>
__device__ __forceinline__ void dit_step(float2 v[6], int h, bool hi,
                                         float cs, float sn) {
#pragma unroll
  for (int r = 0; r < 6; ++r) {
    float2 bt = v[r];
    if (hi) bt = make_float2(v[r].x * cs - v[r].y * sn, v[r].x * sn + v[r].y * cs);
    float2 o;
    o.x = __shfl_xor(bt.x, h);
    o.y = __shfl_xor(bt.y, h);
    v[r] = hi ? make_float2(o.x - bt.x, o.y - bt.y)
              : make_float2(bt.x + o.x, bt.y + o.y);
  }
}
// trivial dit step: hi lanes with iq multiply by +-i first
template<int SIGN>
__device__ __forceinline__ void dit_step_triv(float2 v[6], int h, bool hi, bool iq) {
#pragma unroll
  for (int r = 0; r < 6; ++r) {
    float2 bt = v[r];
    if (hi && iq) bt = make_float2(-(float)SIGN * v[r].y, (float)SIGN * v[r].x);
    float2 o;
    o.x = __shfl_xor(bt.x, h);
    o.y = __shfl_xor(bt.y, h);
    v[r] = hi ? make_float2(o.x - bt.x, o.y - bt.y)
              : make_float2(bt.x + o.x, bt.y + o.y);
  }
}

// radix-2 DIT FFT-64, TWO independent columns interleaved.
template<int SIGN>
__device__ __forceinline__ void dit64t2(float2 u[6], float2 v[6], int t,
                                        float tc, float ts) {
  bool iq = (t & 1) != 0;
  dit_step_triv<SIGN>(u, 1, iq, false);
  dit_step_triv<SIGN>(v, 1, iq, false);
  dit_step_triv<SIGN>(u, 2, (t & 2) != 0, iq);
  dit_step_triv<SIGN>(v, 2, (t & 2) != 0, iq);
#pragma unroll
  for (int hs = 2; hs < 6; ++hs) {
    int h = 1 << hs;
    int j = (t & (h - 1)) << (5 - hs);
    float cs = __shfl(tc, j);
    float sn = __shfl(ts, j);
    sn = (SIGN < 0) ? -sn : sn;
    bool hi = (t & h) != 0;
    dit_step<SIGN>(u, h, hi, cs, sn);
    dit_step<SIGN>(v, h, hi, cs, sn);
  }
}

// single-column variant (unused by hot path but kept for clarity/fallback)
template<int SIGN>
__device__ __forceinline__ void dit64t(float2 v[6], int t, float tc, float ts) {
  bool iq = (t & 1) != 0;
  dit_step_triv<SIGN>(v, 1, iq, false);
  dit_step_triv<SIGN>(v, 2, (t & 2) != 0, iq);
#pragma unroll
  for (int hs = 2; hs < 6; ++hs) {
    int h = 1 << hs;
    int j = (t & (h - 1)) << (5 - hs);
    float cs = __shfl(tc, j);
    float sn = __shfl(ts, j);
    sn = (SIGN < 0) ? -sn : sn;
    dit_step<SIGN>(v, h, (t & h) != 0, cs, sn);
  }
}

// FWD single: natural in -> permuted out. w[r-1] = exp(SIGN*2pi*i*r*t/384).
template<int SIGN>
__device__ __forceinline__ void fwd384t(float2 v[6], int t, float tc, float ts,
                                        const float2 w[5]) {
  dft6<SIGN>(v);
#pragma unroll
  for (int r = 1; r < 6; ++r) v[r] = cmulf(v[r], w[r - 1]);
  dif64t<SIGN>(v, t, tc, ts);
}

// FWD dual
template<int SIGN>
__device__ __forceinline__ void fwd384t2(float2 u[6], float2 v[6], int t,
                                         float tc, float ts, const float2 w[5]) {
  dft6<SIGN>(u);
  dft6<SIGN>(v);
#pragma unroll
  for (int r = 1; r < 6; ++r) { u[r] = cmulf(u[r], w[r - 1]); v[r] = cmulf(v[r], w[r - 1]); }
  dif64t2<SIGN>(u, v, t, tc, ts);
}

// BWD dual: permuted in -> natural out; unnormalized inverse of fwd384t.
template<int SIGN>
__device__ __forceinline__ void bwd384t2(float2 u[6], float2 v[6], int t,
                                         float tc, float ts, const float2 w[5]) {
  dit64t2<SIGN>(u, v, t, tc, ts);
#pragma unroll
  for (int r = 1; r < 6; ++r) { u[r] = cmulf(u[r], w[r - 1]); v[r] = cmulf(v[r], w[r - 1]); }
  dft6<SIGN>(u);
  dft6<SIGN>(v);
}

// ---------------- old LDS fft384 (precompute kernels only) -----------------
template<int R, int NS, int DIR>
__device__ __forceinline__ void fft_stage(const float2* S, float2* D, int t) {
  constexpr int NR = NN / R;
#pragma unroll
  for (int rep = 0; rep < (NR + 63) / 64; ++rep) {
    int j = t + rep * 64;
    if (j < NR) {
      float2 v[R];
#pragma unroll
      for (int r = 0; r < R; ++r) v[r] = S[LID(j + r * NR)];
      if constexpr (NS > 1) {
        float ang = (float)DIR * (TWOPI_F / (float)(NS * R)) * (float)(j % NS);
        float sv, cv;
        __sincosf(ang, &sv, &cv);
        float2 w = make_float2(cv, sv);
        float2 wr = w;
#pragma unroll
        for (int r = 1; r < R; ++r) { v[r] = cmulf(v[r], wr); wr = cmulf(wr, w); }
      }
      if constexpr (R == 4) dft4<DIR>(v); else dft6<DIR>(v);
      int base = (j / NS) * (NS * R) + (j % NS);
#pragma unroll
      for (int r = 0; r < R; ++r) D[LID(base + r * NS)] = v[r];
    }
  }
}

template<int DIR>
__device__ __forceinline__ void fft384(float2* A, float2* Bf, int t) {
  fft_stage<4, 1,  DIR>(A,  Bf, t); __syncthreads();
  fft_stage<4, 4,  DIR>(Bf, A,  t); __syncthreads();
  fft_stage<4, 16, DIR>(A,  Bf, t); __syncthreads();
  fft_stage<6, 64, DIR>(Bf, A,  t); __syncthreads();
}

// ---------------- E: iteration 1 (y0 = 0 -> grad = -cst), elementwise ------
__global__ __launch_bounds__(256) void k_e(const float2* __restrict__ cstb,
                                           const float* __restrict__ zk,
                                           const float* __restrict__ lamp,
                                           float2* __restrict__ xbuf,
                                           float2* __restrict__ ybuf) {
  long i = (long)blockIdx.x * 256 + threadIdx.x;
  long b = i / (NN * NN);
  long p = i % (NN * NN);
  float lamv = lamp[0];
  float2 cs = cstb[i];
  float zr = zk[(b * 2 + 0) * (long)(NN * NN) + p];
  float zi = zk[(b * 2 + 1) * (long)(NN * NN) + p];
  float xr = cs.x - lamv * (cs.x - zr);
  float xi = cs.y - lamv * (cs.y - zi);
  xr = fmaxf(xr, 0.f);
  xi = fmaxf(xi, 0.f);
  float2 x = make_float2(xr, xi);
  xbuf[i] = x;
  ybuf[i] = x;   // t1 = 1 -> y1 = x1
}

// ---------------- P1: row FFT of coil*y -> W1 (permuted-x storage) ---------
// grid B*C*384/4, 256 thr; one wave per row; no LDS, no barriers.
__global__ __launch_bounds__(256) void k_p1(const float2* __restrict__ ybuf,
                                            const float* __restrict__ csm,
                                            float2* __restrict__ W1) {
  int t = threadIdx.x & 63;
  int w = threadIdx.x >> 6;
  long gl = (long)blockIdx.x * 4 + w;       // (b*C + c)*384 + y
  int y = (int)(gl % NN);
  long bc = gl / NN;
  long b = bc >> 4, c = bc & 15;
  long rowoff = (long)y * NN;
  float tc, ts; __sincosf((float)(t & 31) * (PI_F / 32.0f), &ts, &tc);
  float2 w0; __sincosf(-(float)t * (TWOPI_F / 384.0f), &w0.y, &w0.x);
  float2 wf[5];
  wf[0] = w0;
#pragma unroll
  for (int r = 1; r < 5; ++r) wf[r] = cmulf(wf[r - 1], w0);
  const float2* yrow = ybuf + b * (long)(NN * NN) + rowoff;
  const float* crow_re = csm + (b * 2 * CC + c) * (long)(NN * NN) + rowoff;
  const float* crow_im = crow_re + (long)CC * NN * NN;
  float2 v[6];
#pragma unroll
  for (int k = 0; k < 6; ++k) {
    int x = t + 64 * k;
    float2 yv = yrow[x];
    float cre = crow_re[x], cim = crow_im[x];
    v[k] = make_float2(yv.x * cre - yv.y * cim, yv.x * cim + yv.y * cre);
  }
  fwd384t<-1>(v, t, tc, ts, wf);
  float2* orow = W1 + gl * NN;
#pragma unroll
  for (int r = 0; r < 6; ++r) orow[t + 64 * r] = v[r];
}

// ---------------- P2: col FFT -> mask -> col IFFT, in-place on W1 ----------
// grid B*C*(N/8)=3072 blocks, 256 thr. 8-col planar tile, pad 392.
// float4 fill/drain; each wave runs cols {2w, 2w+1} interleaved through one
// FFT body (2x ILP on the shuffle chains). XCD-chunked swizzle (R6).
#define P2PAD 392
__global__ __launch_bounds__(256) void k_p2(float2* __restrict__ W1,
                                            const unsigned char* __restrict__ maskPT) {
  __shared__ float ldsR[8][P2PAD];
  __shared__ float ldsI[8][P2PAD];
  int tid = threadIdx.x;
  const int nwg = BB * CC * (NN / 8);            // 3072, divisible by 8
  int l = ((int)blockIdx.x & 7) * (nwg >> 3) + ((int)blockIdx.x >> 3);
  int xt = l % (NN / 8);
  long bc = l / (NN / 8);
  long b = bc >> 4;
  int s0 = xt * 8;
  long sbase = bc * (long)(NN * NN);
  int w = tid >> 6, t = tid & 63;
  // twiddle setup: table + outer chains both directions
  float tc, ts; __sincosf((float)(t & 31) * (PI_F / 32.0f), &ts, &tc);
  float2 w0; __sincosf(-(float)t * (TWOPI_F / 384.0f), &w0.y, &w0.x);
  float2 wf[5], wb[5];
  wf[0] = w0;
#pragma unroll
  for (int r = 1; r < 5; ++r) wf[r] = cmulf(wf[r - 1], w0);
#pragma unroll
  for (int r = 0; r < 5; ++r) wb[r] = make_float2(wf[r].x, -wf[r].y);
  // fill: float4 (2 complex) per op; 6 ops/thread
  const float4* W1v = (const float4*)W1;
  long f4base = (sbase >> 1) + (s0 >> 1);
#pragma unroll
  for (int k = 0; k < 6; ++k) {
    int e = tid + k * 256; int y = e >> 2; int q = e & 3;
    float4 val = W1v[f4base + (long)y * (NN / 2) + q];
    ldsR[2 * q][y] = val.x; ldsI[2 * q][y] = val.y;
    ldsR[2 * q + 1][y] = val.z; ldsI[2 * q + 1][y] = val.w;
  }
  __syncthreads();
  const unsigned char* mb = maskPT + b * (long)(NN * NN);
  {
    int c0 = 2 * w, c1 = 2 * w + 1;
    float2 u[6], v[6];
#pragma unroll
    for (int k = 0; k < 6; ++k) {
      u[k] = make_float2(ldsR[c0][t + 64 * k], ldsI[c0][t + 64 * k]);
      v[k] = make_float2(ldsR[c1][t + 64 * k], ldsI[c1][t + 64 * k]);
    }
    fwd384t2<-1>(u, v, t, tc, ts, wf);
    const unsigned char* m0 = mb + (long)(s0 + c0) * NN;
    const unsigned char* m1 = mb + (long)(s0 + c1) * NN;
#pragma unroll
    for (int r = 0; r < 6; ++r) {
      float mv0 = (float)m0[t + 64 * r];
      float mv1 = (float)m1[t + 64 * r];
      u[r].x *= mv0; u[r].y *= mv0;
      v[r].x *= mv1; v[r].y *= mv1;
    }
    bwd384t2<1>(u, v, t, tc, ts, wb);
#pragma unroll
    for (int k = 0; k < 6; ++k) {
      ldsR[c0][t + 64 * k] = u[k].x * (1.0f / NN);
      ldsI[c0][t + 64 * k] = u[k].y * (1.0f / NN);
      ldsR[c1][t + 64 * k] = v[k].x * (1.0f / NN);
      ldsI[c1][t + 64 * k] = v[k].y * (1.0f / NN);
    }
  }
  __syncthreads();
  float4* W1o = (float4*)W1;
#pragma unroll
  for (int k = 0; k < 6; ++k) {
    int e = tid + k * 256; int y = e >> 2; int q = e & 3;
    float4 val;
    val.x = ldsR[2 * q][y]; val.y = ldsI[2 * q][y];
    val.z = ldsR[2 * q + 1][y]; val.w = ldsI[2 * q + 1][y];
    W1o[f4base + (long)y * (NN / 2) + q] = val;
  }
}

// ---------------- P3: row IFFT + conj(coil) reduce + FISTA update ----------
// grid B*384 blocks, 256 thr; wave w handles coils 4w..4w+3 (2 at a time,
// interleaved through one FFT body); LDS reduce.
// last!=0: write planar output instead of x/y (final iteration).
__global__ __launch_bounds__(256) void k_p3(const float2* __restrict__ W1,
                                            const float* __restrict__ csm,
                                            const float2* __restrict__ cstb,
                                            const float* __restrict__ zk,
                                            const float* __restrict__ lamp,
                                            float2* __restrict__ xbuf,
                                            float2* __restrict__ ybuf,
                                            float* __restrict__ outp,
                                            float beta, int last) {
  __shared__ float2 part[4][NN];
  int tid = threadIdx.x;
  int w = tid >> 6, t = tid & 63;
  long gl = blockIdx.x;            // b*384 + y
  long b = gl / NN;
  int y = (int)(gl % NN);
  long rowoff = (long)y * NN;
  float tc, ts; __sincosf((float)(t & 31) * (PI_F / 32.0f), &ts, &tc);
  float2 w0; __sincosf((float)t * (TWOPI_F / 384.0f), &w0.y, &w0.x);
  float2 wb[5];
  wb[0] = w0;
#pragma unroll
  for (int r = 1; r < 5; ++r) wb[r] = cmulf(wb[r - 1], w0);
  float2 acc[6];
#pragma unroll
  for (int k = 0; k < 6; ++k) acc[k] = make_float2(0.f, 0.f);
#pragma unroll
  for (int ci = 0; ci < 4; ci += 2) {
    int c0 = w * 4 + ci, c1 = c0 + 1;
    const float2* row0 = W1 + ((b * CC + c0) * (long)NN + y) * NN;
    const float2* row1 = W1 + ((b * CC + c1) * (long)NN + y) * NN;
    float2 u[6], v[6];
#pragma unroll
    for (int r = 0; r < 6; ++r) { u[r] = row0[t + 64 * r]; v[r] = row1[t + 64 * r]; }
    bwd384t2<1>(u, v, t, tc, ts, wb);
    const float* cre0 = csm + (b * 2 * CC + c0) * (long)(NN * NN) + rowoff;
    const float* cim0 = cre0 + (long)CC * NN * NN;
    const float* cre1 = csm + (b * 2 * CC + c1) * (long)(NN * NN) + rowoff;
    const float* cim1 = cre1 + (long)CC * NN * NN;
#pragma unroll
    for (int k = 0; k < 6; ++k) {
      int x = t + 64 * k;
      float a0 = cre0[x], b0 = cim0[x];
      float a1 = cre1[x], b1 = cim1[x];
      acc[k].x += (a0 * u[k].x + b0 * u[k].y) + (a1 * v[k].x + b1 * v[k].y);
      acc[k].y += (a0 * u[k].y - b0 * u[k].x) + (a1 * v[k].y - b1 * v[k].x);
    }
  }
#pragma unroll
  for (int k = 0; k < 6; ++k) part[w][t + 64 * k] = acc[k];
  __syncthreads();
  float lamv = lamp[0];
  long pbase = b * (long)(NN * NN) + rowoff;
  for (int e = tid; e < NN; e += 256) {
    float Qx = (part[0][e].x + part[1][e].x + part[2][e].x + part[3][e].x) * (1.0f / NN);
    float Qy = (part[0][e].y + part[1][e].y + part[2][e].y + part[3][e].y) * (1.0f / NN);
    float2 yv = ybuf[pbase + e];
    float2 cs = cstb[pbase + e];
    float zr = zk[(b * 2 + 0) * (long)(NN * NN) + rowoff + e];
    float zi = zk[(b * 2 + 1) * (long)(NN * NN) + rowoff + e];
    float xr = yv.x - (Qx - cs.x);
    float xi = yv.y - (Qy - cs.y);
    xr = xr - lamv * (xr - zr);
    xi = xi - lamv * (xi - zi);
    xr = fmaxf(xr, 0.f);
    xi = fmaxf(xi, 0.f);
    if (last) {
      outp[(b * 2 + 0) * (long)(NN * NN) + rowoff + e] = xr;
      outp[(b * 2 + 1) * (long)(NN * NN) + rowoff + e] = xi;
    } else {
      float2 xo = xbuf[pbase + e];
      xbuf[pbase + e] = make_float2(xr, xi);
      ybuf[pbase + e] = make_float2(xr + beta * (xr - xo.x), xi + beta * (xi - xo.y));
    }
  }
}

// ---------------- mask permutation precompute (one-time) -------------------
// maskPT[b][sx][sy] = mask[b][P(sy)][P(sx)], P(s) = (s>>6) + 6*brev6(s&63)
__global__ __launch_bounds__(256) void k_mpre(const int* __restrict__ mask,
                                              unsigned char* __restrict__ maskPT) {
  long i = (long)blockIdx.x * 256 + threadIdx.x;
  long b = i / (NN * NN);
  int rem = (int)(i % (NN * NN));
  int sx = rem / NN, sy = rem % NN;
  int fx = (sx >> 6) + 6 * (int)(__brev((unsigned)(sx & 63)) >> 26);
  int fy = (sy >> 6) + 6 * (int)(__brev((unsigned)(sy & 63)) >> 26);
  maskPT[i] = (unsigned char)mask[b * (long)(NN * NN) + (long)fy * NN + fx];
}

// ---------------- precompute: cst = (sum_c conj(coil)) * IFFT2(m*b) --------
__global__ __launch_bounds__(256) void k_preA(const float* __restrict__ x0,
                                              const int* __restrict__ mask,
                                              float2* __restrict__ T) {
  __shared__ float2 U[4][LNPAD], V[4][LNPAD];
  int tid = threadIdx.x;
  int line = tid >> 6, t = tid & 63;
  long gl0 = (long)blockIdx.x * 4;
#pragma unroll
  for (int k = 0; k < 6; ++k) {
    int e = tid + k * 256; int l = e / NN; int x = e % NN;
    long gl = gl0 + l;
    long b = gl / NN;
    int y = (int)(gl % NN);
    long pidx = (long)y * NN + x;
    float mv = (float)mask[b * (long)(NN * NN) + pidx];
    float br = x0[(b * 2 + 0) * (long)(NN * NN) + pidx] * mv;
    float bi = x0[(b * 2 + 1) * (long)(NN * NN) + pidx] * mv;
    U[l][LID(x)] = make_float2(br, bi);
  }
  __syncthreads();
  fft384<1>(U[line], V[line], t);
#pragma unroll
  for (int k = 0; k < 6; ++k) {
    int e = tid + k * 256; int l = e / NN; int x = e % NN;
    float2 u = U[l][LID(x)];
    T[(gl0 + l) * NN + x] = make_float2(u.x * (1.0f / NN), u.y * (1.0f / NN));
  }
}

__global__ __launch_bounds__(256) void k_preB(const float2* __restrict__ T,
                                              float2* __restrict__ r0) {
  __shared__ float2 tile[NN][17];
  __shared__ float2 U[4][LNPAD], V[4][LNPAD];
  int tid = threadIdx.x;
  int xt = blockIdx.x % (NN / 16);
  long b = blockIdx.x / (NN / 16);
  int x0c = xt * 16;
  long sbase = b * (long)(NN * NN);
#pragma unroll
  for (int k = 0; k < 24; ++k) {
    int e = tid + k * 256; int y = e >> 4; int c = e & 15;
    tile[y][c] = T[sbase + (long)y * NN + x0c + c];
  }
  __syncthreads();
  int line = tid >> 6, t = tid & 63;
  for (int g = 0; g < 4; ++g) {
#pragma unroll
    for (int k = 0; k < 6; ++k) {
      int e = tid + k * 256; int l = e / NN; int y = e % NN;
      U[l][LID(y)] = tile[y][4 * g + l];
    }
    __syncthreads();
    fft384<1>(U[line], V[line], t);
#pragma unroll
    for (int k = 0; k < 6; ++k) {
      int e = tid + k * 256; int l = e / NN; int y = e % NN;
      float2 u = U[l][LID(y)];
      tile[y][4 * g + l] = make_float2(u.x * (1.0f / NN), u.y * (1.0f / NN));
    }
    __syncthreads();
  }
#pragma unroll
  for (int k = 0; k < 24; ++k) {
    int e = tid + k * 256; int y = e >> 4; int c = e & 15;
    r0[sbase + (long)y * NN + x0c + c] = tile[y][c];
  }
}

__global__ __launch_bounds__(256) void k_preC(const float* __restrict__ csm,
                                              const float2* __restrict__ r0,
                                              float2* __restrict__ cstb) {
  long i = (long)blockIdx.x * 256 + threadIdx.x;
  long b = i / (NN * NN);
  long p = i % (NN * NN);
  float sr = 0.f, si = 0.f;
#pragma unroll
  for (int c = 0; c < CC; ++c) {
    sr += csm[(b * 2 * CC + c) * (long)(NN * NN) + p];
    si -= csm[((b * 2 + 1) * CC + c) * (long)(NN * NN) + p];
  }
  float2 r = r0[i];
  cstb[i] = make_float2(sr * r.x - si * r.y, sr * r.y + si * r.x);
}

extern "C" void kernel_launch(void* const* d_in, const int* in_sizes, int n_in,
                              void* d_out, int out_size, void* d_ws, size_t ws_size,
                              hipStream_t stream) {
  const float* zk  = (const float*)d_in[0];
  const float* x0  = (const float*)d_in[1];
  const float* csm = (const float*)d_in[2];
  const float* lam = (const float*)d_in[3];
  const int*   msk = (const int*)d_in[4];
  float* out = (float*)d_out;

  // ws layout (float2 units): W1 [B*C*N*N] | y | x | cst | maskPT(uchar)
  size_t img = (size_t)BB * NN * NN;
  float2* W1   = (float2*)d_ws;
  float2* ybuf = W1 + (size_t)BB * CC * NN * NN;
  float2* xbuf = ybuf + img;
  float2* cstb = xbuf + img;
  unsigned char* maskPT = (unsigned char*)(cstb + img);
  float2* T  = W1;        // precompute scratch overlays W1
  float2* r0 = W1 + img;

  double tcur = 1.0;
  float betas[NITER];
  for (int i = 0; i < NITER; ++i) {
    double tn = (1.0 + sqrt(1.0 + 4.0 * tcur * tcur)) * 0.5;
    betas[i] = (float)((tcur - 1.0) / tn);
    tcur = tn;
  }

  k_mpre<<<(BB * NN * NN) / 256, 256, 0, stream>>>(msk, maskPT);
  k_preA<<<BB * NN / 4, 256, 0, stream>>>(x0, msk, T);
  k_preB<<<BB * (NN / 16), 256, 0, stream>>>(T, r0);
  k_preC<<<(BB * NN * NN) / 256, 256, 0, stream>>>(csm, r0, cstb);
  // iteration 1 (y0 = 0): pure elementwise
  k_e<<<(BB * NN * NN) / 256, 256, 0, stream>>>(cstb, zk, lam, xbuf, ybuf);
  // iterations 2..20: forward, mask round-trip, adjoint+update
  for (int i = 1; i < NITER; ++i) {
    k_p1<<<BB * CC * NN / 4, 256, 0, stream>>>(ybuf, csm, W1);
    k_p2<<<BB * CC * (NN / 8), 256, 0, stream>>>(W1, maskPT);
    k_p3<<<BB * NN, 256, 0, stream>>>(W1, csm, cstb, zk, lam, xbuf, ybuf, out,
                                      betas[i], (i == NITER - 1) ? 1 : 0);
  }
}

// Round 10
// 2375.732 us; speedup vs baseline: 1.1356x; 1.0425x over previous
//
#include <hip/hip_runtime.h>
#include <math.h>

// FISTA data-consistency with masked multi-coil 2D FFT operator.
// B=4, C=16, H=W=384.
// Register FFT: 384 = 6 (regs) x 64 (lanes); DIF leaves bit-reversed-permuted
// frequencies; mask is pre-permuted; DIT consumes permuted order (free).
// Twiddles: 32-entry register table (1 sincosf/kernel) pulled via __shfl.
// Exchanges: h=16/32 via __builtin_amdgcn_permlane{16,32}_swap with
// XOR-of-pair recovery (r[0]^r[1]^self = partner, exact & ordering-immune);
// h=1,2,4,8 via __shfl_xor. R9 lesson: never two unverified primitives at
// once (DPP + inline-asm permlane combo failed on HW); DPP deferred.
// R3: don't fuse p3+p1. R4: 64B chunks overfetch 2x across XCDs -> XCD swizzle.
// R7: kernels transform-throughput (LDS shuffle pipe) bound.
// R8: fp16 W1 FAILS (trajectory diverges to ~4e17 -> fp16 range overflow).

#define NN 384
#define BB 4
#define CC 16
#define NITER 20
#define LNPAD 432   // old LDS path (precompute only)
#define PI_F 3.14159265358979323846f
#define TWOPI_F 6.28318530717958647692f

__device__ __forceinline__ int LID(int i) { return i + (i >> 3); }

__device__ __forceinline__ float2 cmulf(float2 a, float2 b) {
  return make_float2(a.x * b.x - a.y * b.y, a.x * b.y + a.y * b.x);
}

// ---------------- cross-lane exchange primitives ---------------------------
typedef unsigned int uint2v __attribute__((ext_vector_type(2)));

// xor-32 partner via permlane32_swap (VALU pipe). With both inputs = s, the
// result pair holds {self, partner} per lane in some order regardless of the
// instruction's swap direction / return ordering; XOR recovers the partner
// bit-exactly.
__device__ __forceinline__ float xswap32(float v) {
  unsigned s = __float_as_uint(v);
  uint2v r = __builtin_amdgcn_permlane32_swap(s, s, false, false);
  return __uint_as_float(r[0] ^ r[1] ^ s);
}

#if __has_builtin(__builtin_amdgcn_permlane16_swap)
__device__ __forceinline__ float xswap16(float v) {
  unsigned s = __float_as_uint(v);
  uint2v r = __builtin_amdgcn_permlane16_swap(s, s, false, false);
  return __uint_as_float(r[0] ^ r[1] ^ s);
}
#else
__device__ __forceinline__ float xswap16(float v) { return __shfl_xor(v, 16); }
#endif

template<int H>
__device__ __forceinline__ float2 exch(float2 v, int t) {
  if constexpr (H == 32) {
    return make_float2(xswap32(v.x), xswap32(v.y));
  } else if constexpr (H == 16) {
    return make_float2(xswap16(v.x), xswap16(v.y));
  } else {
    return make_float2(__shfl_xor(v.x, H), __shfl_xor(v.y, H));
  }
}

template<int DIR>
__device__ __forceinline__ void dft4(float2* v) {
  float ax = v[0].x + v[2].x, ay = v[0].y + v[2].y;
  float bx = v[0].x - v[2].x, by = v[0].y - v[2].y;
  float cx = v[1].x + v[3].x, cy = v[1].y + v[3].y;
  float dx = v[1].x - v[3].x, dy = v[1].y - v[3].y;
  float dix, diy;
  if (DIR < 0) { dix = dy; diy = -dx; }
  else         { dix = -dy; diy = dx; }
  v[0] = make_float2(ax + cx, ay + cy);
  v[2] = make_float2(ax - cx, ay - cy);
  v[1] = make_float2(bx + dix, by + diy);
  v[3] = make_float2(bx - dix, by - diy);
}

// DFT-3: X1 = m + i*s*S3*d, X2 = m - i*s*S3*d; m = a - u/2, u=b+c, d=b-c.
template<int SIGN>
__device__ __forceinline__ void dft3(float2 a, float2 b, float2 c,
                                     float2& X0, float2& X1, float2& X2) {
  const float S3 = 0.86602540378443864676f;
  float ux = b.x + c.x, uy = b.y + c.y;
  float dx = b.x - c.x, dy = b.y - c.y;
  float mx = a.x - 0.5f * ux, my = a.y - 0.5f * uy;
  float ex = S3 * dx, ey = S3 * dy;
  X0 = make_float2(a.x + ux, a.y + uy);
  if (SIGN < 0) {
    X1 = make_float2(mx + ey, my - ex);
    X2 = make_float2(mx - ey, my + ex);
  } else {
    X1 = make_float2(mx - ey, my + ex);
    X2 = make_float2(mx + ey, my - ex);
  }
}

// Fast DFT-6 = two DFT-3 + trivial W6 twiddles. Verified on impulses.
template<int SIGN>
__device__ __forceinline__ void dft6(float2* v) {
  const float S3 = 0.86602540378443864676f;
  float2 E0, E1, E2, O0, O1, O2;
  dft3<SIGN>(v[0], v[2], v[4], E0, E1, E2);
  dft3<SIGN>(v[1], v[3], v[5], O0, O1, O2);
  const float ss = (SIGN < 0) ? -S3 : S3;
  float2 T1 = cmulf(O1, make_float2(0.5f, ss));
  float2 T2 = cmulf(O2, make_float2(-0.5f, ss));
  v[0] = make_float2(E0.x + O0.x, E0.y + O0.y);
  v[1] = make_float2(E1.x + T1.x, E1.y + T1.y);
  v[2] = make_float2(E2.x + T2.x, E2.y + T2.y);
  v[3] = make_float2(E0.x - O0.x, E0.y - O0.y);
  v[4] = make_float2(E1.x - T1.x, E1.y - T1.y);
  v[5] = make_float2(E2.x - T2.x, E2.y - T2.y);
}

// ---------------- register FFT machinery (iteration path) ------------------
// Stage twiddle (hs,t): exp(SIGN*i*pi*j/32), j=(t&(h-1))<<(5-hs); lane j of
// the wave holds (tc,ts)=(cos,sin)(pi*j/32). Stages h=1,2 are trivial.

template<int SIGN, int H>
__device__ __forceinline__ void dif_stepH(float2 v[6], int t, float cs, float sn) {
  bool hi = (t & H) != 0;
#pragma unroll
  for (int r = 0; r < 6; ++r) {
    float2 o = exch<H>(v[r], t);
    float dx = o.x - v[r].x, dy = o.y - v[r].y;
    float2 twv = make_float2(dx * cs - dy * sn, dx * sn + dy * cs);
    v[r] = hi ? twv : make_float2(v[r].x + o.x, v[r].y + o.y);
  }
}
template<int SIGN, int H>
__device__ __forceinline__ void dif_stepH_triv(float2 v[6], int t, bool iq) {
  bool hi = (t & H) != 0;
#pragma unroll
  for (int r = 0; r < 6; ++r) {
    float2 o = exch<H>(v[r], t);
    float dx = o.x - v[r].x, dy = o.y - v[r].y;
    float2 twv = iq ? make_float2(-(float)SIGN * dy, (float)SIGN * dx)
                    : make_float2(dx, dy);
    v[r] = hi ? twv : make_float2(v[r].x + o.x, v[r].y + o.y);
  }
}

// radix-2 DIF FFT-64, TWO independent columns interleaved.
template<int SIGN>
__device__ __forceinline__ void dif64t2(float2 u[6], float2 v[6], int t,
                                        float tc, float ts) {
  {
    int j = t & 31;                                   // h=32
    float cs = __shfl(tc, j), sn = __shfl(ts, j);
    sn = (SIGN < 0) ? -sn : sn;
    dif_stepH<SIGN, 32>(u, t, cs, sn);
    dif_stepH<SIGN, 32>(v, t, cs, sn);
  }
  {
    int j = (t & 15) << 1;                            // h=16
    float cs = __shfl(tc, j), sn = __shfl(ts, j);
    sn = (SIGN < 0) ? -sn : sn;
    dif_stepH<SIGN, 16>(u, t, cs, sn);
    dif_stepH<SIGN, 16>(v, t, cs, sn);
  }
  {
    int j = (t & 7) << 2;                             // h=8
    float cs = __shfl(tc, j), sn = __shfl(ts, j);
    sn = (SIGN < 0) ? -sn : sn;
    dif_stepH<SIGN, 8>(u, t, cs, sn);
    dif_stepH<SIGN, 8>(v, t, cs, sn);
  }
  {
    int j = (t & 3) << 3;                             // h=4
    float cs = __shfl(tc, j), sn = __shfl(ts, j);
    sn = (SIGN < 0) ? -sn : sn;
    dif_stepH<SIGN, 4>(u, t, cs, sn);
    dif_stepH<SIGN, 4>(v, t, cs, sn);
  }
  bool iq = (t & 1) != 0;
  dif_stepH_triv<SIGN, 2>(u, t, iq);
  dif_stepH_triv<SIGN, 2>(v, t, iq);
  dif_stepH_triv<SIGN, 1>(u, t, false);
  dif_stepH_triv<SIGN, 1>(v, t, false);
}

// single-column variant (p1)
template<int SIGN>
__device__ __forceinline__ void dif64t(float2 v[6], int t, float tc, float ts) {
  {
    int j = t & 31;
    float cs = __shfl(tc, j), sn = __shfl(ts, j);
    sn = (SIGN < 0) ? -sn : sn;
    dif_stepH<SIGN, 32>(v, t, cs, sn);
  }
  {
    int j = (t & 15) << 1;
    float cs = __shfl(tc, j), sn = __shfl(ts, j);
    sn = (SIGN < 0) ? -sn : sn;
    dif_stepH<SIGN, 16>(v, t, cs, sn);
  }
  {
    int j = (t & 7) << 2;
    float cs = __shfl(tc, j), sn = __shfl(ts, j);
    sn = (SIGN < 0) ? -sn : sn;
    dif_stepH<SIGN, 8>(v, t, cs, sn);
  }
  {
    int j = (t & 3) << 3;
    float cs = __shfl(tc, j), sn = __shfl(ts, j);
    sn = (SIGN < 0) ? -sn : sn;
    dif_stepH<SIGN, 4>(v, t, cs, sn);
  }
  bool iq = (t & 1) != 0;
  dif_stepH_triv<SIGN, 2>(v, t, iq);
  dif_stepH_triv<SIGN, 1>(v, t, false);
}

template<int SIGN, int H>
__device__ __forceinline__ void dit_stepH(float2 v[6], int t, float cs, float sn) {
  bool hi = (t & H) != 0;
#pragma unroll
  for (int r = 0; r < 6; ++r) {
    float2 bt = v[r];
    if (hi) bt = make_float2(v[r].x * cs - v[r].y * sn, v[r].x * sn + v[r].y * cs);
    float2 o = exch<H>(bt, t);
    v[r] = hi ? make_float2(o.x - bt.x, o.y - bt.y)
              : make_float2(bt.x + o.x, bt.y + o.y);
  }
}
template<int SIGN, int H>
__device__ __forceinline__ void dit_stepH_triv(float2 v[6], int t, bool iq) {
  bool hi = (t & H) != 0;
#pragma unroll
  for (int r = 0; r < 6; ++r) {
    float2 bt = v[r];
    if (hi && iq) bt = make_float2(-(float)SIGN * v[r].y, (float)SIGN * v[r].x);
    float2 o = exch<H>(bt, t);
    v[r] = hi ? make_float2(o.x - bt.x, o.y - bt.y)
              : make_float2(bt.x + o.x, bt.y + o.y);
  }
}

// radix-2 DIT FFT-64, TWO independent columns interleaved.
template<int SIGN>
__device__ __forceinline__ void dit64t2(float2 u[6], float2 v[6], int t,
                                        float tc, float ts) {
  bool iq = (t & 1) != 0;
  dit_stepH_triv<SIGN, 1>(u, t, false);
  dit_stepH_triv<SIGN, 1>(v, t, false);
  dit_stepH_triv<SIGN, 2>(u, t, iq);
  dit_stepH_triv<SIGN, 2>(v, t, iq);
  {
    int j = (t & 3) << 3;                             // h=4
    float cs = __shfl(tc, j), sn = __shfl(ts, j);
    sn = (SIGN < 0) ? -sn : sn;
    dit_stepH<SIGN, 4>(u, t, cs, sn);
    dit_stepH<SIGN, 4>(v, t, cs, sn);
  }
  {
    int j = (t & 7) << 2;                             // h=8
    float cs = __shfl(tc, j), sn = __shfl(ts, j);
    sn = (SIGN < 0) ? -sn : sn;
    dit_stepH<SIGN, 8>(u, t, cs, sn);
    dit_stepH<SIGN, 8>(v, t, cs, sn);
  }
  {
    int j = (t & 15) << 1;                            // h=16
    float cs = __shfl(tc, j), sn = __shfl(ts, j);
    sn = (SIGN < 0) ? -sn : sn;
    dit_stepH<SIGN, 16>(u, t, cs, sn);
    dit_stepH<SIGN, 16>(v, t, cs, sn);
  }
  {
    int j = t & 31;                                   // h=32
    float cs = __shfl(tc, j), sn = __shfl(ts, j);
    sn = (SIGN < 0) ? -sn : sn;
    dit_stepH<SIGN, 32>(u, t, cs, sn);
    dit_stepH<SIGN, 32>(v, t, cs, sn);
  }
}

// FWD single: natural in -> permuted out. w[r-1] = exp(SIGN*2pi*i*r*t/384).
template<int SIGN>
__device__ __forceinline__ void fwd384t(float2 v[6], int t, float tc, float ts,
                                        const float2 w[5]) {
  dft6<SIGN>(v);
#pragma unroll
  for (int r = 1; r < 6; ++r) v[r] = cmulf(v[r], w[r - 1]);
  dif64t<SIGN>(v, t, tc, ts);
}

// FWD dual
template<int SIGN>
__device__ __forceinline__ void fwd384t2(float2 u[6], float2 v[6], int t,
                                         float tc, float ts, const float2 w[5]) {
  dft6<SIGN>(u);
  dft6<SIGN>(v);
#pragma unroll
  for (int r = 1; r < 6; ++r) { u[r] = cmulf(u[r], w[r - 1]); v[r] = cmulf(v[r], w[r - 1]); }
  dif64t2<SIGN>(u, v, t, tc, ts);
}

// BWD dual: permuted in -> natural out; unnormalized inverse of fwd384t.
template<int SIGN>
__device__ __forceinline__ void bwd384t2(float2 u[6], float2 v[6], int t,
                                         float tc, float ts, const float2 w[5]) {
  dit64t2<SIGN>(u, v, t, tc, ts);
#pragma unroll
  for (int r = 1; r < 6; ++r) { u[r] = cmulf(u[r], w[r - 1]); v[r] = cmulf(v[r], w[r - 1]); }
  dft6<SIGN>(u);
  dft6<SIGN>(v);
}

// ---------------- old LDS fft384 (precompute kernels only) -----------------
template<int R, int NS, int DIR>
__device__ __forceinline__ void fft_stage(const float2* S, float2* D, int t) {
  constexpr int NR = NN / R;
#pragma unroll
  for (int rep = 0; rep < (NR + 63) / 64; ++rep) {
    int j = t + rep * 64;
    if (j < NR) {
      float2 v[R];
#pragma unroll
      for (int r = 0; r < R; ++r) v[r] = S[LID(j + r * NR)];
      if constexpr (NS > 1) {
        float ang = (float)DIR * (TWOPI_F / (float)(NS * R)) * (float)(j % NS);
        float sv, cv;
        __sincosf(ang, &sv, &cv);
        float2 w = make_float2(cv, sv);
        float2 wr = w;
#pragma unroll
        for (int r = 1; r < R; ++r) { v[r] = cmulf(v[r], wr); wr = cmulf(wr, w); }
      }
      if constexpr (R == 4) dft4<DIR>(v); else dft6<DIR>(v);
      int base = (j / NS) * (NS * R) + (j % NS);
#pragma unroll
      for (int r = 0; r < R; ++r) D[LID(base + r * NS)] = v[r];
    }
  }
}

template<int DIR>
__device__ __forceinline__ void fft384(float2* A, float2* Bf, int t) {
  fft_stage<4, 1,  DIR>(A,  Bf, t); __syncthreads();
  fft_stage<4, 4,  DIR>(Bf, A,  t); __syncthreads();
  fft_stage<4, 16, DIR>(A,  Bf, t); __syncthreads();
  fft_stage<6, 64, DIR>(Bf, A,  t); __syncthreads();
}

// ---------------- E: iteration 1 (y0 = 0 -> grad = -cst), elementwise ------
__global__ __launch_bounds__(256) void k_e(const float2* __restrict__ cstb,
                                           const float* __restrict__ zk,
                                           const float* __restrict__ lamp,
                                           float2* __restrict__ xbuf,
                                           float2* __restrict__ ybuf) {
  long i = (long)blockIdx.x * 256 + threadIdx.x;
  long b = i / (NN * NN);
  long p = i % (NN * NN);
  float lamv = lamp[0];
  float2 cs = cstb[i];
  float zr = zk[(b * 2 + 0) * (long)(NN * NN) + p];
  float zi = zk[(b * 2 + 1) * (long)(NN * NN) + p];
  float xr = cs.x - lamv * (cs.x - zr);
  float xi = cs.y - lamv * (cs.y - zi);
  xr = fmaxf(xr, 0.f);
  xi = fmaxf(xi, 0.f);
  float2 x = make_float2(xr, xi);
  xbuf[i] = x;
  ybuf[i] = x;   // t1 = 1 -> y1 = x1
}

// ---------------- P1: row FFT of coil*y -> W1 (permuted-x storage) ---------
// grid B*C*384/4, 256 thr; one wave per row; no LDS, no barriers.
__global__ __launch_bounds__(256) void k_p1(const float2* __restrict__ ybuf,
                                            const float* __restrict__ csm,
                                            float2* __restrict__ W1) {
  int t = threadIdx.x & 63;
  int w = threadIdx.x >> 6;
  long gl = (long)blockIdx.x * 4 + w;       // (b*C + c)*384 + y
  int y = (int)(gl % NN);
  long bc = gl / NN;
  long b = bc >> 4, c = bc & 15;
  long rowoff = (long)y * NN;
  float tc, ts; __sincosf((float)(t & 31) * (PI_F / 32.0f), &ts, &tc);
  float2 w0; __sincosf(-(float)t * (TWOPI_F / 384.0f), &w0.y, &w0.x);
  float2 wf[5];
  wf[0] = w0;
#pragma unroll
  for (int r = 1; r < 5; ++r) wf[r] = cmulf(wf[r - 1], w0);
  const float2* yrow = ybuf + b * (long)(NN * NN) + rowoff;
  const float* crow_re = csm + (b * 2 * CC + c) * (long)(NN * NN) + rowoff;
  const float* crow_im = crow_re + (long)CC * NN * NN;
  float2 v[6];
#pragma unroll
  for (int k = 0; k < 6; ++k) {
    int x = t + 64 * k;
    float2 yv = yrow[x];
    float cre = crow_re[x], cim = crow_im[x];
    v[k] = make_float2(yv.x * cre - yv.y * cim, yv.x * cim + yv.y * cre);
  }
  fwd384t<-1>(v, t, tc, ts, wf);
  float2* orow = W1 + gl * NN;
#pragma unroll
  for (int r = 0; r < 6; ++r) orow[t + 64 * r] = v[r];
}

// ---------------- P2: col FFT -> mask -> col IFFT, in-place on W1 ----------
// grid B*C*(N/8)=3072 blocks, 256 thr. 8-col planar tile, pad 392.
// float4 fill/drain; each wave runs cols {2w, 2w+1} interleaved through one
// FFT body (2x ILP on the shuffle chains). XCD-chunked swizzle (R6).
#define P2PAD 392
__global__ __launch_bounds__(256) void k_p2(float2* __restrict__ W1,
                                            const unsigned char* __restrict__ maskPT) {
  __shared__ float ldsR[8][P2PAD];
  __shared__ float ldsI[8][P2PAD];
  int tid = threadIdx.x;
  const int nwg = BB * CC * (NN / 8);            // 3072, divisible by 8
  int l = ((int)blockIdx.x & 7) * (nwg >> 3) + ((int)blockIdx.x >> 3);
  int xt = l % (NN / 8);
  long bc = l / (NN / 8);
  long b = bc >> 4;
  int s0 = xt * 8;
  long sbase = bc * (long)(NN * NN);
  int w = tid >> 6, t = tid & 63;
  // twiddle setup: table + outer chains both directions
  float tc, ts; __sincosf((float)(t & 31) * (PI_F / 32.0f), &ts, &tc);
  float2 w0; __sincosf(-(float)t * (TWOPI_F / 384.0f), &w0.y, &w0.x);
  float2 wf[5], wb[5];
  wf[0] = w0;
#pragma unroll
  for (int r = 1; r < 5; ++r) wf[r] = cmulf(wf[r - 1], w0);
#pragma unroll
  for (int r = 0; r < 5; ++r) wb[r] = make_float2(wf[r].x, -wf[r].y);
  // fill: float4 (2 complex) per op; 6 ops/thread
  const float4* W1v = (const float4*)W1;
  long f4base = (sbase >> 1) + (s0 >> 1);
#pragma unroll
  for (int k = 0; k < 6; ++k) {
    int e = tid + k * 256; int y = e >> 2; int q = e & 3;
    float4 val = W1v[f4base + (long)y * (NN / 2) + q];
    ldsR[2 * q][y] = val.x; ldsI[2 * q][y] = val.y;
    ldsR[2 * q + 1][y] = val.z; ldsI[2 * q + 1][y] = val.w;
  }
  __syncthreads();
  const unsigned char* mb = maskPT + b * (long)(NN * NN);
  {
    int c0 = 2 * w, c1 = 2 * w + 1;
    float2 u[6], v[6];
#pragma unroll
    for (int k = 0; k < 6; ++k) {
      u[k] = make_float2(ldsR[c0][t + 64 * k], ldsI[c0][t + 64 * k]);
      v[k] = make_float2(ldsR[c1][t + 64 * k], ldsI[c1][t + 64 * k]);
    }
    fwd384t2<-1>(u, v, t, tc, ts, wf);
    const unsigned char* m0 = mb + (long)(s0 + c0) * NN;
    const unsigned char* m1 = mb + (long)(s0 + c1) * NN;
#pragma unroll
    for (int r = 0; r < 6; ++r) {
      float mv0 = (float)m0[t + 64 * r];
      float mv1 = (float)m1[t + 64 * r];
      u[r].x *= mv0; u[r].y *= mv0;
      v[r].x *= mv1; v[r].y *= mv1;
    }
    bwd384t2<1>(u, v, t, tc, ts, wb);
#pragma unroll
    for (int k = 0; k < 6; ++k) {
      ldsR[c0][t + 64 * k] = u[k].x * (1.0f / NN);
      ldsI[c0][t + 64 * k] = u[k].y * (1.0f / NN);
      ldsR[c1][t + 64 * k] = v[k].x * (1.0f / NN);
      ldsI[c1][t + 64 * k] = v[k].y * (1.0f / NN);
    }
  }
  __syncthreads();
  float4* W1o = (float4*)W1;
#pragma unroll
  for (int k = 0; k < 6; ++k) {
    int e = tid + k * 256; int y = e >> 2; int q = e & 3;
    float4 val;
    val.x = ldsR[2 * q][y]; val.y = ldsI[2 * q][y];
    val.z = ldsR[2 * q + 1][y]; val.w = ldsI[2 * q + 1][y];
    W1o[f4base + (long)y * (NN / 2) + q] = val;
  }
}

// ---------------- P3: row IFFT + conj(coil) reduce + FISTA update ----------
// grid B*384 blocks, 256 thr; wave w handles coils 4w..4w+3 (2 at a time,
// interleaved through one FFT body); LDS reduce.
// last!=0: write planar output instead of x/y (final iteration).
__global__ __launch_bounds__(256) void k_p3(const float2* __restrict__ W1,
                                            const float* __restrict__ csm,
                                            const float2* __restrict__ cstb,
                                            const float* __restrict__ zk,
                                            const float* __restrict__ lamp,
                                            float2* __restrict__ xbuf,
                                            float2* __restrict__ ybuf,
                                            float* __restrict__ outp,
                                            float beta, int last) {
  __shared__ float2 part[4][NN];
  int tid = threadIdx.x;
  int w = tid >> 6, t = tid & 63;
  long gl = blockIdx.x;            // b*384 + y
  long b = gl / NN;
  int y = (int)(gl % NN);
  long rowoff = (long)y * NN;
  float tc, ts; __sincosf((float)(t & 31) * (PI_F / 32.0f), &ts, &tc);
  float2 w0; __sincosf((float)t * (TWOPI_F / 384.0f), &w0.y, &w0.x);
  float2 wb[5];
  wb[0] = w0;
#pragma unroll
  for (int r = 1; r < 5; ++r) wb[r] = cmulf(wb[r - 1], w0);
  float2 acc[6];
#pragma unroll
  for (int k = 0; k < 6; ++k) acc[k] = make_float2(0.f, 0.f);
#pragma unroll
  for (int ci = 0; ci < 4; ci += 2) {
    int c0 = w * 4 + ci, c1 = c0 + 1;
    const float2* row0 = W1 + ((b * CC + c0) * (long)NN + y) * NN;
    const float2* row1 = W1 + ((b * CC + c1) * (long)NN + y) * NN;
    float2 u[6], v[6];
#pragma unroll
    for (int r = 0; r < 6; ++r) { u[r] = row0[t + 64 * r]; v[r] = row1[t + 64 * r]; }
    bwd384t2<1>(u, v, t, tc, ts, wb);
    const float* cre0 = csm + (b * 2 * CC + c0) * (long)(NN * NN) + rowoff;
    const float* cim0 = cre0 + (long)CC * NN * NN;
    const float* cre1 = csm + (b * 2 * CC + c1) * (long)(NN * NN) + rowoff;
    const float* cim1 = cre1 + (long)CC * NN * NN;
#pragma unroll
    for (int k = 0; k < 6; ++k) {
      int x = t + 64 * k;
      float a0 = cre0[x], b0 = cim0[x];
      float a1 = cre1[x], b1 = cim1[x];
      acc[k].x += (a0 * u[k].x + b0 * u[k].y) + (a1 * v[k].x + b1 * v[k].y);
      acc[k].y += (a0 * u[k].y - b0 * u[k].x) + (a1 * v[k].y - b1 * v[k].x);
    }
  }
#pragma unroll
  for (int k = 0; k < 6; ++k) part[w][t + 64 * k] = acc[k];
  __syncthreads();
  float lamv = lamp[0];
  long pbase = b * (long)(NN * NN) + rowoff;
  for (int e = tid; e < NN; e += 256) {
    float Qx = (part[0][e].x + part[1][e].x + part[2][e].x + part[3][e].x) * (1.0f / NN);
    float Qy = (part[0][e].y + part[1][e].y + part[2][e].y + part[3][e].y) * (1.0f / NN);
    float2 yv = ybuf[pbase + e];
    float2 cs = cstb[pbase + e];
    float zr = zk[(b * 2 + 0) * (long)(NN * NN) + rowoff + e];
    float zi = zk[(b * 2 + 1) * (long)(NN * NN) + rowoff + e];
    float xr = yv.x - (Qx - cs.x);
    float xi = yv.y - (Qy - cs.y);
    xr = xr - lamv * (xr - zr);
    xi = xi - lamv * (xi - zi);
    xr = fmaxf(xr, 0.f);
    xi = fmaxf(xi, 0.f);
    if (last) {
      outp[(b * 2 + 0) * (long)(NN * NN) + rowoff + e] = xr;
      outp[(b * 2 + 1) * (long)(NN * NN) + rowoff + e] = xi;
    } else {
      float2 xo = xbuf[pbase + e];
      xbuf[pbase + e] = make_float2(xr, xi);
      ybuf[pbase + e] = make_float2(xr + beta * (xr - xo.x), xi + beta * (xi - xo.y));
    }
  }
}

// ---------------- mask permutation precompute (one-time) -------------------
// maskPT[b][sx][sy] = mask[b][P(sy)][P(sx)], P(s) = (s>>6) + 6*brev6(s&63)
__global__ __launch_bounds__(256) void k_mpre(const int* __restrict__ mask,
                                              unsigned char* __restrict__ maskPT) {
  long i = (long)blockIdx.x * 256 + threadIdx.x;
  long b = i / (NN * NN);
  int rem = (int)(i % (NN * NN));
  int sx = rem / NN, sy = rem % NN;
  int fx = (sx >> 6) + 6 * (int)(__brev((unsigned)(sx & 63)) >> 26);
  int fy = (sy >> 6) + 6 * (int)(__brev((unsigned)(sy & 63)) >> 26);
  maskPT[i] = (unsigned char)mask[b * (long)(NN * NN) + (long)fy * NN + fx];
}

// ---------------- precompute: cst = (sum_c conj(coil)) * IFFT2(m*b) --------
__global__ __launch_bounds__(256) void k_preA(const float* __restrict__ x0,
                                              const int* __restrict__ mask,
                                              float2* __restrict__ T) {
  __shared__ float2 U[4][LNPAD], V[4][LNPAD];
  int tid = threadIdx.x;
  int line = tid >> 6, t = tid & 63;
  long gl0 = (long)blockIdx.x * 4;
#pragma unroll
  for (int k = 0; k < 6; ++k) {
    int e = tid + k * 256; int l = e / NN; int x = e % NN;
    long gl = gl0 + l;
    long b = gl / NN;
    int y = (int)(gl % NN);
    long pidx = (long)y * NN + x;
    float mv = (float)mask[b * (long)(NN * NN) + pidx];
    float br = x0[(b * 2 + 0) * (long)(NN * NN) + pidx] * mv;
    float bi = x0[(b * 2 + 1) * (long)(NN * NN) + pidx] * mv;
    U[l][LID(x)] = make_float2(br, bi);
  }
  __syncthreads();
  fft384<1>(U[line], V[line], t);
#pragma unroll
  for (int k = 0; k < 6; ++k) {
    int e = tid + k * 256; int l = e / NN; int x = e % NN;
    float2 u = U[l][LID(x)];
    T[(gl0 + l) * NN + x] = make_float2(u.x * (1.0f / NN), u.y * (1.0f / NN));
  }
}

__global__ __launch_bounds__(256) void k_preB(const float2* __restrict__ T,
                                              float2* __restrict__ r0) {
  __shared__ float2 tile[NN][17];
  __shared__ float2 U[4][LNPAD], V[4][LNPAD];
  int tid = threadIdx.x;
  int xt = blockIdx.x % (NN / 16);
  long b = blockIdx.x / (NN / 16);
  int x0c = xt * 16;
  long sbase = b * (long)(NN * NN);
#pragma unroll
  for (int k = 0; k < 24; ++k) {
    int e = tid + k * 256; int y = e >> 4; int c = e & 15;
    tile[y][c] = T[sbase + (long)y * NN + x0c + c];
  }
  __syncthreads();
  int line = tid >> 6, t = tid & 63;
  for (int g = 0; g < 4; ++g) {
#pragma unroll
    for (int k = 0; k < 6; ++k) {
      int e = tid + k * 256; int l = e / NN; int y = e % NN;
      U[l][LID(y)] = tile[y][4 * g + l];
    }
    __syncthreads();
    fft384<1>(U[line], V[line], t);
#pragma unroll
    for (int k = 0; k < 6; ++k) {
      int e = tid + k * 256; int l = e / NN; int y = e % NN;
      float2 u = U[l][LID(y)];
      tile[y][4 * g + l] = make_float2(u.x * (1.0f / NN), u.y * (1.0f / NN));
    }
    __syncthreads();
  }
#pragma unroll
  for (int k = 0; k < 24; ++k) {
    int e = tid + k * 256; int y = e >> 4; int c = e & 15;
    r0[sbase + (long)y * NN + x0c + c] = tile[y][c];
  }
}

__global__ __launch_bounds__(256) void k_preC(const float* __restrict__ csm,
                                              const float2* __restrict__ r0,
                                              float2* __restrict__ cstb) {
  long i = (long)blockIdx.x * 256 + threadIdx.x;
  long b = i / (NN * NN);
  long p = i % (NN * NN);
  float sr = 0.f, si = 0.f;
#pragma unroll
  for (int c = 0; c < CC; ++c) {
    sr += csm[(b * 2 * CC + c) * (long)(NN * NN) + p];
    si -= csm[((b * 2 + 1) * CC + c) * (long)(NN * NN) + p];
  }
  float2 r = r0[i];
  cstb[i] = make_float2(sr * r.x - si * r.y, sr * r.y + si * r.x);
}

extern "C" void kernel_launch(void* const* d_in, const int* in_sizes, int n_in,
                              void* d_out, int out_size, void* d_ws, size_t ws_size,
                              hipStream_t stream) {
  const float* zk  = (const float*)d_in[0];
  const float* x0  = (const float*)d_in[1];
  const float* csm = (const float*)d_in[2];
  const float* lam = (const float*)d_in[3];
  const int*   msk = (const int*)d_in[4];
  float* out = (float*)d_out;

  // ws layout (float2 units): W1 [B*C*N*N] | y | x | cst | maskPT(uchar)
  size_t img = (size_t)BB * NN * NN;
  float2* W1   = (float2*)d_ws;
  float2* ybuf = W1 + (size_t)BB * CC * NN * NN;
  float2* xbuf = ybuf + img;
  float2* cstb = xbuf + img;
  unsigned char* maskPT = (unsigned char*)(cstb + img);
  float2* T  = W1;        // precompute scratch overlays W1
  float2* r0 = W1 + img;

  double tcur = 1.0;
  float betas[NITER];
  for (int i = 0; i < NITER; ++i) {
    double tn = (1.0 + sqrt(1.0 + 4.0 * tcur * tcur)) * 0.5;
    betas[i] = (float)((tcur - 1.0) / tn);
    tcur = tn;
  }

  k_mpre<<<(BB * NN * NN) / 256, 256, 0, stream>>>(msk, maskPT);
  k_preA<<<BB * NN / 4, 256, 0, stream>>>(x0, msk, T);
  k_preB<<<BB * (NN / 16), 256, 0, stream>>>(T, r0);
  k_preC<<<(BB * NN * NN) / 256, 256, 0, stream>>>(csm, r0, cstb);
  // iteration 1 (y0 = 0): pure elementwise
  k_e<<<(BB * NN * NN) / 256, 256, 0, stream>>>(cstb, zk, lam, xbuf, ybuf);
  // iterations 2..20: forward, mask round-trip, adjoint+update
  for (int i = 1; i < NITER; ++i) {
    k_p1<<<BB * CC * NN / 4, 256, 0, stream>>>(ybuf, csm, W1);
    k_p2<<<BB * CC * (NN / 8), 256, 0, stream>>>(W1, maskPT);
    k_p3<<<BB * NN, 256, 0, stream>>>(W1, csm, cstb, zk, lam, xbuf, ybuf, out,
                                      betas[i], (i == NITER - 1) ? 1 : 0);
  }
}

// Round 11
// 2249.148 us; speedup vs baseline: 1.1995x; 1.0563x over previous
//
#include <hip/hip_runtime.h>
#include <math.h>

// FISTA data-consistency with masked multi-coil 2D FFT operator.
// B=4, C=16, H=W=384.
// Register FFT: 384 = 6 (regs) x 64 (lanes); DIF leaves bit-reversed-permuted
// frequencies; mask is pre-permuted; DIT consumes permuted order (free).
// Twiddles: 32-entry register table (1 sincosf/kernel) via __shfl, PRE-SIGNED.
// Exchanges: h=16/32 permlane{16,32}_swap DIRECT (partner = hi?r[0]:r[1];
// sum uses r[1], diff uses r[0] — no XOR recovery); h=1..8 __shfl_xor.
// zk folded out of the loop: cz = (1-lam)cst + lam*z precomputed; update is
// x = prox((1-lam)(y - Q) + cz). 1/N of the col-IFFT folded into wb chain.
// R3: don't fuse p3+p1. R4: XCD swizzle for split 64B chunks. R7: was LDS-pipe
// bound; R10: permlane verified, now VALU-bound (81%) -> cut VALU ops.
// R8: fp16 W1 FAILS (range). R9: inline-asm permlane aliasing -> use builtins.

#define NN 384
#define BB 4
#define CC 16
#define NITER 20
#define LNPAD 432   // old LDS path (precompute only)
#define PI_F 3.14159265358979323846f
#define TWOPI_F 6.28318530717958647692f

__device__ __forceinline__ int LID(int i) { return i + (i >> 3); }

__device__ __forceinline__ float2 cmulf(float2 a, float2 b) {
  return make_float2(a.x * b.x - a.y * b.y, a.x * b.y + a.y * b.x);
}

// ---------------- cross-lane exchange primitives ---------------------------
typedef unsigned int uint2v __attribute__((ext_vector_type(2)));

// permlane swap with both inputs = s: r[0] = self on "lo" rows, partner on
// "hi" rows (rows swapped INTO vdst); r[1] = partner on lo rows, self on hi.
// (R10 verified the pair is {self, xor-partner}; ordering per CDNA4 swap
// semantics: vdst receives src's rows in its hi positions.)
template<int H>
__device__ __forceinline__ void xpair(float v, float& olo, float& ohi) {
  unsigned s = __float_as_uint(v);
  uint2v r;
  if constexpr (H == 32) {
    r = __builtin_amdgcn_permlane32_swap(s, s, false, false);
  } else {
    r = __builtin_amdgcn_permlane16_swap(s, s, false, false);
  }
  ohi = __uint_as_float(r[0]);   // valid where (t & H) != 0
  olo = __uint_as_float(r[1]);   // valid where (t & H) == 0
}

template<int DIR>
__device__ __forceinline__ void dft4(float2* v) {
  float ax = v[0].x + v[2].x, ay = v[0].y + v[2].y;
  float bx = v[0].x - v[2].x, by = v[0].y - v[2].y;
  float cx = v[1].x + v[3].x, cy = v[1].y + v[3].y;
  float dx = v[1].x - v[3].x, dy = v[1].y - v[3].y;
  float dix, diy;
  if (DIR < 0) { dix = dy; diy = -dx; }
  else         { dix = -dy; diy = dx; }
  v[0] = make_float2(ax + cx, ay + cy);
  v[2] = make_float2(ax - cx, ay - cy);
  v[1] = make_float2(bx + dix, by + diy);
  v[3] = make_float2(bx - dix, by - diy);
}

// DFT-3: X1 = m + i*s*S3*d, X2 = m - i*s*S3*d; m = a - u/2, u=b+c, d=b-c.
template<int SIGN>
__device__ __forceinline__ void dft3(float2 a, float2 b, float2 c,
                                     float2& X0, float2& X1, float2& X2) {
  const float S3 = 0.86602540378443864676f;
  float ux = b.x + c.x, uy = b.y + c.y;
  float dx = b.x - c.x, dy = b.y - c.y;
  float mx = a.x - 0.5f * ux, my = a.y - 0.5f * uy;
  float ex = S3 * dx, ey = S3 * dy;
  X0 = make_float2(a.x + ux, a.y + uy);
  if (SIGN < 0) {
    X1 = make_float2(mx + ey, my - ex);
    X2 = make_float2(mx - ey, my + ex);
  } else {
    X1 = make_float2(mx - ey, my + ex);
    X2 = make_float2(mx + ey, my - ex);
  }
}

// Fast DFT-6 = two DFT-3 + trivial W6 twiddles. Verified on impulses.
template<int SIGN>
__device__ __forceinline__ void dft6(float2* v) {
  const float S3 = 0.86602540378443864676f;
  float2 E0, E1, E2, O0, O1, O2;
  dft3<SIGN>(v[0], v[2], v[4], E0, E1, E2);
  dft3<SIGN>(v[1], v[3], v[5], O0, O1, O2);
  const float ss = (SIGN < 0) ? -S3 : S3;
  float2 T1 = cmulf(O1, make_float2(0.5f, ss));
  float2 T2 = cmulf(O2, make_float2(-0.5f, ss));
  v[0] = make_float2(E0.x + O0.x, E0.y + O0.y);
  v[1] = make_float2(E1.x + T1.x, E1.y + T1.y);
  v[2] = make_float2(E2.x + T2.x, E2.y + T2.y);
  v[3] = make_float2(E0.x - O0.x, E0.y - O0.y);
  v[4] = make_float2(E1.x - T1.x, E1.y - T1.y);
  v[5] = make_float2(E2.x - T2.x, E2.y - T2.y);
}

// ---------------- register FFT machinery (iteration path) ------------------
// Stage twiddle (hs,t): exp(SIGN*i*pi*j/32), j=(t&(h-1))<<(5-hs); lane j of
// the wave holds (tc,ts). ts passed PRE-SIGNED for the direction.

// shfl-based dif step (h=4,8)
template<int H>
__device__ __forceinline__ void dif_stepS(float2 v[6], int t, float cs, float sn) {
  bool hi = (t & H) != 0;
#pragma unroll
  for (int r = 0; r < 6; ++r) {
    float ox = __shfl_xor(v[r].x, H);
    float oy = __shfl_xor(v[r].y, H);
    float dx = ox - v[r].x, dy = oy - v[r].y;
    float2 twv = make_float2(dx * cs - dy * sn, dx * sn + dy * cs);
    v[r] = hi ? twv : make_float2(v[r].x + ox, v[r].y + oy);
  }
}
// permlane-based dif step (h=16,32): sum from r[1] (lo-valid), diff from r[0]
// (hi-valid); cndmask keeps only the valid one per lane.
template<int H>
__device__ __forceinline__ void dif_stepP(float2 v[6], int t, float cs, float sn) {
  bool hi = (t & H) != 0;
#pragma unroll
  for (int r = 0; r < 6; ++r) {
    float xlo, xhi, ylo, yhi;
    xpair<H>(v[r].x, xlo, xhi);
    xpair<H>(v[r].y, ylo, yhi);
    float dx = xhi - v[r].x, dy = yhi - v[r].y;
    float2 twv = make_float2(dx * cs - dy * sn, dx * sn + dy * cs);
    v[r] = hi ? twv : make_float2(v[r].x + xlo, v[r].y + ylo);
  }
}
// trivial dif step (h=1,2): tw = 1 or +-i
template<int SIGN, int H>
__device__ __forceinline__ void dif_stepS_triv(float2 v[6], int t, bool iq) {
  bool hi = (t & H) != 0;
#pragma unroll
  for (int r = 0; r < 6; ++r) {
    float ox = __shfl_xor(v[r].x, H);
    float oy = __shfl_xor(v[r].y, H);
    float dx = ox - v[r].x, dy = oy - v[r].y;
    float2 twv = iq ? make_float2(-(float)SIGN * dy, (float)SIGN * dx)
                    : make_float2(dx, dy);
    v[r] = hi ? twv : make_float2(v[r].x + ox, v[r].y + oy);
  }
}

// radix-2 DIF FFT-64, TWO independent columns interleaved. tss pre-signed.
template<int SIGN>
__device__ __forceinline__ void dif64t2(float2 u[6], float2 v[6], int t,
                                        float tc, float tss) {
  { int j = t & 31;                                   // h=32 (permlane)
    float cs = __shfl(tc, j), sn = __shfl(tss, j);
    dif_stepP<32>(u, t, cs, sn);
    dif_stepP<32>(v, t, cs, sn); }
  { int j = (t & 15) << 1;                            // h=16 (permlane)
    float cs = __shfl(tc, j), sn = __shfl(tss, j);
    dif_stepP<16>(u, t, cs, sn);
    dif_stepP<16>(v, t, cs, sn); }
  { int j = (t & 7) << 2;                             // h=8
    float cs = __shfl(tc, j), sn = __shfl(tss, j);
    dif_stepS<8>(u, t, cs, sn);
    dif_stepS<8>(v, t, cs, sn); }
  { int j = (t & 3) << 3;                             // h=4
    float cs = __shfl(tc, j), sn = __shfl(tss, j);
    dif_stepS<4>(u, t, cs, sn);
    dif_stepS<4>(v, t, cs, sn); }
  bool iq = (t & 1) != 0;
  dif_stepS_triv<SIGN, 2>(u, t, iq);
  dif_stepS_triv<SIGN, 2>(v, t, iq);
  dif_stepS_triv<SIGN, 1>(u, t, false);
  dif_stepS_triv<SIGN, 1>(v, t, false);
}

// single-column variant (p1)
template<int SIGN>
__device__ __forceinline__ void dif64t(float2 v[6], int t, float tc, float tss) {
  { int j = t & 31;
    float cs = __shfl(tc, j), sn = __shfl(tss, j);
    dif_stepP<32>(v, t, cs, sn); }
  { int j = (t & 15) << 1;
    float cs = __shfl(tc, j), sn = __shfl(tss, j);
    dif_stepP<16>(v, t, cs, sn); }
  { int j = (t & 7) << 2;
    float cs = __shfl(tc, j), sn = __shfl(tss, j);
    dif_stepS<8>(v, t, cs, sn); }
  { int j = (t & 3) << 3;
    float cs = __shfl(tc, j), sn = __shfl(tss, j);
    dif_stepS<4>(v, t, cs, sn); }
  bool iq = (t & 1) != 0;
  dif_stepS_triv<SIGN, 2>(v, t, iq);
  dif_stepS_triv<SIGN, 1>(v, t, false);
}

// shfl-based dit step (h=4,8)
template<int H>
__device__ __forceinline__ void dit_stepS(float2 v[6], int t, float cs, float sn) {
  bool hi = (t & H) != 0;
#pragma unroll
  for (int r = 0; r < 6; ++r) {
    float2 bt = v[r];
    if (hi) bt = make_float2(v[r].x * cs - v[r].y * sn, v[r].x * sn + v[r].y * cs);
    float ox = __shfl_xor(bt.x, H);
    float oy = __shfl_xor(bt.y, H);
    v[r] = hi ? make_float2(ox - bt.x, oy - bt.y)
              : make_float2(bt.x + ox, bt.y + oy);
  }
}
// permlane-based dit step (h=16,32)
template<int H>
__device__ __forceinline__ void dit_stepP(float2 v[6], int t, float cs, float sn) {
  bool hi = (t & H) != 0;
#pragma unroll
  for (int r = 0; r < 6; ++r) {
    float2 bt = v[r];
    if (hi) bt = make_float2(v[r].x * cs - v[r].y * sn, v[r].x * sn + v[r].y * cs);
    float xlo, xhi, ylo, yhi;
    xpair<H>(bt.x, xlo, xhi);
    xpair<H>(bt.y, ylo, yhi);
    v[r] = hi ? make_float2(xhi - bt.x, yhi - bt.y)
              : make_float2(bt.x + xlo, bt.y + ylo);
  }
}
// trivial dit step (h=1,2)
template<int SIGN, int H>
__device__ __forceinline__ void dit_stepS_triv(float2 v[6], int t, bool iq) {
  bool hi = (t & H) != 0;
#pragma unroll
  for (int r = 0; r < 6; ++r) {
    float2 bt = v[r];
    if (hi && iq) bt = make_float2(-(float)SIGN * v[r].y, (float)SIGN * v[r].x);
    float ox = __shfl_xor(bt.x, H);
    float oy = __shfl_xor(bt.y, H);
    v[r] = hi ? make_float2(ox - bt.x, oy - bt.y)
              : make_float2(bt.x + ox, bt.y + oy);
  }
}

// radix-2 DIT FFT-64, TWO independent columns interleaved. tss pre-signed.
template<int SIGN>
__device__ __forceinline__ void dit64t2(float2 u[6], float2 v[6], int t,
                                        float tc, float tss) {
  bool iq = (t & 1) != 0;
  dit_stepS_triv<SIGN, 1>(u, t, false);
  dit_stepS_triv<SIGN, 1>(v, t, false);
  dit_stepS_triv<SIGN, 2>(u, t, iq);
  dit_stepS_triv<SIGN, 2>(v, t, iq);
  { int j = (t & 3) << 3;                             // h=4
    float cs = __shfl(tc, j), sn = __shfl(tss, j);
    dit_stepS<4>(u, t, cs, sn);
    dit_stepS<4>(v, t, cs, sn); }
  { int j = (t & 7) << 2;                             // h=8
    float cs = __shfl(tc, j), sn = __shfl(tss, j);
    dit_stepS<8>(u, t, cs, sn);
    dit_stepS<8>(v, t, cs, sn); }
  { int j = (t & 15) << 1;                            // h=16 (permlane)
    float cs = __shfl(tc, j), sn = __shfl(tss, j);
    dit_stepP<16>(u, t, cs, sn);
    dit_stepP<16>(v, t, cs, sn); }
  { int j = t & 31;                                   // h=32 (permlane)
    float cs = __shfl(tc, j), sn = __shfl(tss, j);
    dit_stepP<32>(u, t, cs, sn);
    dit_stepP<32>(v, t, cs, sn); }
}

// FWD single: natural in -> permuted out. w[r-1] = exp(SIGN*2pi*i*r*t/384).
template<int SIGN>
__device__ __forceinline__ void fwd384t(float2 v[6], int t, float tc, float tss,
                                        const float2 w[5]) {
  dft6<SIGN>(v);
#pragma unroll
  for (int r = 1; r < 6; ++r) v[r] = cmulf(v[r], w[r - 1]);
  dif64t<SIGN>(v, t, tc, tss);
}

// FWD dual
template<int SIGN>
__device__ __forceinline__ void fwd384t2(float2 u[6], float2 v[6], int t,
                                         float tc, float tss, const float2 w[5]) {
  dft6<SIGN>(u);
  dft6<SIGN>(v);
#pragma unroll
  for (int r = 1; r < 6; ++r) { u[r] = cmulf(u[r], w[r - 1]); v[r] = cmulf(v[r], w[r - 1]); }
  dif64t2<SIGN>(u, v, t, tc, tss);
}

// BWD dual: permuted in -> natural out. w may carry an extra uniform scale s;
// sc0 applies the same scale to the r=0 (untwiddled) term.
template<int SIGN>
__device__ __forceinline__ void bwd384t2(float2 u[6], float2 v[6], int t,
                                         float tc, float tss, const float2 w[5],
                                         float sc0) {
  dit64t2<SIGN>(u, v, t, tc, tss);
  u[0].x *= sc0; u[0].y *= sc0;
  v[0].x *= sc0; v[0].y *= sc0;
#pragma unroll
  for (int r = 1; r < 6; ++r) { u[r] = cmulf(u[r], w[r - 1]); v[r] = cmulf(v[r], w[r - 1]); }
  dft6<SIGN>(u);
  dft6<SIGN>(v);
}

// ---------------- old LDS fft384 (precompute kernels only) -----------------
template<int R, int NS, int DIR>
__device__ __forceinline__ void fft_stage(const float2* S, float2* D, int t) {
  constexpr int NR = NN / R;
#pragma unroll
  for (int rep = 0; rep < (NR + 63) / 64; ++rep) {
    int j = t + rep * 64;
    if (j < NR) {
      float2 v[R];
#pragma unroll
      for (int r = 0; r < R; ++r) v[r] = S[LID(j + r * NR)];
      if constexpr (NS > 1) {
        float ang = (float)DIR * (TWOPI_F / (float)(NS * R)) * (float)(j % NS);
        float sv, cv;
        __sincosf(ang, &sv, &cv);
        float2 w = make_float2(cv, sv);
        float2 wr = w;
#pragma unroll
        for (int r = 1; r < R; ++r) { v[r] = cmulf(v[r], wr); wr = cmulf(wr, w); }
      }
      if constexpr (R == 4) dft4<DIR>(v); else dft6<DIR>(v);
      int base = (j / NS) * (NS * R) + (j % NS);
#pragma unroll
      for (int r = 0; r < R; ++r) D[LID(base + r * NS)] = v[r];
    }
  }
}

template<int DIR>
__device__ __forceinline__ void fft384(float2* A, float2* Bf, int t) {
  fft_stage<4, 1,  DIR>(A,  Bf, t); __syncthreads();
  fft_stage<4, 4,  DIR>(Bf, A,  t); __syncthreads();
  fft_stage<4, 16, DIR>(A,  Bf, t); __syncthreads();
  fft_stage<6, 64, DIR>(Bf, A,  t); __syncthreads();
}

// ---------------- E: iteration 1 (y0 = 0 -> xn = cz), elementwise ----------
__global__ __launch_bounds__(256) void k_e(const float2* __restrict__ czb,
                                           float2* __restrict__ xbuf,
                                           float2* __restrict__ ybuf) {
  long i = (long)blockIdx.x * 256 + threadIdx.x;
  float2 cz = czb[i];
  float2 x = make_float2(fmaxf(cz.x, 0.f), fmaxf(cz.y, 0.f));
  xbuf[i] = x;
  ybuf[i] = x;   // t1 = 1 -> y1 = x1
}

// ---------------- P1: row FFT of coil*y -> W1 (permuted-x storage) ---------
// grid B*C*384/4, 256 thr; one wave per row; no LDS, no barriers.
__global__ __launch_bounds__(256) void k_p1(const float2* __restrict__ ybuf,
                                            const float* __restrict__ csm,
                                            float2* __restrict__ W1) {
  int t = threadIdx.x & 63;
  int w = threadIdx.x >> 6;
  long gl = (long)blockIdx.x * 4 + w;       // (b*C + c)*384 + y
  int y = (int)(gl % NN);
  long bc = gl / NN;
  long b = bc >> 4, c = bc & 15;
  long rowoff = (long)y * NN;
  float tc, ts; __sincosf((float)(t & 31) * (PI_F / 32.0f), &ts, &tc);
  float tsf = -ts;                           // fwd (SIGN=-1) pre-signed
  float2 w0; __sincosf(-(float)t * (TWOPI_F / 384.0f), &w0.y, &w0.x);
  float2 wf[5];
  wf[0] = w0;
#pragma unroll
  for (int r = 1; r < 5; ++r) wf[r] = cmulf(wf[r - 1], w0);
  const float2* yrow = ybuf + b * (long)(NN * NN) + rowoff;
  const float* crow_re = csm + (b * 2 * CC + c) * (long)(NN * NN) + rowoff;
  const float* crow_im = crow_re + (long)CC * NN * NN;
  float2 v[6];
#pragma unroll
  for (int k = 0; k < 6; ++k) {
    int x = t + 64 * k;
    float2 yv = yrow[x];
    float cre = crow_re[x], cim = crow_im[x];
    v[k] = make_float2(yv.x * cre - yv.y * cim, yv.x * cim + yv.y * cre);
  }
  fwd384t<-1>(v, t, tc, tsf, wf);
  float2* orow = W1 + gl * NN;
#pragma unroll
  for (int r = 0; r < 6; ++r) orow[t + 64 * r] = v[r];
}

// ---------------- P2: col FFT -> mask -> col IFFT, in-place on W1 ----------
// grid B*C*(N/8)=3072 blocks, 256 thr. 8-col planar tile, pad 392.
// float4 fill/drain; each wave runs cols {2w, 2w+1} interleaved through one
// FFT body. XCD-chunked swizzle (R6). 1/N folded into wb + sc0.
#define P2PAD 392
__global__ __launch_bounds__(256) void k_p2(float2* __restrict__ W1,
                                            const unsigned char* __restrict__ maskPT) {
  __shared__ float ldsR[8][P2PAD];
  __shared__ float ldsI[8][P2PAD];
  int tid = threadIdx.x;
  const int nwg = BB * CC * (NN / 8);            // 3072, divisible by 8
  int l = ((int)blockIdx.x & 7) * (nwg >> 3) + ((int)blockIdx.x >> 3);
  int xt = l % (NN / 8);
  long bc = l / (NN / 8);
  long b = bc >> 4;
  int s0 = xt * 8;
  long sbase = bc * (long)(NN * NN);
  int w = tid >> 6, t = tid & 63;
  // twiddle setup: table (pre-signed per direction) + outer chains
  float tc, ts; __sincosf((float)(t & 31) * (PI_F / 32.0f), &ts, &tc);
  float tsf = -ts;
  float2 w0; __sincosf(-(float)t * (TWOPI_F / 384.0f), &w0.y, &w0.x);
  float2 wf[5], wb[5];
  wf[0] = w0;
#pragma unroll
  for (int r = 1; r < 5; ++r) wf[r] = cmulf(wf[r - 1], w0);
  const float inv = 1.0f / NN;
#pragma unroll
  for (int r = 0; r < 5; ++r) wb[r] = make_float2(wf[r].x * inv, -wf[r].y * inv);
  // fill: float4 (2 complex) per op; 6 ops/thread
  const float4* W1v = (const float4*)W1;
  long f4base = (sbase >> 1) + (s0 >> 1);
#pragma unroll
  for (int k = 0; k < 6; ++k) {
    int e = tid + k * 256; int y = e >> 2; int q = e & 3;
    float4 val = W1v[f4base + (long)y * (NN / 2) + q];
    ldsR[2 * q][y] = val.x; ldsI[2 * q][y] = val.y;
    ldsR[2 * q + 1][y] = val.z; ldsI[2 * q + 1][y] = val.w;
  }
  __syncthreads();
  const unsigned char* mb = maskPT + b * (long)(NN * NN);
  {
    int c0 = 2 * w, c1 = 2 * w + 1;
    float2 u[6], v[6];
#pragma unroll
    for (int k = 0; k < 6; ++k) {
      u[k] = make_float2(ldsR[c0][t + 64 * k], ldsI[c0][t + 64 * k]);
      v[k] = make_float2(ldsR[c1][t + 64 * k], ldsI[c1][t + 64 * k]);
    }
    fwd384t2<-1>(u, v, t, tc, tsf, wf);
    const unsigned char* m0 = mb + (long)(s0 + c0) * NN;
    const unsigned char* m1 = mb + (long)(s0 + c1) * NN;
#pragma unroll
    for (int r = 0; r < 6; ++r) {
      float mv0 = (float)m0[t + 64 * r];
      float mv1 = (float)m1[t + 64 * r];
      u[r].x *= mv0; u[r].y *= mv0;
      v[r].x *= mv1; v[r].y *= mv1;
    }
    bwd384t2<1>(u, v, t, tc, ts, wb, inv);
#pragma unroll
    for (int k = 0; k < 6; ++k) {
      ldsR[c0][t + 64 * k] = u[k].x;
      ldsI[c0][t + 64 * k] = u[k].y;
      ldsR[c1][t + 64 * k] = v[k].x;
      ldsI[c1][t + 64 * k] = v[k].y;
    }
  }
  __syncthreads();
  float4* W1o = (float4*)W1;
#pragma unroll
  for (int k = 0; k < 6; ++k) {
    int e = tid + k * 256; int y = e >> 2; int q = e & 3;
    float4 val;
    val.x = ldsR[2 * q][y]; val.y = ldsI[2 * q][y];
    val.z = ldsR[2 * q + 1][y]; val.w = ldsI[2 * q + 1][y];
    W1o[f4base + (long)y * (NN / 2) + q] = val;
  }
}

// ---------------- P3: row IFFT + conj(coil) reduce + FISTA update ----------
// grid B*384 blocks, 256 thr; wave w handles coils 4w..4w+3 (2 at a time);
// LDS reduce. Update: x = prox((1-lam)(y - Q) + cz); zk not touched.
// last!=0: write planar output instead of x/y (final iteration).
__global__ __launch_bounds__(256) void k_p3(const float2* __restrict__ W1,
                                            const float* __restrict__ csm,
                                            const float2* __restrict__ czb,
                                            const float* __restrict__ lamp,
                                            float2* __restrict__ xbuf,
                                            float2* __restrict__ ybuf,
                                            float* __restrict__ outp,
                                            float beta, int last) {
  __shared__ float2 part[4][NN];
  int tid = threadIdx.x;
  int w = tid >> 6, t = tid & 63;
  long gl = blockIdx.x;            // b*384 + y
  long b = gl / NN;
  int y = (int)(gl % NN);
  long rowoff = (long)y * NN;
  float tc, ts; __sincosf((float)(t & 31) * (PI_F / 32.0f), &ts, &tc);
  float2 w0; __sincosf((float)t * (TWOPI_F / 384.0f), &w0.y, &w0.x);
  float2 wb[5];
  wb[0] = w0;
#pragma unroll
  for (int r = 1; r < 5; ++r) wb[r] = cmulf(wb[r - 1], w0);
  float2 acc[6];
#pragma unroll
  for (int k = 0; k < 6; ++k) acc[k] = make_float2(0.f, 0.f);
#pragma unroll
  for (int ci = 0; ci < 4; ci += 2) {
    int c0 = w * 4 + ci, c1 = c0 + 1;
    const float2* row0 = W1 + ((b * CC + c0) * (long)NN + y) * NN;
    const float2* row1 = W1 + ((b * CC + c1) * (long)NN + y) * NN;
    float2 u[6], v[6];
#pragma unroll
    for (int r = 0; r < 6; ++r) { u[r] = row0[t + 64 * r]; v[r] = row1[t + 64 * r]; }
    bwd384t2<1>(u, v, t, tc, ts, wb, 1.0f);
    const float* cre0 = csm + (b * 2 * CC + c0) * (long)(NN * NN) + rowoff;
    const float* cim0 = cre0 + (long)CC * NN * NN;
    const float* cre1 = csm + (b * 2 * CC + c1) * (long)(NN * NN) + rowoff;
    const float* cim1 = cre1 + (long)CC * NN * NN;
#pragma unroll
    for (int k = 0; k < 6; ++k) {
      int x = t + 64 * k;
      float a0 = cre0[x], b0 = cim0[x];
      float a1 = cre1[x], b1 = cim1[x];
      acc[k].x += (a0 * u[k].x + b0 * u[k].y) + (a1 * v[k].x + b1 * v[k].y);
      acc[k].y += (a0 * u[k].y - b0 * u[k].x) + (a1 * v[k].y - b1 * v[k].x);
    }
  }
#pragma unroll
  for (int k = 0; k < 6; ++k) part[w][t + 64 * k] = acc[k];
  __syncthreads();
  float lamv = lamp[0];
  float oml = 1.0f - lamv;
  long pbase = b * (long)(NN * NN) + rowoff;
  for (int e = tid; e < NN; e += 256) {
    float Qx = (part[0][e].x + part[1][e].x + part[2][e].x + part[3][e].x) * (1.0f / NN);
    float Qy = (part[0][e].y + part[1][e].y + part[2][e].y + part[3][e].y) * (1.0f / NN);
    float2 yv = ybuf[pbase + e];
    float2 cz = czb[pbase + e];
    float xr = oml * (yv.x - Qx) + cz.x;
    float xi = oml * (yv.y - Qy) + cz.y;
    xr = fmaxf(xr, 0.f);
    xi = fmaxf(xi, 0.f);
    if (last) {
      outp[(b * 2 + 0) * (long)(NN * NN) + rowoff + e] = xr;
      outp[(b * 2 + 1) * (long)(NN * NN) + rowoff + e] = xi;
    } else {
      float2 xo = xbuf[pbase + e];
      xbuf[pbase + e] = make_float2(xr, xi);
      ybuf[pbase + e] = make_float2(xr + beta * (xr - xo.x), xi + beta * (xi - xo.y));
    }
  }
}

// ---------------- mask permutation precompute (one-time) -------------------
// maskPT[b][sx][sy] = mask[b][P(sy)][P(sx)], P(s) = (s>>6) + 6*brev6(s&63)
__global__ __launch_bounds__(256) void k_mpre(const int* __restrict__ mask,
                                              unsigned char* __restrict__ maskPT) {
  long i = (long)blockIdx.x * 256 + threadIdx.x;
  long b = i / (NN * NN);
  int rem = (int)(i % (NN * NN));
  int sx = rem / NN, sy = rem % NN;
  int fx = (sx >> 6) + 6 * (int)(__brev((unsigned)(sx & 63)) >> 26);
  int fy = (sy >> 6) + 6 * (int)(__brev((unsigned)(sy & 63)) >> 26);
  maskPT[i] = (unsigned char)mask[b * (long)(NN * NN) + (long)fy * NN + fx];
}

// ---------------- precompute: cz = (1-lam)*cst + lam*z ---------------------
__global__ __launch_bounds__(256) void k_preA(const float* __restrict__ x0,
                                              const int* __restrict__ mask,
                                              float2* __restrict__ T) {
  __shared__ float2 U[4][LNPAD], V[4][LNPAD];
  int tid = threadIdx.x;
  int line = tid >> 6, t = tid & 63;
  long gl0 = (long)blockIdx.x * 4;
#pragma unroll
  for (int k = 0; k < 6; ++k) {
    int e = tid + k * 256; int l = e / NN; int x = e % NN;
    long gl = gl0 + l;
    long b = gl / NN;
    int y = (int)(gl % NN);
    long pidx = (long)y * NN + x;
    float mv = (float)mask[b * (long)(NN * NN) + pidx];
    float br = x0[(b * 2 + 0) * (long)(NN * NN) + pidx] * mv;
    float bi = x0[(b * 2 + 1) * (long)(NN * NN) + pidx] * mv;
    U[l][LID(x)] = make_float2(br, bi);
  }
  __syncthreads();
  fft384<1>(U[line], V[line], t);
#pragma unroll
  for (int k = 0; k < 6; ++k) {
    int e = tid + k * 256; int l = e / NN; int x = e % NN;
    float2 u = U[l][LID(x)];
    T[(gl0 + l) * NN + x] = make_float2(u.x * (1.0f / NN), u.y * (1.0f / NN));
  }
}

__global__ __launch_bounds__(256) void k_preB(const float2* __restrict__ T,
                                              float2* __restrict__ r0) {
  __shared__ float2 tile[NN][17];
  __shared__ float2 U[4][LNPAD], V[4][LNPAD];
  int tid = threadIdx.x;
  int xt = blockIdx.x % (NN / 16);
  long b = blockIdx.x / (NN / 16);
  int x0c = xt * 16;
  long sbase = b * (long)(NN * NN);
#pragma unroll
  for (int k = 0; k < 24; ++k) {
    int e = tid + k * 256; int y = e >> 4; int c = e & 15;
    tile[y][c] = T[sbase + (long)y * NN + x0c + c];
  }
  __syncthreads();
  int line = tid >> 6, t = tid & 63;
  for (int g = 0; g < 4; ++g) {
#pragma unroll
    for (int k = 0; k < 6; ++k) {
      int e = tid + k * 256; int l = e / NN; int y = e % NN;
      U[l][LID(y)] = tile[y][4 * g + l];
    }
    __syncthreads();
    fft384<1>(U[line], V[line], t);
#pragma unroll
    for (int k = 0; k < 6; ++k) {
      int e = tid + k * 256; int l = e / NN; int y = e % NN;
      float2 u = U[l][LID(y)];
      tile[y][4 * g + l] = make_float2(u.x * (1.0f / NN), u.y * (1.0f / NN));
    }
    __syncthreads();
  }
#pragma unroll
  for (int k = 0; k < 24; ++k) {
    int e = tid + k * 256; int y = e >> 4; int c = e & 15;
    r0[sbase + (long)y * NN + x0c + c] = tile[y][c];
  }
}

__global__ __launch_bounds__(256) void k_preC(const float* __restrict__ csm,
                                              const float2* __restrict__ r0,
                                              const float* __restrict__ zk,
                                              const float* __restrict__ lamp,
                                              float2* __restrict__ czb) {
  long i = (long)blockIdx.x * 256 + threadIdx.x;
  long b = i / (NN * NN);
  long p = i % (NN * NN);
  float sr = 0.f, si = 0.f;
#pragma unroll
  for (int c = 0; c < CC; ++c) {
    sr += csm[(b * 2 * CC + c) * (long)(NN * NN) + p];
    si -= csm[((b * 2 + 1) * CC + c) * (long)(NN * NN) + p];
  }
  float2 r = r0[i];
  float cstx = sr * r.x - si * r.y;
  float csty = sr * r.y + si * r.x;
  float lamv = lamp[0];
  float oml = 1.0f - lamv;
  float zr = zk[(b * 2 + 0) * (long)(NN * NN) + p];
  float zi = zk[(b * 2 + 1) * (long)(NN * NN) + p];
  czb[i] = make_float2(oml * cstx + lamv * zr, oml * csty + lamv * zi);
}

extern "C" void kernel_launch(void* const* d_in, const int* in_sizes, int n_in,
                              void* d_out, int out_size, void* d_ws, size_t ws_size,
                              hipStream_t stream) {
  const float* zk  = (const float*)d_in[0];
  const float* x0  = (const float*)d_in[1];
  const float* csm = (const float*)d_in[2];
  const float* lam = (const float*)d_in[3];
  const int*   msk = (const int*)d_in[4];
  float* out = (float*)d_out;

  // ws layout (float2 units): W1 [B*C*N*N] | y | x | cz | maskPT(uchar)
  size_t img = (size_t)BB * NN * NN;
  float2* W1   = (float2*)d_ws;
  float2* ybuf = W1 + (size_t)BB * CC * NN * NN;
  float2* xbuf = ybuf + img;
  float2* czb  = xbuf + img;
  unsigned char* maskPT = (unsigned char*)(czb + img);
  float2* T  = W1;        // precompute scratch overlays W1
  float2* r0 = W1 + img;

  double tcur = 1.0;
  float betas[NITER];
  for (int i = 0; i < NITER; ++i) {
    double tn = (1.0 + sqrt(1.0 + 4.0 * tcur * tcur)) * 0.5;
    betas[i] = (float)((tcur - 1.0) / tn);
    tcur = tn;
  }

  k_mpre<<<(BB * NN * NN) / 256, 256, 0, stream>>>(msk, maskPT);
  k_preA<<<BB * NN / 4, 256, 0, stream>>>(x0, msk, T);
  k_preB<<<BB * (NN / 16), 256, 0, stream>>>(T, r0);
  k_preC<<<(BB * NN * NN) / 256, 256, 0, stream>>>(csm, r0, zk, lam, czb);
  // iteration 1 (y0 = 0): x1 = prox(cz)
  k_e<<<(BB * NN * NN) / 256, 256, 0, stream>>>(czb, xbuf, ybuf);
  // iterations 2..20: forward, mask round-trip, adjoint+update
  for (int i = 1; i < NITER; ++i) {
    k_p1<<<BB * CC * NN / 4, 256, 0, stream>>>(ybuf, csm, W1);
    k_p2<<<BB * CC * (NN / 8), 256, 0, stream>>>(W1, maskPT);
    k_p3<<<BB * NN, 256, 0, stream>>>(W1, csm, czb, lam, xbuf, ybuf, out,
                                      betas[i], (i == NITER - 1) ? 1 : 0);
  }
}

// Round 12
// 2222.659 us; speedup vs baseline: 1.2138x; 1.0119x over previous
//
#include <hip/hip_runtime.h>
#include <math.h>

// FISTA data-consistency with masked multi-coil 2D FFT operator.
// B=4, C=16, H=W=384.
// Register FFT: 384 = 6 (regs) x 64 (lanes); DIF leaves bit-reversed-permuted
// frequencies; mask is pre-permuted; DIT consumes permuted order (free).
// Twiddles: 32-entry register table (1 sincosf/kernel) via __shfl, PRE-SIGNED.
// Exchanges: h=1,2 DPP quad_perm (VALU); h=4,8 __shfl_xor (LDS pipe);
// h=16/32 permlane{16,32}_swap + XOR-recovery (r[0]^r[1]^self = partner —
// R11 lesson: XOR form keeps live ranges short; VGPR 44 vs 56, occ +6%).
// zk folded out: cz = (1-lam)cst + lam*z; update x = prox((1-lam)(y-Q)+cz).
// 1/N of col-IFFT folded into wb chain.
// R3: don't fuse p3+p1. R4: XCD swizzle for split 64B chunks. R7: LDS-pipe
// transform-throughput bound. R8: fp16 W1 FAILS (range overflow).
// R9: inline-asm permlane aliasing broke — builtins only, 1 new primitive
// per round with bit-exact absmax discriminator (expect 5.6295e14).

#define NN 384
#define BB 4
#define CC 16
#define NITER 20
#define LNPAD 432   // old LDS path (precompute only)
#define PI_F 3.14159265358979323846f
#define TWOPI_F 6.28318530717958647692f

__device__ __forceinline__ int LID(int i) { return i + (i >> 3); }

__device__ __forceinline__ float2 cmulf(float2 a, float2 b) {
  return make_float2(a.x * b.x - a.y * b.y, a.x * b.y + a.y * b.x);
}

// ---------------- cross-lane exchange primitives ---------------------------
typedef unsigned int uint2v __attribute__((ext_vector_type(2)));

// xor-32 / xor-16 partner via permlane swap (VALU pipe), XOR recovery:
// with both inputs = s the result pair is {self, partner}; XOR recovers
// the partner bit-exactly regardless of pair ordering. [R10-verified]
__device__ __forceinline__ float xswap32(float v) {
  unsigned s = __float_as_uint(v);
  uint2v r = __builtin_amdgcn_permlane32_swap(s, s, false, false);
  return __uint_as_float(r[0] ^ r[1] ^ s);
}
__device__ __forceinline__ float xswap16(float v) {
  unsigned s = __float_as_uint(v);
  uint2v r = __builtin_amdgcn_permlane16_swap(s, s, false, false);
  return __uint_as_float(r[0] ^ r[1] ^ s);
}
// xor-1 / xor-2 via DPP quad_perm (VALU pipe). ctrl = p0|p1<<2|p2<<4|p3<<6.
// xor-1: [1,0,3,2] = 0xB1; xor-2: [2,3,0,1] = 0x4E. old = src (safe).
template<int CTRL>
__device__ __forceinline__ float dppx(float v) {
  int s = __float_as_int(v);
  return __int_as_float(__builtin_amdgcn_update_dpp(s, s, CTRL, 0xF, 0xF, true));
}

template<int H>
__device__ __forceinline__ float2 exch(float2 v) {
  if constexpr (H == 1) {
    return make_float2(dppx<0xB1>(v.x), dppx<0xB1>(v.y));
  } else if constexpr (H == 2) {
    return make_float2(dppx<0x4E>(v.x), dppx<0x4E>(v.y));
  } else if constexpr (H == 16) {
    return make_float2(xswap16(v.x), xswap16(v.y));
  } else if constexpr (H == 32) {
    return make_float2(xswap32(v.x), xswap32(v.y));
  } else {
    return make_float2(__shfl_xor(v.x, H), __shfl_xor(v.y, H));
  }
}

template<int DIR>
__device__ __forceinline__ void dft4(float2* v) {
  float ax = v[0].x + v[2].x, ay = v[0].y + v[2].y;
  float bx = v[0].x - v[2].x, by = v[0].y - v[2].y;
  float cx = v[1].x + v[3].x, cy = v[1].y + v[3].y;
  float dx = v[1].x - v[3].x, dy = v[1].y - v[3].y;
  float dix, diy;
  if (DIR < 0) { dix = dy; diy = -dx; }
  else         { dix = -dy; diy = dx; }
  v[0] = make_float2(ax + cx, ay + cy);
  v[2] = make_float2(ax - cx, ay - cy);
  v[1] = make_float2(bx + dix, by + diy);
  v[3] = make_float2(bx - dix, by - diy);
}

// DFT-3: X1 = m + i*s*S3*d, X2 = m - i*s*S3*d; m = a - u/2, u=b+c, d=b-c.
template<int SIGN>
__device__ __forceinline__ void dft3(float2 a, float2 b, float2 c,
                                     float2& X0, float2& X1, float2& X2) {
  const float S3 = 0.86602540378443864676f;
  float ux = b.x + c.x, uy = b.y + c.y;
  float dx = b.x - c.x, dy = b.y - c.y;
  float mx = a.x - 0.5f * ux, my = a.y - 0.5f * uy;
  float ex = S3 * dx, ey = S3 * dy;
  X0 = make_float2(a.x + ux, a.y + uy);
  if (SIGN < 0) {
    X1 = make_float2(mx + ey, my - ex);
    X2 = make_float2(mx - ey, my + ex);
  } else {
    X1 = make_float2(mx - ey, my + ex);
    X2 = make_float2(mx + ey, my - ex);
  }
}

// Fast DFT-6 = two DFT-3 + trivial W6 twiddles. Verified on impulses.
template<int SIGN>
__device__ __forceinline__ void dft6(float2* v) {
  const float S3 = 0.86602540378443864676f;
  float2 E0, E1, E2, O0, O1, O2;
  dft3<SIGN>(v[0], v[2], v[4], E0, E1, E2);
  dft3<SIGN>(v[1], v[3], v[5], O0, O1, O2);
  const float ss = (SIGN < 0) ? -S3 : S3;
  float2 T1 = cmulf(O1, make_float2(0.5f, ss));
  float2 T2 = cmulf(O2, make_float2(-0.5f, ss));
  v[0] = make_float2(E0.x + O0.x, E0.y + O0.y);
  v[1] = make_float2(E1.x + T1.x, E1.y + T1.y);
  v[2] = make_float2(E2.x + T2.x, E2.y + T2.y);
  v[3] = make_float2(E0.x - O0.x, E0.y - O0.y);
  v[4] = make_float2(E1.x - T1.x, E1.y - T1.y);
  v[5] = make_float2(E2.x - T2.x, E2.y - T2.y);
}

// ---------------- register FFT machinery (iteration path) ------------------
// Stage twiddle (hs,t): exp(SIGN*i*pi*j/32), j=(t&(h-1))<<(5-hs); lane j of
// the wave holds (tc,ts). ts passed PRE-SIGNED for the direction.

template<int H>
__device__ __forceinline__ void dif_step(float2 v[6], int t, float cs, float sn) {
  bool hi = (t & H) != 0;
#pragma unroll
  for (int r = 0; r < 6; ++r) {
    float2 o = exch<H>(v[r]);
    float dx = o.x - v[r].x, dy = o.y - v[r].y;
    float2 twv = make_float2(dx * cs - dy * sn, dx * sn + dy * cs);
    v[r] = hi ? twv : make_float2(v[r].x + o.x, v[r].y + o.y);
  }
}
// trivial dif step (h=1,2): tw = 1 or +-i
template<int SIGN, int H>
__device__ __forceinline__ void dif_step_triv(float2 v[6], int t, bool iq) {
  bool hi = (t & H) != 0;
#pragma unroll
  for (int r = 0; r < 6; ++r) {
    float2 o = exch<H>(v[r]);
    float dx = o.x - v[r].x, dy = o.y - v[r].y;
    float2 twv = iq ? make_float2(-(float)SIGN * dy, (float)SIGN * dx)
                    : make_float2(dx, dy);
    v[r] = hi ? twv : make_float2(v[r].x + o.x, v[r].y + o.y);
  }
}

// radix-2 DIF FFT-64, TWO independent columns interleaved. tss pre-signed.
template<int SIGN>
__device__ __forceinline__ void dif64t2(float2 u[6], float2 v[6], int t,
                                        float tc, float tss) {
  { int j = t & 31;                                   // h=32 (permlane)
    float cs = __shfl(tc, j), sn = __shfl(tss, j);
    dif_step<32>(u, t, cs, sn);
    dif_step<32>(v, t, cs, sn); }
  { int j = (t & 15) << 1;                            // h=16 (permlane)
    float cs = __shfl(tc, j), sn = __shfl(tss, j);
    dif_step<16>(u, t, cs, sn);
    dif_step<16>(v, t, cs, sn); }
  { int j = (t & 7) << 2;                             // h=8
    float cs = __shfl(tc, j), sn = __shfl(tss, j);
    dif_step<8>(u, t, cs, sn);
    dif_step<8>(v, t, cs, sn); }
  { int j = (t & 3) << 3;                             // h=4
    float cs = __shfl(tc, j), sn = __shfl(tss, j);
    dif_step<4>(u, t, cs, sn);
    dif_step<4>(v, t, cs, sn); }
  bool iq = (t & 1) != 0;
  dif_step_triv<SIGN, 2>(u, t, iq);                   // h=2 (DPP)
  dif_step_triv<SIGN, 2>(v, t, iq);
  dif_step_triv<SIGN, 1>(u, t, false);                // h=1 (DPP)
  dif_step_triv<SIGN, 1>(v, t, false);
}

// single-column variant (p1)
template<int SIGN>
__device__ __forceinline__ void dif64t(float2 v[6], int t, float tc, float tss) {
  { int j = t & 31;
    float cs = __shfl(tc, j), sn = __shfl(tss, j);
    dif_step<32>(v, t, cs, sn); }
  { int j = (t & 15) << 1;
    float cs = __shfl(tc, j), sn = __shfl(tss, j);
    dif_step<16>(v, t, cs, sn); }
  { int j = (t & 7) << 2;
    float cs = __shfl(tc, j), sn = __shfl(tss, j);
    dif_step<8>(v, t, cs, sn); }
  { int j = (t & 3) << 3;
    float cs = __shfl(tc, j), sn = __shfl(tss, j);
    dif_step<4>(v, t, cs, sn); }
  bool iq = (t & 1) != 0;
  dif_step_triv<SIGN, 2>(v, t, iq);
  dif_step_triv<SIGN, 1>(v, t, false);
}

template<int H>
__device__ __forceinline__ void dit_step(float2 v[6], int t, float cs, float sn) {
  bool hi = (t & H) != 0;
#pragma unroll
  for (int r = 0; r < 6; ++r) {
    float2 bt = v[r];
    if (hi) bt = make_float2(v[r].x * cs - v[r].y * sn, v[r].x * sn + v[r].y * cs);
    float2 o = exch<H>(bt);
    v[r] = hi ? make_float2(o.x - bt.x, o.y - bt.y)
              : make_float2(bt.x + o.x, bt.y + o.y);
  }
}
// trivial dit step (h=1,2)
template<int SIGN, int H>
__device__ __forceinline__ void dit_step_triv(float2 v[6], int t, bool iq) {
  bool hi = (t & H) != 0;
#pragma unroll
  for (int r = 0; r < 6; ++r) {
    float2 bt = v[r];
    if (hi && iq) bt = make_float2(-(float)SIGN * v[r].y, (float)SIGN * v[r].x);
    float2 o = exch<H>(bt);
    v[r] = hi ? make_float2(o.x - bt.x, o.y - bt.y)
              : make_float2(bt.x + o.x, bt.y + o.y);
  }
}

// radix-2 DIT FFT-64, TWO independent columns interleaved. tss pre-signed.
template<int SIGN>
__device__ __forceinline__ void dit64t2(float2 u[6], float2 v[6], int t,
                                        float tc, float tss) {
  bool iq = (t & 1) != 0;
  dit_step_triv<SIGN, 1>(u, t, false);                // h=1 (DPP)
  dit_step_triv<SIGN, 1>(v, t, false);
  dit_step_triv<SIGN, 2>(u, t, iq);                   // h=2 (DPP)
  dit_step_triv<SIGN, 2>(v, t, iq);
  { int j = (t & 3) << 3;                             // h=4
    float cs = __shfl(tc, j), sn = __shfl(tss, j);
    dit_step<4>(u, t, cs, sn);
    dit_step<4>(v, t, cs, sn); }
  { int j = (t & 7) << 2;                             // h=8
    float cs = __shfl(tc, j), sn = __shfl(tss, j);
    dit_step<8>(u, t, cs, sn);
    dit_step<8>(v, t, cs, sn); }
  { int j = (t & 15) << 1;                            // h=16 (permlane)
    float cs = __shfl(tc, j), sn = __shfl(tss, j);
    dit_step<16>(u, t, cs, sn);
    dit_step<16>(v, t, cs, sn); }
  { int j = t & 31;                                   // h=32 (permlane)
    float cs = __shfl(tc, j), sn = __shfl(tss, j);
    dit_step<32>(u, t, cs, sn);
    dit_step<32>(v, t, cs, sn); }
}

// FWD single: natural in -> permuted out. w[r-1] = exp(SIGN*2pi*i*r*t/384).
template<int SIGN>
__device__ __forceinline__ void fwd384t(float2 v[6], int t, float tc, float tss,
                                        const float2 w[5]) {
  dft6<SIGN>(v);
#pragma unroll
  for (int r = 1; r < 6; ++r) v[r] = cmulf(v[r], w[r - 1]);
  dif64t<SIGN>(v, t, tc, tss);
}

// FWD dual
template<int SIGN>
__device__ __forceinline__ void fwd384t2(float2 u[6], float2 v[6], int t,
                                         float tc, float tss, const float2 w[5]) {
  dft6<SIGN>(u);
  dft6<SIGN>(v);
#pragma unroll
  for (int r = 1; r < 6; ++r) { u[r] = cmulf(u[r], w[r - 1]); v[r] = cmulf(v[r], w[r - 1]); }
  dif64t2<SIGN>(u, v, t, tc, tss);
}

// BWD dual: permuted in -> natural out. w may carry an extra uniform scale;
// sc0 applies the same scale to the r=0 (untwiddled) term.
template<int SIGN>
__device__ __forceinline__ void bwd384t2(float2 u[6], float2 v[6], int t,
                                         float tc, float tss, const float2 w[5],
                                         float sc0) {
  dit64t2<SIGN>(u, v, t, tc, tss);
  u[0].x *= sc0; u[0].y *= sc0;
  v[0].x *= sc0; v[0].y *= sc0;
#pragma unroll
  for (int r = 1; r < 6; ++r) { u[r] = cmulf(u[r], w[r - 1]); v[r] = cmulf(v[r], w[r - 1]); }
  dft6<SIGN>(u);
  dft6<SIGN>(v);
}

// ---------------- old LDS fft384 (precompute kernels only) -----------------
template<int R, int NS, int DIR>
__device__ __forceinline__ void fft_stage(const float2* S, float2* D, int t) {
  constexpr int NR = NN / R;
#pragma unroll
  for (int rep = 0; rep < (NR + 63) / 64; ++rep) {
    int j = t + rep * 64;
    if (j < NR) {
      float2 v[R];
#pragma unroll
      for (int r = 0; r < R; ++r) v[r] = S[LID(j + r * NR)];
      if constexpr (NS > 1) {
        float ang = (float)DIR * (TWOPI_F / (float)(NS * R)) * (float)(j % NS);
        float sv, cv;
        __sincosf(ang, &sv, &cv);
        float2 w = make_float2(cv, sv);
        float2 wr = w;
#pragma unroll
        for (int r = 1; r < R; ++r) { v[r] = cmulf(v[r], wr); wr = cmulf(wr, w); }
      }
      if constexpr (R == 4) dft4<DIR>(v); else dft6<DIR>(v);
      int base = (j / NS) * (NS * R) + (j % NS);
#pragma unroll
      for (int r = 0; r < R; ++r) D[LID(base + r * NS)] = v[r];
    }
  }
}

template<int DIR>
__device__ __forceinline__ void fft384(float2* A, float2* Bf, int t) {
  fft_stage<4, 1,  DIR>(A,  Bf, t); __syncthreads();
  fft_stage<4, 4,  DIR>(Bf, A,  t); __syncthreads();
  fft_stage<4, 16, DIR>(A,  Bf, t); __syncthreads();
  fft_stage<6, 64, DIR>(Bf, A,  t); __syncthreads();
}

// ---------------- E: iteration 1 (y0 = 0 -> xn = cz), elementwise ----------
__global__ __launch_bounds__(256) void k_e(const float2* __restrict__ czb,
                                           float2* __restrict__ xbuf,
                                           float2* __restrict__ ybuf) {
  long i = (long)blockIdx.x * 256 + threadIdx.x;
  float2 cz = czb[i];
  float2 x = make_float2(fmaxf(cz.x, 0.f), fmaxf(cz.y, 0.f));
  xbuf[i] = x;
  ybuf[i] = x;   // t1 = 1 -> y1 = x1
}

// ---------------- P1: row FFT of coil*y -> W1 (permuted-x storage) ---------
// grid B*C*384/4, 256 thr; one wave per row; no LDS, no barriers.
__global__ __launch_bounds__(256) void k_p1(const float2* __restrict__ ybuf,
                                            const float* __restrict__ csm,
                                            float2* __restrict__ W1) {
  int t = threadIdx.x & 63;
  int w = threadIdx.x >> 6;
  long gl = (long)blockIdx.x * 4 + w;       // (b*C + c)*384 + y
  int y = (int)(gl % NN);
  long bc = gl / NN;
  long b = bc >> 4, c = bc & 15;
  long rowoff = (long)y * NN;
  float tc, ts; __sincosf((float)(t & 31) * (PI_F / 32.0f), &ts, &tc);
  float tsf = -ts;                           // fwd (SIGN=-1) pre-signed
  float2 w0; __sincosf(-(float)t * (TWOPI_F / 384.0f), &w0.y, &w0.x);
  float2 wf[5];
  wf[0] = w0;
#pragma unroll
  for (int r = 1; r < 5; ++r) wf[r] = cmulf(wf[r - 1], w0);
  const float2* yrow = ybuf + b * (long)(NN * NN) + rowoff;
  const float* crow_re = csm + (b * 2 * CC + c) * (long)(NN * NN) + rowoff;
  const float* crow_im = crow_re + (long)CC * NN * NN;
  float2 v[6];
#pragma unroll
  for (int k = 0; k < 6; ++k) {
    int x = t + 64 * k;
    float2 yv = yrow[x];
    float cre = crow_re[x], cim = crow_im[x];
    v[k] = make_float2(yv.x * cre - yv.y * cim, yv.x * cim + yv.y * cre);
  }
  fwd384t<-1>(v, t, tc, tsf, wf);
  float2* orow = W1 + gl * NN;
#pragma unroll
  for (int r = 0; r < 6; ++r) orow[t + 64 * r] = v[r];
}

// ---------------- P2: col FFT -> mask -> col IFFT, in-place on W1 ----------
// grid B*C*(N/8)=3072 blocks, 256 thr. 8-col planar tile, pad 392.
// float4 fill/drain; each wave runs cols {2w, 2w+1} interleaved through one
// FFT body. XCD-chunked swizzle (R6). 1/N folded into wb + sc0.
#define P2PAD 392
__global__ __launch_bounds__(256) void k_p2(float2* __restrict__ W1,
                                            const unsigned char* __restrict__ maskPT) {
  __shared__ float ldsR[8][P2PAD];
  __shared__ float ldsI[8][P2PAD];
  int tid = threadIdx.x;
  const int nwg = BB * CC * (NN / 8);            // 3072, divisible by 8
  int l = ((int)blockIdx.x & 7) * (nwg >> 3) + ((int)blockIdx.x >> 3);
  int xt = l % (NN / 8);
  long bc = l / (NN / 8);
  long b = bc >> 4;
  int s0 = xt * 8;
  long sbase = bc * (long)(NN * NN);
  int w = tid >> 6, t = tid & 63;
  // twiddle setup: table (pre-signed per direction) + outer chains
  float tc, ts; __sincosf((float)(t & 31) * (PI_F / 32.0f), &ts, &tc);
  float tsf = -ts;
  float2 w0; __sincosf(-(float)t * (TWOPI_F / 384.0f), &w0.y, &w0.x);
  float2 wf[5], wb[5];
  wf[0] = w0;
#pragma unroll
  for (int r = 1; r < 5; ++r) wf[r] = cmulf(wf[r - 1], w0);
  const float inv = 1.0f / NN;
#pragma unroll
  for (int r = 0; r < 5; ++r) wb[r] = make_float2(wf[r].x * inv, -wf[r].y * inv);
  // fill: float4 (2 complex) per op; 6 ops/thread
  const float4* W1v = (const float4*)W1;
  long f4base = (sbase >> 1) + (s0 >> 1);
#pragma unroll
  for (int k = 0; k < 6; ++k) {
    int e = tid + k * 256; int y = e >> 2; int q = e & 3;
    float4 val = W1v[f4base + (long)y * (NN / 2) + q];
    ldsR[2 * q][y] = val.x; ldsI[2 * q][y] = val.y;
    ldsR[2 * q + 1][y] = val.z; ldsI[2 * q + 1][y] = val.w;
  }
  __syncthreads();
  const unsigned char* mb = maskPT + b * (long)(NN * NN);
  {
    int c0 = 2 * w, c1 = 2 * w + 1;
    float2 u[6], v[6];
#pragma unroll
    for (int k = 0; k < 6; ++k) {
      u[k] = make_float2(ldsR[c0][t + 64 * k], ldsI[c0][t + 64 * k]);
      v[k] = make_float2(ldsR[c1][t + 64 * k], ldsI[c1][t + 64 * k]);
    }
    fwd384t2<-1>(u, v, t, tc, tsf, wf);
    const unsigned char* m0 = mb + (long)(s0 + c0) * NN;
    const unsigned char* m1 = mb + (long)(s0 + c1) * NN;
#pragma unroll
    for (int r = 0; r < 6; ++r) {
      float mv0 = (float)m0[t + 64 * r];
      float mv1 = (float)m1[t + 64 * r];
      u[r].x *= mv0; u[r].y *= mv0;
      v[r].x *= mv1; v[r].y *= mv1;
    }
    bwd384t2<1>(u, v, t, tc, ts, wb, inv);
#pragma unroll
    for (int k = 0; k < 6; ++k) {
      ldsR[c0][t + 64 * k] = u[k].x;
      ldsI[c0][t + 64 * k] = u[k].y;
      ldsR[c1][t + 64 * k] = v[k].x;
      ldsI[c1][t + 64 * k] = v[k].y;
    }
  }
  __syncthreads();
  float4* W1o = (float4*)W1;
#pragma unroll
  for (int k = 0; k < 6; ++k) {
    int e = tid + k * 256; int y = e >> 2; int q = e & 3;
    float4 val;
    val.x = ldsR[2 * q][y]; val.y = ldsI[2 * q][y];
    val.z = ldsR[2 * q + 1][y]; val.w = ldsI[2 * q + 1][y];
    W1o[f4base + (long)y * (NN / 2) + q] = val;
  }
}

// ---------------- P3: row IFFT + conj(coil) reduce + FISTA update ----------
// grid B*384 blocks, 256 thr; wave w handles coils 4w..4w+3 (2 at a time);
// LDS reduce. Update: x = prox((1-lam)(y - Q) + cz); zk not touched.
// last!=0: write planar output instead of x/y (final iteration).
__global__ __launch_bounds__(256) void k_p3(const float2* __restrict__ W1,
                                            const float* __restrict__ csm,
                                            const float2* __restrict__ czb,
                                            const float* __restrict__ lamp,
                                            float2* __restrict__ xbuf,
                                            float2* __restrict__ ybuf,
                                            float* __restrict__ outp,
                                            float beta, int last) {
  __shared__ float2 part[4][NN];
  int tid = threadIdx.x;
  int w = tid >> 6, t = tid & 63;
  long gl = blockIdx.x;            // b*384 + y
  long b = gl / NN;
  int y = (int)(gl % NN);
  long rowoff = (long)y * NN;
  float tc, ts; __sincosf((float)(t & 31) * (PI_F / 32.0f), &ts, &tc);
  float2 w0; __sincosf((float)t * (TWOPI_F / 384.0f), &w0.y, &w0.x);
  float2 wb[5];
  wb[0] = w0;
#pragma unroll
  for (int r = 1; r < 5; ++r) wb[r] = cmulf(wb[r - 1], w0);
  float2 acc[6];
#pragma unroll
  for (int k = 0; k < 6; ++k) acc[k] = make_float2(0.f, 0.f);
#pragma unroll
  for (int ci = 0; ci < 4; ci += 2) {
    int c0 = w * 4 + ci, c1 = c0 + 1;
    const float2* row0 = W1 + ((b * CC + c0) * (long)NN + y) * NN;
    const float2* row1 = W1 + ((b * CC + c1) * (long)NN + y) * NN;
    float2 u[6], v[6];
#pragma unroll
    for (int r = 0; r < 6; ++r) { u[r] = row0[t + 64 * r]; v[r] = row1[t + 64 * r]; }
    bwd384t2<1>(u, v, t, tc, ts, wb, 1.0f);
    const float* cre0 = csm + (b * 2 * CC + c0) * (long)(NN * NN) + rowoff;
    const float* cim0 = cre0 + (long)CC * NN * NN;
    const float* cre1 = csm + (b * 2 * CC + c1) * (long)(NN * NN) + rowoff;
    const float* cim1 = cre1 + (long)CC * NN * NN;
#pragma unroll
    for (int k = 0; k < 6; ++k) {
      int x = t + 64 * k;
      float a0 = cre0[x], b0 = cim0[x];
      float a1 = cre1[x], b1 = cim1[x];
      acc[k].x += (a0 * u[k].x + b0 * u[k].y) + (a1 * v[k].x + b1 * v[k].y);
      acc[k].y += (a0 * u[k].y - b0 * u[k].x) + (a1 * v[k].y - b1 * v[k].x);
    }
  }
#pragma unroll
  for (int k = 0; k < 6; ++k) part[w][t + 64 * k] = acc[k];
  __syncthreads();
  float lamv = lamp[0];
  float oml = 1.0f - lamv;
  long pbase = b * (long)(NN * NN) + rowoff;
  for (int e = tid; e < NN; e += 256) {
    float Qx = (part[0][e].x + part[1][e].x + part[2][e].x + part[3][e].x) * (1.0f / NN);
    float Qy = (part[0][e].y + part[1][e].y + part[2][e].y + part[3][e].y) * (1.0f / NN);
    float2 yv = ybuf[pbase + e];
    float2 cz = czb[pbase + e];
    float xr = oml * (yv.x - Qx) + cz.x;
    float xi = oml * (yv.y - Qy) + cz.y;
    xr = fmaxf(xr, 0.f);
    xi = fmaxf(xi, 0.f);
    if (last) {
      outp[(b * 2 + 0) * (long)(NN * NN) + rowoff + e] = xr;
      outp[(b * 2 + 1) * (long)(NN * NN) + rowoff + e] = xi;
    } else {
      float2 xo = xbuf[pbase + e];
      xbuf[pbase + e] = make_float2(xr, xi);
      ybuf[pbase + e] = make_float2(xr + beta * (xr - xo.x), xi + beta * (xi - xo.y));
    }
  }
}

// ---------------- mask permutation precompute (one-time) -------------------
// maskPT[b][sx][sy] = mask[b][P(sy)][P(sx)], P(s) = (s>>6) + 6*brev6(s&63)
__global__ __launch_bounds__(256) void k_mpre(const int* __restrict__ mask,
                                              unsigned char* __restrict__ maskPT) {
  long i = (long)blockIdx.x * 256 + threadIdx.x;
  long b = i / (NN * NN);
  int rem = (int)(i % (NN * NN));
  int sx = rem / NN, sy = rem % NN;
  int fx = (sx >> 6) + 6 * (int)(__brev((unsigned)(sx & 63)) >> 26);
  int fy = (sy >> 6) + 6 * (int)(__brev((unsigned)(sy & 63)) >> 26);
  maskPT[i] = (unsigned char)mask[b * (long)(NN * NN) + (long)fy * NN + fx];
}

// ---------------- precompute: cz = (1-lam)*cst + lam*z ---------------------
__global__ __launch_bounds__(256) void k_preA(const float* __restrict__ x0,
                                              const int* __restrict__ mask,
                                              float2* __restrict__ T) {
  __shared__ float2 U[4][LNPAD], V[4][LNPAD];
  int tid = threadIdx.x;
  int line = tid >> 6, t = tid & 63;
  long gl0 = (long)blockIdx.x * 4;
#pragma unroll
  for (int k = 0; k < 6; ++k) {
    int e = tid + k * 256; int l = e / NN; int x = e % NN;
    long gl = gl0 + l;
    long b = gl / NN;
    int y = (int)(gl % NN);
    long pidx = (long)y * NN + x;
    float mv = (float)mask[b * (long)(NN * NN) + pidx];
    float br = x0[(b * 2 + 0) * (long)(NN * NN) + pidx] * mv;
    float bi = x0[(b * 2 + 1) * (long)(NN * NN) + pidx] * mv;
    U[l][LID(x)] = make_float2(br, bi);
  }
  __syncthreads();
  fft384<1>(U[line], V[line], t);
#pragma unroll
  for (int k = 0; k < 6; ++k) {
    int e = tid + k * 256; int l = e / NN; int x = e % NN;
    float2 u = U[l][LID(x)];
    T[(gl0 + l) * NN + x] = make_float2(u.x * (1.0f / NN), u.y * (1.0f / NN));
  }
}

__global__ __launch_bounds__(256) void k_preB(const float2* __restrict__ T,
                                              float2* __restrict__ r0) {
  __shared__ float2 tile[NN][17];
  __shared__ float2 U[4][LNPAD], V[4][LNPAD];
  int tid = threadIdx.x;
  int xt = blockIdx.x % (NN / 16);
  long b = blockIdx.x / (NN / 16);
  int x0c = xt * 16;
  long sbase = b * (long)(NN * NN);
#pragma unroll
  for (int k = 0; k < 24; ++k) {
    int e = tid + k * 256; int y = e >> 4; int c = e & 15;
    tile[y][c] = T[sbase + (long)y * NN + x0c + c];
  }
  __syncthreads();
  int line = tid >> 6, t = tid & 63;
  for (int g = 0; g < 4; ++g) {
#pragma unroll
    for (int k = 0; k < 6; ++k) {
      int e = tid + k * 256; int l = e / NN; int y = e % NN;
      U[l][LID(y)] = tile[y][4 * g + l];
    }
    __syncthreads();
    fft384<1>(U[line], V[line], t);
#pragma unroll
    for (int k = 0; k < 6; ++k) {
      int e = tid + k * 256; int l = e / NN; int y = e % NN;
      float2 u = U[l][LID(y)];
      tile[y][4 * g + l] = make_float2(u.x * (1.0f / NN), u.y * (1.0f / NN));
    }
    __syncthreads();
  }
#pragma unroll
  for (int k = 0; k < 24; ++k) {
    int e = tid + k * 256; int y = e >> 4; int c = e & 15;
    r0[sbase + (long)y * NN + x0c + c] = tile[y][c];
  }
}

__global__ __launch_bounds__(256) void k_preC(const float* __restrict__ csm,
                                              const float2* __restrict__ r0,
                                              const float* __restrict__ zk,
                                              const float* __restrict__ lamp,
                                              float2* __restrict__ czb) {
  long i = (long)blockIdx.x * 256 + threadIdx.x;
  long b = i / (NN * NN);
  long p = i % (NN * NN);
  float sr = 0.f, si = 0.f;
#pragma unroll
  for (int c = 0; c < CC; ++c) {
    sr += csm[(b * 2 * CC + c) * (long)(NN * NN) + p];
    si -= csm[((b * 2 + 1) * CC + c) * (long)(NN * NN) + p];
  }
  float2 r = r0[i];
  float cstx = sr * r.x - si * r.y;
  float csty = sr * r.y + si * r.x;
  float lamv = lamp[0];
  float oml = 1.0f - lamv;
  float zr = zk[(b * 2 + 0) * (long)(NN * NN) + p];
  float zi = zk[(b * 2 + 1) * (long)(NN * NN) + p];
  czb[i] = make_float2(oml * cstx + lamv * zr, oml * csty + lamv * zi);
}

extern "C" void kernel_launch(void* const* d_in, const int* in_sizes, int n_in,
                              void* d_out, int out_size, void* d_ws, size_t ws_size,
                              hipStream_t stream) {
  const float* zk  = (const float*)d_in[0];
  const float* x0  = (const float*)d_in[1];
  const float* csm = (const float*)d_in[2];
  const float* lam = (const float*)d_in[3];
  const int*   msk = (const int*)d_in[4];
  float* out = (float*)d_out;

  // ws layout (float2 units): W1 [B*C*N*N] | y | x | cz | maskPT(uchar)
  size_t img = (size_t)BB * NN * NN;
  float2* W1   = (float2*)d_ws;
  float2* ybuf = W1 + (size_t)BB * CC * NN * NN;
  float2* xbuf = ybuf + img;
  float2* czb  = xbuf + img;
  unsigned char* maskPT = (unsigned char*)(czb + img);
  float2* T  = W1;        // precompute scratch overlays W1
  float2* r0 = W1 + img;

  double tcur = 1.0;
  float betas[NITER];
  for (int i = 0; i < NITER; ++i) {
    double tn = (1.0 + sqrt(1.0 + 4.0 * tcur * tcur)) * 0.5;
    betas[i] = (float)((tcur - 1.0) / tn);
    tcur = tn;
  }

  k_mpre<<<(BB * NN * NN) / 256, 256, 0, stream>>>(msk, maskPT);
  k_preA<<<BB * NN / 4, 256, 0, stream>>>(x0, msk, T);
  k_preB<<<BB * (NN / 16), 256, 0, stream>>>(T, r0);
  k_preC<<<(BB * NN * NN) / 256, 256, 0, stream>>>(csm, r0, zk, lam, czb);
  // iteration 1 (y0 = 0): x1 = prox(cz)
  k_e<<<(BB * NN * NN) / 256, 256, 0, stream>>>(czb, xbuf, ybuf);
  // iterations 2..20: forward, mask round-trip, adjoint+update
  for (int i = 1; i < NITER; ++i) {
    k_p1<<<BB * CC * NN / 4, 256, 0, stream>>>(ybuf, csm, W1);
    k_p2<<<BB * CC * (NN / 8), 256, 0, stream>>>(W1, maskPT);
    k_p3<<<BB * NN, 256, 0, stream>>>(W1, csm, czb, lam, xbuf, ybuf, out,
                                      betas[i], (i == NITER - 1) ? 1 : 0);
  }
}

// Round 13
// 2150.781 us; speedup vs baseline: 1.2544x; 1.0334x over previous
//
#include <hip/hip_runtime.h>
#include <math.h>

// FISTA data-consistency with masked multi-coil 2D FFT operator.
// B=4, C=16, H=W=384.
// Register FFT: 384 = 6 (regs) x 64 (lanes); DIF leaves bit-reversed-permuted
// frequencies; mask is pre-permuted; DIT consumes permuted order (free).
// Twiddles: 32-entry register table (1 sincosf/kernel) via __shfl, PRE-SIGNED.
// Exchanges: h=1,2 DPP quad_perm; h=4,8 __shfl_xor; h=16/32 permlane_swap+XOR.
// Butterflies (R13): fma/fold form — per stage hoist s=hi?-1:1 and
// tw'=(hi?cs:1, hi?sn:0); dif: v'=cmul(fma(s,v,o), tw'); dit:
// bt=cmul(v,tw'); v'=fma(s,bt,exch(bt)). Lo-lane cmul by (1,0) is exact ->
// bit-identical results, ~30% fewer VALU ops (p2 was 80% VALUBusy).
// zk folded out: cz = (1-lam)cst + lam*z; 1/N folded into wb chain.
// R3: don't fuse p3+p1. R4: XCD swizzle. R7: LDS-pipe bound (fixed R10/R12).
// R8: fp16 W1 FAILS (range). R9: inline-asm permlane broke; builtins only.
// R11: XOR-recovery keeps VGPR 44 (direct selector -> 56, occ loss).

#define NN 384
#define BB 4
#define CC 16
#define NITER 20
#define LNPAD 432   // old LDS path (precompute only)
#define PI_F 3.14159265358979323846f
#define TWOPI_F 6.28318530717958647692f

__device__ __forceinline__ int LID(int i) { return i + (i >> 3); }

__device__ __forceinline__ float2 cmulf(float2 a, float2 b) {
  return make_float2(a.x * b.x - a.y * b.y, a.x * b.y + a.y * b.x);
}

// ---------------- cross-lane exchange primitives ---------------------------
typedef unsigned int uint2v __attribute__((ext_vector_type(2)));

__device__ __forceinline__ float xswap32(float v) {
  unsigned s = __float_as_uint(v);
  uint2v r = __builtin_amdgcn_permlane32_swap(s, s, false, false);
  return __uint_as_float(r[0] ^ r[1] ^ s);
}
__device__ __forceinline__ float xswap16(float v) {
  unsigned s = __float_as_uint(v);
  uint2v r = __builtin_amdgcn_permlane16_swap(s, s, false, false);
  return __uint_as_float(r[0] ^ r[1] ^ s);
}
template<int CTRL>
__device__ __forceinline__ float dppx(float v) {
  int s = __float_as_int(v);
  return __int_as_float(__builtin_amdgcn_update_dpp(s, s, CTRL, 0xF, 0xF, true));
}

template<int H>
__device__ __forceinline__ float2 exch(float2 v) {
  if constexpr (H == 1) {
    return make_float2(dppx<0xB1>(v.x), dppx<0xB1>(v.y));
  } else if constexpr (H == 2) {
    return make_float2(dppx<0x4E>(v.x), dppx<0x4E>(v.y));
  } else if constexpr (H == 16) {
    return make_float2(xswap16(v.x), xswap16(v.y));
  } else if constexpr (H == 32) {
    return make_float2(xswap32(v.x), xswap32(v.y));
  } else {
    return make_float2(__shfl_xor(v.x, H), __shfl_xor(v.y, H));
  }
}

template<int DIR>
__device__ __forceinline__ void dft4(float2* v) {
  float ax = v[0].x + v[2].x, ay = v[0].y + v[2].y;
  float bx = v[0].x - v[2].x, by = v[0].y - v[2].y;
  float cx = v[1].x + v[3].x, cy = v[1].y + v[3].y;
  float dx = v[1].x - v[3].x, dy = v[1].y - v[3].y;
  float dix, diy;
  if (DIR < 0) { dix = dy; diy = -dx; }
  else         { dix = -dy; diy = dx; }
  v[0] = make_float2(ax + cx, ay + cy);
  v[2] = make_float2(ax - cx, ay - cy);
  v[1] = make_float2(bx + dix, by + diy);
  v[3] = make_float2(bx - dix, by - diy);
}

// DFT-3: X1 = m + i*s*S3*d, X2 = m - i*s*S3*d; m = a - u/2, u=b+c, d=b-c.
template<int SIGN>
__device__ __forceinline__ void dft3(float2 a, float2 b, float2 c,
                                     float2& X0, float2& X1, float2& X2) {
  const float S3 = 0.86602540378443864676f;
  float ux = b.x + c.x, uy = b.y + c.y;
  float dx = b.x - c.x, dy = b.y - c.y;
  float mx = a.x - 0.5f * ux, my = a.y - 0.5f * uy;
  float ex = S3 * dx, ey = S3 * dy;
  X0 = make_float2(a.x + ux, a.y + uy);
  if (SIGN < 0) {
    X1 = make_float2(mx + ey, my - ex);
    X2 = make_float2(mx - ey, my + ex);
  } else {
    X1 = make_float2(mx - ey, my + ex);
    X2 = make_float2(mx + ey, my - ex);
  }
}

// Fast DFT-6 = two DFT-3 + trivial W6 twiddles. Verified on impulses.
template<int SIGN>
__device__ __forceinline__ void dft6(float2* v) {
  const float S3 = 0.86602540378443864676f;
  float2 E0, E1, E2, O0, O1, O2;
  dft3<SIGN>(v[0], v[2], v[4], E0, E1, E2);
  dft3<SIGN>(v[1], v[3], v[5], O0, O1, O2);
  const float ss = (SIGN < 0) ? -S3 : S3;
  float2 T1 = cmulf(O1, make_float2(0.5f, ss));
  float2 T2 = cmulf(O2, make_float2(-0.5f, ss));
  v[0] = make_float2(E0.x + O0.x, E0.y + O0.y);
  v[1] = make_float2(E1.x + T1.x, E1.y + T1.y);
  v[2] = make_float2(E2.x + T2.x, E2.y + T2.y);
  v[3] = make_float2(E0.x - O0.x, E0.y - O0.y);
  v[4] = make_float2(E1.x - T1.x, E1.y - T1.y);
  v[5] = make_float2(E2.x - T2.x, E2.y - T2.y);
}

// ---------------- register FFT machinery (iteration path) ------------------
// fma/fold butterflies. Per stage (lane-hoisted): s = hi?-1:1,
// (csl,snl) = hi?(cs,sn):(1,0). Lo-lane cmul by (1,0) is exact.

// dif: o = exch(v); d = fma(s,v,o); v' = cmul(d, tw')
template<int H>
__device__ __forceinline__ void dif_step1(float2 v[6], float s, float csl, float snl) {
#pragma unroll
  for (int r = 0; r < 6; ++r) {
    float2 o = exch<H>(v[r]);
    float dx = fmaf(s, v[r].x, o.x);
    float dy = fmaf(s, v[r].y, o.y);
    v[r] = make_float2(dx * csl - dy * snl, dx * snl + dy * csl);
  }
}
template<int H>
__device__ __forceinline__ void dif_step1_notw(float2 v[6], float s) {
#pragma unroll
  for (int r = 0; r < 6; ++r) {
    float2 o = exch<H>(v[r]);
    v[r] = make_float2(fmaf(s, v[r].x, o.x), fmaf(s, v[r].y, o.y));
  }
}
template<int H>
__device__ __forceinline__ void dif_step2(float2 u[6], float2 v[6],
                                          float s, float csl, float snl) {
#pragma unroll
  for (int r = 0; r < 6; ++r) {
    float2 ou = exch<H>(u[r]);
    float2 ov = exch<H>(v[r]);
    float dux = fmaf(s, u[r].x, ou.x), duy = fmaf(s, u[r].y, ou.y);
    float dvx = fmaf(s, v[r].x, ov.x), dvy = fmaf(s, v[r].y, ov.y);
    u[r] = make_float2(dux * csl - duy * snl, dux * snl + duy * csl);
    v[r] = make_float2(dvx * csl - dvy * snl, dvx * snl + dvy * csl);
  }
}
template<int H>
__device__ __forceinline__ void dif_step2_notw(float2 u[6], float2 v[6], float s) {
#pragma unroll
  for (int r = 0; r < 6; ++r) {
    float2 ou = exch<H>(u[r]);
    float2 ov = exch<H>(v[r]);
    u[r] = make_float2(fmaf(s, u[r].x, ou.x), fmaf(s, u[r].y, ou.y));
    v[r] = make_float2(fmaf(s, v[r].x, ov.x), fmaf(s, v[r].y, ov.y));
  }
}

// dit: bt = cmul(v, tw'); v' = fma(s, bt, exch(bt))
template<int H>
__device__ __forceinline__ void dit_step2(float2 u[6], float2 v[6],
                                          float s, float csl, float snl) {
#pragma unroll
  for (int r = 0; r < 6; ++r) {
    float2 bu = make_float2(u[r].x * csl - u[r].y * snl, u[r].x * snl + u[r].y * csl);
    float2 bv = make_float2(v[r].x * csl - v[r].y * snl, v[r].x * snl + v[r].y * csl);
    float2 ou = exch<H>(bu);
    float2 ov = exch<H>(bv);
    u[r] = make_float2(fmaf(s, bu.x, ou.x), fmaf(s, bu.y, ou.y));
    v[r] = make_float2(fmaf(s, bv.x, ov.x), fmaf(s, bv.y, ov.y));
  }
}
template<int H>
__device__ __forceinline__ void dit_step2_notw(float2 u[6], float2 v[6], float s) {
#pragma unroll
  for (int r = 0; r < 6; ++r) {
    float2 ou = exch<H>(u[r]);
    float2 ov = exch<H>(v[r]);
    u[r] = make_float2(fmaf(s, u[r].x, ou.x), fmaf(s, u[r].y, ou.y));
    v[r] = make_float2(fmaf(s, v[r].x, ov.x), fmaf(s, v[r].y, ov.y));
  }
}

// radix-2 DIF FFT-64, TWO columns interleaved. tss pre-signed.
template<int SIGN>
__device__ __forceinline__ void dif64t2(float2 u[6], float2 v[6], int t,
                                        float tc, float tss) {
  { int j = t & 31; bool hi = (t & 32) != 0;                  // h=32 (permlane)
    float cs = __shfl(tc, j), sn = __shfl(tss, j);
    float s = hi ? -1.f : 1.f, csl = hi ? cs : 1.f, snl = hi ? sn : 0.f;
    dif_step2<32>(u, v, s, csl, snl); }
  { int j = (t & 15) << 1; bool hi = (t & 16) != 0;           // h=16 (permlane)
    float cs = __shfl(tc, j), sn = __shfl(tss, j);
    float s = hi ? -1.f : 1.f, csl = hi ? cs : 1.f, snl = hi ? sn : 0.f;
    dif_step2<16>(u, v, s, csl, snl); }
  { int j = (t & 7) << 2; bool hi = (t & 8) != 0;             // h=8
    float cs = __shfl(tc, j), sn = __shfl(tss, j);
    float s = hi ? -1.f : 1.f, csl = hi ? cs : 1.f, snl = hi ? sn : 0.f;
    dif_step2<8>(u, v, s, csl, snl); }
  { int j = (t & 3) << 3; bool hi = (t & 4) != 0;             // h=4
    float cs = __shfl(tc, j), sn = __shfl(tss, j);
    float s = hi ? -1.f : 1.f, csl = hi ? cs : 1.f, snl = hi ? sn : 0.f;
    dif_step2<4>(u, v, s, csl, snl); }
  { bool hi = (t & 2) != 0, iq = (t & 1) != 0;                // h=2 (DPP)
    float s = hi ? -1.f : 1.f;
    float c2 = (hi && iq) ? 0.f : 1.f;
    float s2 = (hi && iq) ? (float)SIGN : 0.f;
    dif_step2<2>(u, v, s, c2, s2); }
  { bool hi = (t & 1) != 0;                                   // h=1 (DPP, tw=1)
    float s = hi ? -1.f : 1.f;
    dif_step2_notw<1>(u, v, s); }
}

// single-column variant (p1)
template<int SIGN>
__device__ __forceinline__ void dif64t(float2 v[6], int t, float tc, float tss) {
  { int j = t & 31; bool hi = (t & 32) != 0;
    float cs = __shfl(tc, j), sn = __shfl(tss, j);
    float s = hi ? -1.f : 1.f, csl = hi ? cs : 1.f, snl = hi ? sn : 0.f;
    dif_step1<32>(v, s, csl, snl); }
  { int j = (t & 15) << 1; bool hi = (t & 16) != 0;
    float cs = __shfl(tc, j), sn = __shfl(tss, j);
    float s = hi ? -1.f : 1.f, csl = hi ? cs : 1.f, snl = hi ? sn : 0.f;
    dif_step1<16>(v, s, csl, snl); }
  { int j = (t & 7) << 2; bool hi = (t & 8) != 0;
    float cs = __shfl(tc, j), sn = __shfl(tss, j);
    float s = hi ? -1.f : 1.f, csl = hi ? cs : 1.f, snl = hi ? sn : 0.f;
    dif_step1<8>(v, s, csl, snl); }
  { int j = (t & 3) << 3; bool hi = (t & 4) != 0;
    float cs = __shfl(tc, j), sn = __shfl(tss, j);
    float s = hi ? -1.f : 1.f, csl = hi ? cs : 1.f, snl = hi ? sn : 0.f;
    dif_step1<4>(v, s, csl, snl); }
  { bool hi = (t & 2) != 0, iq = (t & 1) != 0;
    float s = hi ? -1.f : 1.f;
    float c2 = (hi && iq) ? 0.f : 1.f;
    float s2 = (hi && iq) ? (float)SIGN : 0.f;
    dif_step1<2>(v, s, c2, s2); }
  { bool hi = (t & 1) != 0;
    float s = hi ? -1.f : 1.f;
    dif_step1_notw<1>(v, s); }
}

// radix-2 DIT FFT-64, TWO columns interleaved. tss pre-signed.
template<int SIGN>
__device__ __forceinline__ void dit64t2(float2 u[6], float2 v[6], int t,
                                        float tc, float tss) {
  { bool hi = (t & 1) != 0;                                   // h=1 (DPP, tw=1)
    float s = hi ? -1.f : 1.f;
    dit_step2_notw<1>(u, v, s); }
  { bool hi = (t & 2) != 0, iq = (t & 1) != 0;                // h=2 (DPP)
    float s = hi ? -1.f : 1.f;
    float c2 = (hi && iq) ? 0.f : 1.f;
    float s2 = (hi && iq) ? (float)SIGN : 0.f;
    dit_step2<2>(u, v, s, c2, s2); }
  { int j = (t & 3) << 3; bool hi = (t & 4) != 0;             // h=4
    float cs = __shfl(tc, j), sn = __shfl(tss, j);
    float s = hi ? -1.f : 1.f, csl = hi ? cs : 1.f, snl = hi ? sn : 0.f;
    dit_step2<4>(u, v, s, csl, snl); }
  { int j = (t & 7) << 2; bool hi = (t & 8) != 0;             // h=8
    float cs = __shfl(tc, j), sn = __shfl(tss, j);
    float s = hi ? -1.f : 1.f, csl = hi ? cs : 1.f, snl = hi ? sn : 0.f;
    dit_step2<8>(u, v, s, csl, snl); }
  { int j = (t & 15) << 1; bool hi = (t & 16) != 0;           // h=16 (permlane)
    float cs = __shfl(tc, j), sn = __shfl(tss, j);
    float s = hi ? -1.f : 1.f, csl = hi ? cs : 1.f, snl = hi ? sn : 0.f;
    dit_step2<16>(u, v, s, csl, snl); }
  { int j = t & 31; bool hi = (t & 32) != 0;                  // h=32 (permlane)
    float cs = __shfl(tc, j), sn = __shfl(tss, j);
    float s = hi ? -1.f : 1.f, csl = hi ? cs : 1.f, snl = hi ? sn : 0.f;
    dit_step2<32>(u, v, s, csl, snl); }
}

// FWD single: natural in -> permuted out. w[r-1] = exp(SIGN*2pi*i*r*t/384).
template<int SIGN>
__device__ __forceinline__ void fwd384t(float2 v[6], int t, float tc, float tss,
                                        const float2 w[5]) {
  dft6<SIGN>(v);
#pragma unroll
  for (int r = 1; r < 6; ++r) v[r] = cmulf(v[r], w[r - 1]);
  dif64t<SIGN>(v, t, tc, tss);
}

// FWD dual
template<int SIGN>
__device__ __forceinline__ void fwd384t2(float2 u[6], float2 v[6], int t,
                                         float tc, float tss, const float2 w[5]) {
  dft6<SIGN>(u);
  dft6<SIGN>(v);
#pragma unroll
  for (int r = 1; r < 6; ++r) { u[r] = cmulf(u[r], w[r - 1]); v[r] = cmulf(v[r], w[r - 1]); }
  dif64t2<SIGN>(u, v, t, tc, tss);
}

// BWD dual: permuted in -> natural out. w may carry an extra uniform scale;
// sc0 applies the same scale to the r=0 (untwiddled) term.
template<int SIGN>
__device__ __forceinline__ void bwd384t2(float2 u[6], float2 v[6], int t,
                                         float tc, float tss, const float2 w[5],
                                         float sc0) {
  dit64t2<SIGN>(u, v, t, tc, tss);
  u[0].x *= sc0; u[0].y *= sc0;
  v[0].x *= sc0; v[0].y *= sc0;
#pragma unroll
  for (int r = 1; r < 6; ++r) { u[r] = cmulf(u[r], w[r - 1]); v[r] = cmulf(v[r], w[r - 1]); }
  dft6<SIGN>(u);
  dft6<SIGN>(v);
}

// ---------------- old LDS fft384 (precompute kernels only) -----------------
template<int R, int NS, int DIR>
__device__ __forceinline__ void fft_stage(const float2* S, float2* D, int t) {
  constexpr int NR = NN / R;
#pragma unroll
  for (int rep = 0; rep < (NR + 63) / 64; ++rep) {
    int j = t + rep * 64;
    if (j < NR) {
      float2 v[R];
#pragma unroll
      for (int r = 0; r < R; ++r) v[r] = S[LID(j + r * NR)];
      if constexpr (NS > 1) {
        float ang = (float)DIR * (TWOPI_F / (float)(NS * R)) * (float)(j % NS);
        float sv, cv;
        __sincosf(ang, &sv, &cv);
        float2 w = make_float2(cv, sv);
        float2 wr = w;
#pragma unroll
        for (int r = 1; r < R; ++r) { v[r] = cmulf(v[r], wr); wr = cmulf(wr, w); }
      }
      if constexpr (R == 4) dft4<DIR>(v); else dft6<DIR>(v);
      int base = (j / NS) * (NS * R) + (j % NS);
#pragma unroll
      for (int r = 0; r < R; ++r) D[LID(base + r * NS)] = v[r];
    }
  }
}

template<int DIR>
__device__ __forceinline__ void fft384(float2* A, float2* Bf, int t) {
  fft_stage<4, 1,  DIR>(A,  Bf, t); __syncthreads();
  fft_stage<4, 4,  DIR>(Bf, A,  t); __syncthreads();
  fft_stage<4, 16, DIR>(A,  Bf, t); __syncthreads();
  fft_stage<6, 64, DIR>(Bf, A,  t); __syncthreads();
}

// ---------------- E: iteration 1 (y0 = 0 -> xn = cz), elementwise ----------
__global__ __launch_bounds__(256) void k_e(const float2* __restrict__ czb,
                                           float2* __restrict__ xbuf,
                                           float2* __restrict__ ybuf) {
  long i = (long)blockIdx.x * 256 + threadIdx.x;
  float2 cz = czb[i];
  float2 x = make_float2(fmaxf(cz.x, 0.f), fmaxf(cz.y, 0.f));
  xbuf[i] = x;
  ybuf[i] = x;   // t1 = 1 -> y1 = x1
}

// ---------------- P1: row FFT of coil*y -> W1 (permuted-x storage) ---------
// grid B*C*384/4, 256 thr; one wave per row; no LDS, no barriers.
__global__ __launch_bounds__(256) void k_p1(const float2* __restrict__ ybuf,
                                            const float* __restrict__ csm,
                                            float2* __restrict__ W1) {
  int t = threadIdx.x & 63;
  int w = threadIdx.x >> 6;
  long gl = (long)blockIdx.x * 4 + w;       // (b*C + c)*384 + y
  int y = (int)(gl % NN);
  long bc = gl / NN;
  long b = bc >> 4, c = bc & 15;
  long rowoff = (long)y * NN;
  float tc, ts; __sincosf((float)(t & 31) * (PI_F / 32.0f), &ts, &tc);
  float tsf = -ts;                           // fwd (SIGN=-1) pre-signed
  float2 w0; __sincosf(-(float)t * (TWOPI_F / 384.0f), &w0.y, &w0.x);
  float2 wf[5];
  wf[0] = w0;
#pragma unroll
  for (int r = 1; r < 5; ++r) wf[r] = cmulf(wf[r - 1], w0);
  const float2* yrow = ybuf + b * (long)(NN * NN) + rowoff;
  const float* crow_re = csm + (b * 2 * CC + c) * (long)(NN * NN) + rowoff;
  const float* crow_im = crow_re + (long)CC * NN * NN;
  float2 v[6];
#pragma unroll
  for (int k = 0; k < 6; ++k) {
    int x = t + 64 * k;
    float2 yv = yrow[x];
    float cre = crow_re[x], cim = crow_im[x];
    v[k] = make_float2(yv.x * cre - yv.y * cim, yv.x * cim + yv.y * cre);
  }
  fwd384t<-1>(v, t, tc, tsf, wf);
  float2* orow = W1 + gl * NN;
#pragma unroll
  for (int r = 0; r < 6; ++r) orow[t + 64 * r] = v[r];
}

// ---------------- P2: col FFT -> mask -> col IFFT, in-place on W1 ----------
// grid B*C*(N/8)=3072 blocks, 256 thr. 8-col planar tile, pad 392.
// float4 fill/drain; each wave runs cols {2w, 2w+1} interleaved through one
// FFT body. XCD-chunked swizzle (R6). 1/N folded into wb + sc0.
#define P2PAD 392
__global__ __launch_bounds__(256) void k_p2(float2* __restrict__ W1,
                                            const unsigned char* __restrict__ maskPT) {
  __shared__ float ldsR[8][P2PAD];
  __shared__ float ldsI[8][P2PAD];
  int tid = threadIdx.x;
  const int nwg = BB * CC * (NN / 8);            // 3072, divisible by 8
  int l = ((int)blockIdx.x & 7) * (nwg >> 3) + ((int)blockIdx.x >> 3);
  int xt = l % (NN / 8);
  long bc = l / (NN / 8);
  long b = bc >> 4;
  int s0 = xt * 8;
  long sbase = bc * (long)(NN * NN);
  int w = tid >> 6, t = tid & 63;
  // twiddle setup: table (pre-signed per direction) + outer chains
  float tc, ts; __sincosf((float)(t & 31) * (PI_F / 32.0f), &ts, &tc);
  float tsf = -ts;
  float2 w0; __sincosf(-(float)t * (TWOPI_F / 384.0f), &w0.y, &w0.x);
  float2 wf[5], wb[5];
  wf[0] = w0;
#pragma unroll
  for (int r = 1; r < 5; ++r) wf[r] = cmulf(wf[r - 1], w0);
  const float inv = 1.0f / NN;
#pragma unroll
  for (int r = 0; r < 5; ++r) wb[r] = make_float2(wf[r].x * inv, -wf[r].y * inv);
  // fill: float4 (2 complex) per op; 6 ops/thread
  const float4* W1v = (const float4*)W1;
  long f4base = (sbase >> 1) + (s0 >> 1);
#pragma unroll
  for (int k = 0; k < 6; ++k) {
    int e = tid + k * 256; int y = e >> 2; int q = e & 3;
    float4 val = W1v[f4base + (long)y * (NN / 2) + q];
    ldsR[2 * q][y] = val.x; ldsI[2 * q][y] = val.y;
    ldsR[2 * q + 1][y] = val.z; ldsI[2 * q + 1][y] = val.w;
  }
  __syncthreads();
  const unsigned char* mb = maskPT + b * (long)(NN * NN);
  {
    int c0 = 2 * w, c1 = 2 * w + 1;
    float2 u[6], v[6];
#pragma unroll
    for (int k = 0; k < 6; ++k) {
      u[k] = make_float2(ldsR[c0][t + 64 * k], ldsI[c0][t + 64 * k]);
      v[k] = make_float2(ldsR[c1][t + 64 * k], ldsI[c1][t + 64 * k]);
    }
    fwd384t2<-1>(u, v, t, tc, tsf, wf);
    const unsigned char* m0 = mb + (long)(s0 + c0) * NN;
    const unsigned char* m1 = mb + (long)(s0 + c1) * NN;
#pragma unroll
    for (int r = 0; r < 6; ++r) {
      float mv0 = (float)m0[t + 64 * r];
      float mv1 = (float)m1[t + 64 * r];
      u[r].x *= mv0; u[r].y *= mv0;
      v[r].x *= mv1; v[r].y *= mv1;
    }
    bwd384t2<1>(u, v, t, tc, ts, wb, inv);
#pragma unroll
    for (int k = 0; k < 6; ++k) {
      ldsR[c0][t + 64 * k] = u[k].x;
      ldsI[c0][t + 64 * k] = u[k].y;
      ldsR[c1][t + 64 * k] = v[k].x;
      ldsI[c1][t + 64 * k] = v[k].y;
    }
  }
  __syncthreads();
  float4* W1o = (float4*)W1;
#pragma unroll
  for (int k = 0; k < 6; ++k) {
    int e = tid + k * 256; int y = e >> 2; int q = e & 3;
    float4 val;
    val.x = ldsR[2 * q][y]; val.y = ldsI[2 * q][y];
    val.z = ldsR[2 * q + 1][y]; val.w = ldsI[2 * q + 1][y];
    W1o[f4base + (long)y * (NN / 2) + q] = val;
  }
}

// ---------------- P3: row IFFT + conj(coil) reduce + FISTA update ----------
// grid B*384 blocks, 256 thr; wave w handles coils 4w..4w+3 (2 at a time);
// LDS reduce. Update: x = prox((1-lam)(y - Q) + cz); zk not touched.
// last!=0: write planar output instead of x/y (final iteration).
__global__ __launch_bounds__(256) void k_p3(const float2* __restrict__ W1,
                                            const float* __restrict__ csm,
                                            const float2* __restrict__ czb,
                                            const float* __restrict__ lamp,
                                            float2* __restrict__ xbuf,
                                            float2* __restrict__ ybuf,
                                            float* __restrict__ outp,
                                            float beta, int last) {
  __shared__ float2 part[4][NN];
  int tid = threadIdx.x;
  int w = tid >> 6, t = tid & 63;
  long gl = blockIdx.x;            // b*384 + y
  long b = gl / NN;
  int y = (int)(gl % NN);
  long rowoff = (long)y * NN;
  float tc, ts; __sincosf((float)(t & 31) * (PI_F / 32.0f), &ts, &tc);
  float2 w0; __sincosf((float)t * (TWOPI_F / 384.0f), &w0.y, &w0.x);
  float2 wb[5];
  wb[0] = w0;
#pragma unroll
  for (int r = 1; r < 5; ++r) wb[r] = cmulf(wb[r - 1], w0);
  float2 acc[6];
#pragma unroll
  for (int k = 0; k < 6; ++k) acc[k] = make_float2(0.f, 0.f);
#pragma unroll
  for (int ci = 0; ci < 4; ci += 2) {
    int c0 = w * 4 + ci, c1 = c0 + 1;
    const float2* row0 = W1 + ((b * CC + c0) * (long)NN + y) * NN;
    const float2* row1 = W1 + ((b * CC + c1) * (long)NN + y) * NN;
    float2 u[6], v[6];
#pragma unroll
    for (int r = 0; r < 6; ++r) { u[r] = row0[t + 64 * r]; v[r] = row1[t + 64 * r]; }
    bwd384t2<1>(u, v, t, tc, ts, wb, 1.0f);
    const float* cre0 = csm + (b * 2 * CC + c0) * (long)(NN * NN) + rowoff;
    const float* cim0 = cre0 + (long)CC * NN * NN;
    const float* cre1 = csm + (b * 2 * CC + c1) * (long)(NN * NN) + rowoff;
    const float* cim1 = cre1 + (long)CC * NN * NN;
#pragma unroll
    for (int k = 0; k < 6; ++k) {
      int x = t + 64 * k;
      float a0 = cre0[x], b0 = cim0[x];
      float a1 = cre1[x], b1 = cim1[x];
      acc[k].x += (a0 * u[k].x + b0 * u[k].y) + (a1 * v[k].x + b1 * v[k].y);
      acc[k].y += (a0 * u[k].y - b0 * u[k].x) + (a1 * v[k].y - b1 * v[k].x);
    }
  }
#pragma unroll
  for (int k = 0; k < 6; ++k) part[w][t + 64 * k] = acc[k];
  __syncthreads();
  float lamv = lamp[0];
  float oml = 1.0f - lamv;
  long pbase = b * (long)(NN * NN) + rowoff;
  for (int e = tid; e < NN; e += 256) {
    float Qx = (part[0][e].x + part[1][e].x + part[2][e].x + part[3][e].x) * (1.0f / NN);
    float Qy = (part[0][e].y + part[1][e].y + part[2][e].y + part[3][e].y) * (1.0f / NN);
    float2 yv = ybuf[pbase + e];
    float2 cz = czb[pbase + e];
    float xr = oml * (yv.x - Qx) + cz.x;
    float xi = oml * (yv.y - Qy) + cz.y;
    xr = fmaxf(xr, 0.f);
    xi = fmaxf(xi, 0.f);
    if (last) {
      outp[(b * 2 + 0) * (long)(NN * NN) + rowoff + e] = xr;
      outp[(b * 2 + 1) * (long)(NN * NN) + rowoff + e] = xi;
    } else {
      float2 xo = xbuf[pbase + e];
      xbuf[pbase + e] = make_float2(xr, xi);
      ybuf[pbase + e] = make_float2(xr + beta * (xr - xo.x), xi + beta * (xi - xo.y));
    }
  }
}

// ---------------- mask permutation precompute (one-time) -------------------
// maskPT[b][sx][sy] = mask[b][P(sy)][P(sx)], P(s) = (s>>6) + 6*brev6(s&63)
__global__ __launch_bounds__(256) void k_mpre(const int* __restrict__ mask,
                                              unsigned char* __restrict__ maskPT) {
  long i = (long)blockIdx.x * 256 + threadIdx.x;
  long b = i / (NN * NN);
  int rem = (int)(i % (NN * NN));
  int sx = rem / NN, sy = rem % NN;
  int fx = (sx >> 6) + 6 * (int)(__brev((unsigned)(sx & 63)) >> 26);
  int fy = (sy >> 6) + 6 * (int)(__brev((unsigned)(sy & 63)) >> 26);
  maskPT[i] = (unsigned char)mask[b * (long)(NN * NN) + (long)fy * NN + fx];
}

// ---------------- precompute: cz = (1-lam)*cst + lam*z ---------------------
__global__ __launch_bounds__(256) void k_preA(const float* __restrict__ x0,
                                              const int* __restrict__ mask,
                                              float2* __restrict__ T) {
  __shared__ float2 U[4][LNPAD], V[4][LNPAD];
  int tid = threadIdx.x;
  int line = tid >> 6, t = tid & 63;
  long gl0 = (long)blockIdx.x * 4;
#pragma unroll
  for (int k = 0; k < 6; ++k) {
    int e = tid + k * 256; int l = e / NN; int x = e % NN;
    long gl = gl0 + l;
    long b = gl / NN;
    int y = (int)(gl % NN);
    long pidx = (long)y * NN + x;
    float mv = (float)mask[b * (long)(NN * NN) + pidx];
    float br = x0[(b * 2 + 0) * (long)(NN * NN) + pidx] * mv;
    float bi = x0[(b * 2 + 1) * (long)(NN * NN) + pidx] * mv;
    U[l][LID(x)] = make_float2(br, bi);
  }
  __syncthreads();
  fft384<1>(U[line], V[line], t);
#pragma unroll
  for (int k = 0; k < 6; ++k) {
    int e = tid + k * 256; int l = e / NN; int x = e % NN;
    float2 u = U[l][LID(x)];
    T[(gl0 + l) * NN + x] = make_float2(u.x * (1.0f / NN), u.y * (1.0f / NN));
  }
}

__global__ __launch_bounds__(256) void k_preB(const float2* __restrict__ T,
                                              float2* __restrict__ r0) {
  __shared__ float2 tile[NN][17];
  __shared__ float2 U[4][LNPAD], V[4][LNPAD];
  int tid = threadIdx.x;
  int xt = blockIdx.x % (NN / 16);
  long b = blockIdx.x / (NN / 16);
  int x0c = xt * 16;
  long sbase = b * (long)(NN * NN);
#pragma unroll
  for (int k = 0; k < 24; ++k) {
    int e = tid + k * 256; int y = e >> 4; int c = e & 15;
    tile[y][c] = T[sbase + (long)y * NN + x0c + c];
  }
  __syncthreads();
  int line = tid >> 6, t = tid & 63;
  for (int g = 0; g < 4; ++g) {
#pragma unroll
    for (int k = 0; k < 6; ++k) {
      int e = tid + k * 256; int l = e / NN; int y = e % NN;
      U[l][LID(y)] = tile[y][4 * g + l];
    }
    __syncthreads();
    fft384<1>(U[line], V[line], t);
#pragma unroll
    for (int k = 0; k < 6; ++k) {
      int e = tid + k * 256; int l = e / NN; int y = e % NN;
      float2 u = U[l][LID(y)];
      tile[y][4 * g + l] = make_float2(u.x * (1.0f / NN), u.y * (1.0f / NN));
    }
    __syncthreads();
  }
#pragma unroll
  for (int k = 0; k < 24; ++k) {
    int e = tid + k * 256; int y = e >> 4; int c = e & 15;
    r0[sbase + (long)y * NN + x0c + c] = tile[y][c];
  }
}

__global__ __launch_bounds__(256) void k_preC(const float* __restrict__ csm,
                                              const float2* __restrict__ r0,
                                              const float* __restrict__ zk,
                                              const float* __restrict__ lamp,
                                              float2* __restrict__ czb) {
  long i = (long)blockIdx.x * 256 + threadIdx.x;
  long b = i / (NN * NN);
  long p = i % (NN * NN);
  float sr = 0.f, si = 0.f;
#pragma unroll
  for (int c = 0; c < CC; ++c) {
    sr += csm[(b * 2 * CC + c) * (long)(NN * NN) + p];
    si -= csm[((b * 2 + 1) * CC + c) * (long)(NN * NN) + p];
  }
  float2 r = r0[i];
  float cstx = sr * r.x - si * r.y;
  float csty = sr * r.y + si * r.x;
  float lamv = lamp[0];
  float oml = 1.0f - lamv;
  float zr = zk[(b * 2 + 0) * (long)(NN * NN) + p];
  float zi = zk[(b * 2 + 1) * (long)(NN * NN) + p];
  czb[i] = make_float2(oml * cstx + lamv * zr, oml * csty + lamv * zi);
}

extern "C" void kernel_launch(void* const* d_in, const int* in_sizes, int n_in,
                              void* d_out, int out_size, void* d_ws, size_t ws_size,
                              hipStream_t stream) {
  const float* zk  = (const float*)d_in[0];
  const float* x0  = (const float*)d_in[1];
  const float* csm = (const float*)d_in[2];
  const float* lam = (const float*)d_in[3];
  const int*   msk = (const int*)d_in[4];
  float* out = (float*)d_out;

  // ws layout (float2 units): W1 [B*C*N*N] | y | x | cz | maskPT(uchar)
  size_t img = (size_t)BB * NN * NN;
  float2* W1   = (float2*)d_ws;
  float2* ybuf = W1 + (size_t)BB * CC * NN * NN;
  float2* xbuf = ybuf + img;
  float2* czb  = xbuf + img;
  unsigned char* maskPT = (unsigned char*)(czb + img);
  float2* T  = W1;        // precompute scratch overlays W1
  float2* r0 = W1 + img;

  double tcur = 1.0;
  float betas[NITER];
  for (int i = 0; i < NITER; ++i) {
    double tn = (1.0 + sqrt(1.0 + 4.0 * tcur * tcur)) * 0.5;
    betas[i] = (float)((tcur - 1.0) / tn);
    tcur = tn;
  }

  k_mpre<<<(BB * NN * NN) / 256, 256, 0, stream>>>(msk, maskPT);
  k_preA<<<BB * NN / 4, 256, 0, stream>>>(x0, msk, T);
  k_preB<<<BB * (NN / 16), 256, 0, stream>>>(T, r0);
  k_preC<<<(BB * NN * NN) / 256, 256, 0, stream>>>(csm, r0, zk, lam, czb);
  // iteration 1 (y0 = 0): x1 = prox(cz)
  k_e<<<(BB * NN * NN) / 256, 256, 0, stream>>>(czb, xbuf, ybuf);
  // iterations 2..20: forward, mask round-trip, adjoint+update
  for (int i = 1; i < NITER; ++i) {
    k_p1<<<BB * CC * NN / 4, 256, 0, stream>>>(ybuf, csm, W1);
    k_p2<<<BB * CC * (NN / 8), 256, 0, stream>>>(W1, maskPT);
    k_p3<<<BB * NN, 256, 0, stream>>>(W1, csm, czb, lam, xbuf, ybuf, out,
                                      betas[i], (i == NITER - 1) ? 1 : 0);
  }
}

// Round 14
// 2062.132 us; speedup vs baseline: 1.3083x; 1.0430x over previous
//
#include <hip/hip_runtime.h>
#include <math.h>

// FISTA data-consistency with masked multi-coil 2D FFT operator.
// B=4, C=16, H=W=384.
// Register FFT: 384 = 6 (regs) x 64 (lanes); DIF leaves bit-reversed-permuted
// frequencies; mask is pre-permuted; DIT consumes permuted order (free).
// Twiddles: 32-entry register table (1 sincosf/kernel) via __shfl, PRE-SIGNED.
// Exchanges (R14 rebalance): h=1,2 DPP quad_perm (1 VALU op); h=4,8,16,32
// __shfl_xor (1 LDS-pipe op) — permlane_swap builtin costs ~5 VALU ops/float
// (2 copies + swap + 2 xor), and with only 2 stages on the LDS pipe that
// pipe has headroom; VALU is the critical pipe (75% busy at R13).
// Butterflies: fma/fold — s=hi?-1:1, tw'=(hi?cs:1, hi?sn:0);
// dif: v'=cmul(fma(s,v,o),tw'); dit: bt=cmul(v,tw'); v'=fma(s,bt,exch(bt)).
// zk folded out: cz=(1-lam)cst+lam*z; 1/N folded into wb chain.
// R3: don't fuse p3+p1. R4: XCD swizzle. R8: fp16 W1 FAILS (range).
// R9: inline-asm permlane broke; builtins only. R11: keep live ranges short.

#define NN 384
#define BB 4
#define CC 16
#define NITER 20
#define LNPAD 432   // old LDS path (precompute only)
#define PI_F 3.14159265358979323846f
#define TWOPI_F 6.28318530717958647692f

__device__ __forceinline__ int LID(int i) { return i + (i >> 3); }

__device__ __forceinline__ float2 cmulf(float2 a, float2 b) {
  return make_float2(a.x * b.x - a.y * b.y, a.x * b.y + a.y * b.x);
}

// ---------------- cross-lane exchange primitives ---------------------------
// xor-1 / xor-2 via DPP quad_perm (VALU). ctrl = p0|p1<<2|p2<<4|p3<<6.
template<int CTRL>
__device__ __forceinline__ float dppx(float v) {
  int s = __float_as_int(v);
  return __int_as_float(__builtin_amdgcn_update_dpp(s, s, CTRL, 0xF, 0xF, true));
}

template<int H>
__device__ __forceinline__ float2 exch(float2 v) {
  if constexpr (H == 1) {
    return make_float2(dppx<0xB1>(v.x), dppx<0xB1>(v.y));   // [1,0,3,2]
  } else if constexpr (H == 2) {
    return make_float2(dppx<0x4E>(v.x), dppx<0x4E>(v.y));   // [2,3,0,1]
  } else {
    return make_float2(__shfl_xor(v.x, H), __shfl_xor(v.y, H));
  }
}

template<int DIR>
__device__ __forceinline__ void dft4(float2* v) {
  float ax = v[0].x + v[2].x, ay = v[0].y + v[2].y;
  float bx = v[0].x - v[2].x, by = v[0].y - v[2].y;
  float cx = v[1].x + v[3].x, cy = v[1].y + v[3].y;
  float dx = v[1].x - v[3].x, dy = v[1].y - v[3].y;
  float dix, diy;
  if (DIR < 0) { dix = dy; diy = -dx; }
  else         { dix = -dy; diy = dx; }
  v[0] = make_float2(ax + cx, ay + cy);
  v[2] = make_float2(ax - cx, ay - cy);
  v[1] = make_float2(bx + dix, by + diy);
  v[3] = make_float2(bx - dix, by - diy);
}

// DFT-3: X1 = m + i*s*S3*d, X2 = m - i*s*S3*d; m = a - u/2, u=b+c, d=b-c.
template<int SIGN>
__device__ __forceinline__ void dft3(float2 a, float2 b, float2 c,
                                     float2& X0, float2& X1, float2& X2) {
  const float S3 = 0.86602540378443864676f;
  float ux = b.x + c.x, uy = b.y + c.y;
  float dx = b.x - c.x, dy = b.y - c.y;
  float mx = a.x - 0.5f * ux, my = a.y - 0.5f * uy;
  float ex = S3 * dx, ey = S3 * dy;
  X0 = make_float2(a.x + ux, a.y + uy);
  if (SIGN < 0) {
    X1 = make_float2(mx + ey, my - ex);
    X2 = make_float2(mx - ey, my + ex);
  } else {
    X1 = make_float2(mx - ey, my + ex);
    X2 = make_float2(mx + ey, my - ex);
  }
}

// Fast DFT-6 = two DFT-3 + trivial W6 twiddles. Verified on impulses.
template<int SIGN>
__device__ __forceinline__ void dft6(float2* v) {
  const float S3 = 0.86602540378443864676f;
  float2 E0, E1, E2, O0, O1, O2;
  dft3<SIGN>(v[0], v[2], v[4], E0, E1, E2);
  dft3<SIGN>(v[1], v[3], v[5], O0, O1, O2);
  const float ss = (SIGN < 0) ? -S3 : S3;
  float2 T1 = cmulf(O1, make_float2(0.5f, ss));
  float2 T2 = cmulf(O2, make_float2(-0.5f, ss));
  v[0] = make_float2(E0.x + O0.x, E0.y + O0.y);
  v[1] = make_float2(E1.x + T1.x, E1.y + T1.y);
  v[2] = make_float2(E2.x + T2.x, E2.y + T2.y);
  v[3] = make_float2(E0.x - O0.x, E0.y - O0.y);
  v[4] = make_float2(E1.x - T1.x, E1.y - T1.y);
  v[5] = make_float2(E2.x - T2.x, E2.y - T2.y);
}

// ---------------- register FFT machinery (iteration path) ------------------
// fma/fold butterflies. Per stage (lane-hoisted): s = hi?-1:1,
// (csl,snl) = hi?(cs,sn):(1,0). Lo-lane cmul by (1,0) is exact.

// dif: o = exch(v); d = fma(s,v,o); v' = cmul(d, tw')
template<int H>
__device__ __forceinline__ void dif_step1(float2 v[6], float s, float csl, float snl) {
#pragma unroll
  for (int r = 0; r < 6; ++r) {
    float2 o = exch<H>(v[r]);
    float dx = fmaf(s, v[r].x, o.x);
    float dy = fmaf(s, v[r].y, o.y);
    v[r] = make_float2(dx * csl - dy * snl, dx * snl + dy * csl);
  }
}
template<int H>
__device__ __forceinline__ void dif_step1_notw(float2 v[6], float s) {
#pragma unroll
  for (int r = 0; r < 6; ++r) {
    float2 o = exch<H>(v[r]);
    v[r] = make_float2(fmaf(s, v[r].x, o.x), fmaf(s, v[r].y, o.y));
  }
}
template<int H>
__device__ __forceinline__ void dif_step2(float2 u[6], float2 v[6],
                                          float s, float csl, float snl) {
#pragma unroll
  for (int r = 0; r < 6; ++r) {
    float2 ou = exch<H>(u[r]);
    float2 ov = exch<H>(v[r]);
    float dux = fmaf(s, u[r].x, ou.x), duy = fmaf(s, u[r].y, ou.y);
    float dvx = fmaf(s, v[r].x, ov.x), dvy = fmaf(s, v[r].y, ov.y);
    u[r] = make_float2(dux * csl - duy * snl, dux * snl + duy * csl);
    v[r] = make_float2(dvx * csl - dvy * snl, dvx * snl + dvy * csl);
  }
}
template<int H>
__device__ __forceinline__ void dif_step2_notw(float2 u[6], float2 v[6], float s) {
#pragma unroll
  for (int r = 0; r < 6; ++r) {
    float2 ou = exch<H>(u[r]);
    float2 ov = exch<H>(v[r]);
    u[r] = make_float2(fmaf(s, u[r].x, ou.x), fmaf(s, u[r].y, ou.y));
    v[r] = make_float2(fmaf(s, v[r].x, ov.x), fmaf(s, v[r].y, ov.y));
  }
}

// dit: bt = cmul(v, tw'); v' = fma(s, bt, exch(bt))
template<int H>
__device__ __forceinline__ void dit_step2(float2 u[6], float2 v[6],
                                          float s, float csl, float snl) {
#pragma unroll
  for (int r = 0; r < 6; ++r) {
    float2 bu = make_float2(u[r].x * csl - u[r].y * snl, u[r].x * snl + u[r].y * csl);
    float2 bv = make_float2(v[r].x * csl - v[r].y * snl, v[r].x * snl + v[r].y * csl);
    float2 ou = exch<H>(bu);
    float2 ov = exch<H>(bv);
    u[r] = make_float2(fmaf(s, bu.x, ou.x), fmaf(s, bu.y, ou.y));
    v[r] = make_float2(fmaf(s, bv.x, ov.x), fmaf(s, bv.y, ov.y));
  }
}
template<int H>
__device__ __forceinline__ void dit_step2_notw(float2 u[6], float2 v[6], float s) {
#pragma unroll
  for (int r = 0; r < 6; ++r) {
    float2 ou = exch<H>(u[r]);
    float2 ov = exch<H>(v[r]);
    u[r] = make_float2(fmaf(s, u[r].x, ou.x), fmaf(s, u[r].y, ou.y));
    v[r] = make_float2(fmaf(s, v[r].x, ov.x), fmaf(s, v[r].y, ov.y));
  }
}

// radix-2 DIF FFT-64, TWO columns interleaved. tss pre-signed.
template<int SIGN>
__device__ __forceinline__ void dif64t2(float2 u[6], float2 v[6], int t,
                                        float tc, float tss) {
  { int j = t & 31; bool hi = (t & 32) != 0;                  // h=32
    float cs = __shfl(tc, j), sn = __shfl(tss, j);
    float s = hi ? -1.f : 1.f, csl = hi ? cs : 1.f, snl = hi ? sn : 0.f;
    dif_step2<32>(u, v, s, csl, snl); }
  { int j = (t & 15) << 1; bool hi = (t & 16) != 0;           // h=16
    float cs = __shfl(tc, j), sn = __shfl(tss, j);
    float s = hi ? -1.f : 1.f, csl = hi ? cs : 1.f, snl = hi ? sn : 0.f;
    dif_step2<16>(u, v, s, csl, snl); }
  { int j = (t & 7) << 2; bool hi = (t & 8) != 0;             // h=8
    float cs = __shfl(tc, j), sn = __shfl(tss, j);
    float s = hi ? -1.f : 1.f, csl = hi ? cs : 1.f, snl = hi ? sn : 0.f;
    dif_step2<8>(u, v, s, csl, snl); }
  { int j = (t & 3) << 3; bool hi = (t & 4) != 0;             // h=4
    float cs = __shfl(tc, j), sn = __shfl(tss, j);
    float s = hi ? -1.f : 1.f, csl = hi ? cs : 1.f, snl = hi ? sn : 0.f;
    dif_step2<4>(u, v, s, csl, snl); }
  { bool hi = (t & 2) != 0, iq = (t & 1) != 0;                // h=2 (DPP)
    float s = hi ? -1.f : 1.f;
    float c2 = (hi && iq) ? 0.f : 1.f;
    float s2 = (hi && iq) ? (float)SIGN : 0.f;
    dif_step2<2>(u, v, s, c2, s2); }
  { bool hi = (t & 1) != 0;                                   // h=1 (DPP, tw=1)
    float s = hi ? -1.f : 1.f;
    dif_step2_notw<1>(u, v, s); }
}

// single-column variant (p1)
template<int SIGN>
__device__ __forceinline__ void dif64t(float2 v[6], int t, float tc, float tss) {
  { int j = t & 31; bool hi = (t & 32) != 0;
    float cs = __shfl(tc, j), sn = __shfl(tss, j);
    float s = hi ? -1.f : 1.f, csl = hi ? cs : 1.f, snl = hi ? sn : 0.f;
    dif_step1<32>(v, s, csl, snl); }
  { int j = (t & 15) << 1; bool hi = (t & 16) != 0;
    float cs = __shfl(tc, j), sn = __shfl(tss, j);
    float s = hi ? -1.f : 1.f, csl = hi ? cs : 1.f, snl = hi ? sn : 0.f;
    dif_step1<16>(v, s, csl, snl); }
  { int j = (t & 7) << 2; bool hi = (t & 8) != 0;
    float cs = __shfl(tc, j), sn = __shfl(tss, j);
    float s = hi ? -1.f : 1.f, csl = hi ? cs : 1.f, snl = hi ? sn : 0.f;
    dif_step1<8>(v, s, csl, snl); }
  { int j = (t & 3) << 3; bool hi = (t & 4) != 0;
    float cs = __shfl(tc, j), sn = __shfl(tss, j);
    float s = hi ? -1.f : 1.f, csl = hi ? cs : 1.f, snl = hi ? sn : 0.f;
    dif_step1<4>(v, s, csl, snl); }
  { bool hi = (t & 2) != 0, iq = (t & 1) != 0;
    float s = hi ? -1.f : 1.f;
    float c2 = (hi && iq) ? 0.f : 1.f;
    float s2 = (hi && iq) ? (float)SIGN : 0.f;
    dif_step1<2>(v, s, c2, s2); }
  { bool hi = (t & 1) != 0;
    float s = hi ? -1.f : 1.f;
    dif_step1_notw<1>(v, s); }
}

// radix-2 DIT FFT-64, TWO columns interleaved. tss pre-signed.
template<int SIGN>
__device__ __forceinline__ void dit64t2(float2 u[6], float2 v[6], int t,
                                        float tc, float tss) {
  { bool hi = (t & 1) != 0;                                   // h=1 (DPP, tw=1)
    float s = hi ? -1.f : 1.f;
    dit_step2_notw<1>(u, v, s); }
  { bool hi = (t & 2) != 0, iq = (t & 1) != 0;                // h=2 (DPP)
    float s = hi ? -1.f : 1.f;
    float c2 = (hi && iq) ? 0.f : 1.f;
    float s2 = (hi && iq) ? (float)SIGN : 0.f;
    dit_step2<2>(u, v, s, c2, s2); }
  { int j = (t & 3) << 3; bool hi = (t & 4) != 0;             // h=4
    float cs = __shfl(tc, j), sn = __shfl(tss, j);
    float s = hi ? -1.f : 1.f, csl = hi ? cs : 1.f, snl = hi ? sn : 0.f;
    dit_step2<4>(u, v, s, csl, snl); }
  { int j = (t & 7) << 2; bool hi = (t & 8) != 0;             // h=8
    float cs = __shfl(tc, j), sn = __shfl(tss, j);
    float s = hi ? -1.f : 1.f, csl = hi ? cs : 1.f, snl = hi ? sn : 0.f;
    dit_step2<8>(u, v, s, csl, snl); }
  { int j = (t & 15) << 1; bool hi = (t & 16) != 0;           // h=16
    float cs = __shfl(tc, j), sn = __shfl(tss, j);
    float s = hi ? -1.f : 1.f, csl = hi ? cs : 1.f, snl = hi ? sn : 0.f;
    dit_step2<16>(u, v, s, csl, snl); }
  { int j = t & 31; bool hi = (t & 32) != 0;                  // h=32
    float cs = __shfl(tc, j), sn = __shfl(tss, j);
    float s = hi ? -1.f : 1.f, csl = hi ? cs : 1.f, snl = hi ? sn : 0.f;
    dit_step2<32>(u, v, s, csl, snl); }
}

// FWD single: natural in -> permuted out. w[r-1] = exp(SIGN*2pi*i*r*t/384).
template<int SIGN>
__device__ __forceinline__ void fwd384t(float2 v[6], int t, float tc, float tss,
                                        const float2 w[5]) {
  dft6<SIGN>(v);
#pragma unroll
  for (int r = 1; r < 6; ++r) v[r] = cmulf(v[r], w[r - 1]);
  dif64t<SIGN>(v, t, tc, tss);
}

// FWD dual
template<int SIGN>
__device__ __forceinline__ void fwd384t2(float2 u[6], float2 v[6], int t,
                                         float tc, float tss, const float2 w[5]) {
  dft6<SIGN>(u);
  dft6<SIGN>(v);
#pragma unroll
  for (int r = 1; r < 6; ++r) { u[r] = cmulf(u[r], w[r - 1]); v[r] = cmulf(v[r], w[r - 1]); }
  dif64t2<SIGN>(u, v, t, tc, tss);
}

// BWD dual: permuted in -> natural out. w may carry an extra uniform scale;
// sc0 applies the same scale to the r=0 (untwiddled) term.
template<int SIGN>
__device__ __forceinline__ void bwd384t2(float2 u[6], float2 v[6], int t,
                                         float tc, float tss, const float2 w[5],
                                         float sc0) {
  dit64t2<SIGN>(u, v, t, tc, tss);
  u[0].x *= sc0; u[0].y *= sc0;
  v[0].x *= sc0; v[0].y *= sc0;
#pragma unroll
  for (int r = 1; r < 6; ++r) { u[r] = cmulf(u[r], w[r - 1]); v[r] = cmulf(v[r], w[r - 1]); }
  dft6<SIGN>(u);
  dft6<SIGN>(v);
}

// ---------------- old LDS fft384 (precompute kernels only) -----------------
template<int R, int NS, int DIR>
__device__ __forceinline__ void fft_stage(const float2* S, float2* D, int t) {
  constexpr int NR = NN / R;
#pragma unroll
  for (int rep = 0; rep < (NR + 63) / 64; ++rep) {
    int j = t + rep * 64;
    if (j < NR) {
      float2 v[R];
#pragma unroll
      for (int r = 0; r < R; ++r) v[r] = S[LID(j + r * NR)];
      if constexpr (NS > 1) {
        float ang = (float)DIR * (TWOPI_F / (float)(NS * R)) * (float)(j % NS);
        float sv, cv;
        __sincosf(ang, &sv, &cv);
        float2 w = make_float2(cv, sv);
        float2 wr = w;
#pragma unroll
        for (int r = 1; r < R; ++r) { v[r] = cmulf(v[r], wr); wr = cmulf(wr, w); }
      }
      if constexpr (R == 4) dft4<DIR>(v); else dft6<DIR>(v);
      int base = (j / NS) * (NS * R) + (j % NS);
#pragma unroll
      for (int r = 0; r < R; ++r) D[LID(base + r * NS)] = v[r];
    }
  }
}

template<int DIR>
__device__ __forceinline__ void fft384(float2* A, float2* Bf, int t) {
  fft_stage<4, 1,  DIR>(A,  Bf, t); __syncthreads();
  fft_stage<4, 4,  DIR>(Bf, A,  t); __syncthreads();
  fft_stage<4, 16, DIR>(A,  Bf, t); __syncthreads();
  fft_stage<6, 64, DIR>(Bf, A,  t); __syncthreads();
}

// ---------------- E: iteration 1 (y0 = 0 -> xn = cz), elementwise ----------
__global__ __launch_bounds__(256) void k_e(const float2* __restrict__ czb,
                                           float2* __restrict__ xbuf,
                                           float2* __restrict__ ybuf) {
  long i = (long)blockIdx.x * 256 + threadIdx.x;
  float2 cz = czb[i];
  float2 x = make_float2(fmaxf(cz.x, 0.f), fmaxf(cz.y, 0.f));
  xbuf[i] = x;
  ybuf[i] = x;   // t1 = 1 -> y1 = x1
}

// ---------------- P1: row FFT of coil*y -> W1 (permuted-x storage) ---------
// grid B*C*384/4, 256 thr; one wave per row; no LDS, no barriers.
__global__ __launch_bounds__(256) void k_p1(const float2* __restrict__ ybuf,
                                            const float* __restrict__ csm,
                                            float2* __restrict__ W1) {
  int t = threadIdx.x & 63;
  int w = threadIdx.x >> 6;
  long gl = (long)blockIdx.x * 4 + w;       // (b*C + c)*384 + y
  int y = (int)(gl % NN);
  long bc = gl / NN;
  long b = bc >> 4, c = bc & 15;
  long rowoff = (long)y * NN;
  float tc, ts; __sincosf((float)(t & 31) * (PI_F / 32.0f), &ts, &tc);
  float tsf = -ts;                           // fwd (SIGN=-1) pre-signed
  float2 w0; __sincosf(-(float)t * (TWOPI_F / 384.0f), &w0.y, &w0.x);
  float2 wf[5];
  wf[0] = w0;
#pragma unroll
  for (int r = 1; r < 5; ++r) wf[r] = cmulf(wf[r - 1], w0);
  const float2* yrow = ybuf + b * (long)(NN * NN) + rowoff;
  const float* crow_re = csm + (b * 2 * CC + c) * (long)(NN * NN) + rowoff;
  const float* crow_im = crow_re + (long)CC * NN * NN;
  float2 v[6];
#pragma unroll
  for (int k = 0; k < 6; ++k) {
    int x = t + 64 * k;
    float2 yv = yrow[x];
    float cre = crow_re[x], cim = crow_im[x];
    v[k] = make_float2(yv.x * cre - yv.y * cim, yv.x * cim + yv.y * cre);
  }
  fwd384t<-1>(v, t, tc, tsf, wf);
  float2* orow = W1 + gl * NN;
#pragma unroll
  for (int r = 0; r < 6; ++r) orow[t + 64 * r] = v[r];
}

// ---------------- P2: col FFT -> mask -> col IFFT, in-place on W1 ----------
// grid B*C*(N/8)=3072 blocks, 256 thr. 8-col planar tile, pad 392.
// float4 fill/drain; each wave runs cols {2w, 2w+1} interleaved through one
// FFT body. XCD-chunked swizzle (R6). 1/N folded into wb + sc0.
#define P2PAD 392
__global__ __launch_bounds__(256) void k_p2(float2* __restrict__ W1,
                                            const unsigned char* __restrict__ maskPT) {
  __shared__ float ldsR[8][P2PAD];
  __shared__ float ldsI[8][P2PAD];
  int tid = threadIdx.x;
  const int nwg = BB * CC * (NN / 8);            // 3072, divisible by 8
  int l = ((int)blockIdx.x & 7) * (nwg >> 3) + ((int)blockIdx.x >> 3);
  int xt = l % (NN / 8);
  long bc = l / (NN / 8);
  long b = bc >> 4;
  int s0 = xt * 8;
  long sbase = bc * (long)(NN * NN);
  int w = tid >> 6, t = tid & 63;
  // twiddle setup: table (pre-signed per direction) + outer chains
  float tc, ts; __sincosf((float)(t & 31) * (PI_F / 32.0f), &ts, &tc);
  float tsf = -ts;
  float2 w0; __sincosf(-(float)t * (TWOPI_F / 384.0f), &w0.y, &w0.x);
  float2 wf[5], wb[5];
  wf[0] = w0;
#pragma unroll
  for (int r = 1; r < 5; ++r) wf[r] = cmulf(wf[r - 1], w0);
  const float inv = 1.0f / NN;
#pragma unroll
  for (int r = 0; r < 5; ++r) wb[r] = make_float2(wf[r].x * inv, -wf[r].y * inv);
  // fill: float4 (2 complex) per op; 6 ops/thread
  const float4* W1v = (const float4*)W1;
  long f4base = (sbase >> 1) + (s0 >> 1);
#pragma unroll
  for (int k = 0; k < 6; ++k) {
    int e = tid + k * 256; int y = e >> 2; int q = e & 3;
    float4 val = W1v[f4base + (long)y * (NN / 2) + q];
    ldsR[2 * q][y] = val.x; ldsI[2 * q][y] = val.y;
    ldsR[2 * q + 1][y] = val.z; ldsI[2 * q + 1][y] = val.w;
  }
  __syncthreads();
  const unsigned char* mb = maskPT + b * (long)(NN * NN);
  {
    int c0 = 2 * w, c1 = 2 * w + 1;
    float2 u[6], v[6];
#pragma unroll
    for (int k = 0; k < 6; ++k) {
      u[k] = make_float2(ldsR[c0][t + 64 * k], ldsI[c0][t + 64 * k]);
      v[k] = make_float2(ldsR[c1][t + 64 * k], ldsI[c1][t + 64 * k]);
    }
    fwd384t2<-1>(u, v, t, tc, tsf, wf);
    const unsigned char* m0 = mb + (long)(s0 + c0) * NN;
    const unsigned char* m1 = mb + (long)(s0 + c1) * NN;
#pragma unroll
    for (int r = 0; r < 6; ++r) {
      float mv0 = (float)m0[t + 64 * r];
      float mv1 = (float)m1[t + 64 * r];
      u[r].x *= mv0; u[r].y *= mv0;
      v[r].x *= mv1; v[r].y *= mv1;
    }
    bwd384t2<1>(u, v, t, tc, ts, wb, inv);
#pragma unroll
    for (int k = 0; k < 6; ++k) {
      ldsR[c0][t + 64 * k] = u[k].x;
      ldsI[c0][t + 64 * k] = u[k].y;
      ldsR[c1][t + 64 * k] = v[k].x;
      ldsI[c1][t + 64 * k] = v[k].y;
    }
  }
  __syncthreads();
  float4* W1o = (float4*)W1;
#pragma unroll
  for (int k = 0; k < 6; ++k) {
    int e = tid + k * 256; int y = e >> 2; int q = e & 3;
    float4 val;
    val.x = ldsR[2 * q][y]; val.y = ldsI[2 * q][y];
    val.z = ldsR[2 * q + 1][y]; val.w = ldsI[2 * q + 1][y];
    W1o[f4base + (long)y * (NN / 2) + q] = val;
  }
}

// ---------------- P3: row IFFT + conj(coil) reduce + FISTA update ----------
// grid B*384 blocks, 256 thr; wave w handles coils 4w..4w+3 (2 at a time);
// LDS reduce. Update: x = prox((1-lam)(y - Q) + cz); zk not touched.
// last!=0: write planar output instead of x/y (final iteration).
__global__ __launch_bounds__(256) void k_p3(const float2* __restrict__ W1,
                                            const float* __restrict__ csm,
                                            const float2* __restrict__ czb,
                                            const float* __restrict__ lamp,
                                            float2* __restrict__ xbuf,
                                            float2* __restrict__ ybuf,
                                            float* __restrict__ outp,
                                            float beta, int last) {
  __shared__ float2 part[4][NN];
  int tid = threadIdx.x;
  int w = tid >> 6, t = tid & 63;
  long gl = blockIdx.x;            // b*384 + y
  long b = gl / NN;
  int y = (int)(gl % NN);
  long rowoff = (long)y * NN;
  float tc, ts; __sincosf((float)(t & 31) * (PI_F / 32.0f), &ts, &tc);
  float2 w0; __sincosf((float)t * (TWOPI_F / 384.0f), &w0.y, &w0.x);
  float2 wb[5];
  wb[0] = w0;
#pragma unroll
  for (int r = 1; r < 5; ++r) wb[r] = cmulf(wb[r - 1], w0);
  float2 acc[6];
#pragma unroll
  for (int k = 0; k < 6; ++k) acc[k] = make_float2(0.f, 0.f);
#pragma unroll
  for (int ci = 0; ci < 4; ci += 2) {
    int c0 = w * 4 + ci, c1 = c0 + 1;
    const float2* row0 = W1 + ((b * CC + c0) * (long)NN + y) * NN;
    const float2* row1 = W1 + ((b * CC + c1) * (long)NN + y) * NN;
    float2 u[6], v[6];
#pragma unroll
    for (int r = 0; r < 6; ++r) { u[r] = row0[t + 64 * r]; v[r] = row1[t + 64 * r]; }
    bwd384t2<1>(u, v, t, tc, ts, wb, 1.0f);
    const float* cre0 = csm + (b * 2 * CC + c0) * (long)(NN * NN) + rowoff;
    const float* cim0 = cre0 + (long)CC * NN * NN;
    const float* cre1 = csm + (b * 2 * CC + c1) * (long)(NN * NN) + rowoff;
    const float* cim1 = cre1 + (long)CC * NN * NN;
#pragma unroll
    for (int k = 0; k < 6; ++k) {
      int x = t + 64 * k;
      float a0 = cre0[x], b0 = cim0[x];
      float a1 = cre1[x], b1 = cim1[x];
      acc[k].x += (a0 * u[k].x + b0 * u[k].y) + (a1 * v[k].x + b1 * v[k].y);
      acc[k].y += (a0 * u[k].y - b0 * u[k].x) + (a1 * v[k].y - b1 * v[k].x);
    }
  }
#pragma unroll
  for (int k = 0; k < 6; ++k) part[w][t + 64 * k] = acc[k];
  __syncthreads();
  float lamv = lamp[0];
  float oml = 1.0f - lamv;
  long pbase = b * (long)(NN * NN) + rowoff;
  for (int e = tid; e < NN; e += 256) {
    float Qx = (part[0][e].x + part[1][e].x + part[2][e].x + part[3][e].x) * (1.0f / NN);
    float Qy = (part[0][e].y + part[1][e].y + part[2][e].y + part[3][e].y) * (1.0f / NN);
    float2 yv = ybuf[pbase + e];
    float2 cz = czb[pbase + e];
    float xr = oml * (yv.x - Qx) + cz.x;
    float xi = oml * (yv.y - Qy) + cz.y;
    xr = fmaxf(xr, 0.f);
    xi = fmaxf(xi, 0.f);
    if (last) {
      outp[(b * 2 + 0) * (long)(NN * NN) + rowoff + e] = xr;
      outp[(b * 2 + 1) * (long)(NN * NN) + rowoff + e] = xi;
    } else {
      float2 xo = xbuf[pbase + e];
      xbuf[pbase + e] = make_float2(xr, xi);
      ybuf[pbase + e] = make_float2(xr + beta * (xr - xo.x), xi + beta * (xi - xo.y));
    }
  }
}

// ---------------- mask permutation precompute (one-time) -------------------
// maskPT[b][sx][sy] = mask[b][P(sy)][P(sx)], P(s) = (s>>6) + 6*brev6(s&63)
__global__ __launch_bounds__(256) void k_mpre(const int* __restrict__ mask,
                                              unsigned char* __restrict__ maskPT) {
  long i = (long)blockIdx.x * 256 + threadIdx.x;
  long b = i / (NN * NN);
  int rem = (int)(i % (NN * NN));
  int sx = rem / NN, sy = rem % NN;
  int fx = (sx >> 6) + 6 * (int)(__brev((unsigned)(sx & 63)) >> 26);
  int fy = (sy >> 6) + 6 * (int)(__brev((unsigned)(sy & 63)) >> 26);
  maskPT[i] = (unsigned char)mask[b * (long)(NN * NN) + (long)fy * NN + fx];
}

// ---------------- precompute: cz = (1-lam)*cst + lam*z ---------------------
__global__ __launch_bounds__(256) void k_preA(const float* __restrict__ x0,
                                              const int* __restrict__ mask,
                                              float2* __restrict__ T) {
  __shared__ float2 U[4][LNPAD], V[4][LNPAD];
  int tid = threadIdx.x;
  int line = tid >> 6, t = tid & 63;
  long gl0 = (long)blockIdx.x * 4;
#pragma unroll
  for (int k = 0; k < 6; ++k) {
    int e = tid + k * 256; int l = e / NN; int x = e % NN;
    long gl = gl0 + l;
    long b = gl / NN;
    int y = (int)(gl % NN);
    long pidx = (long)y * NN + x;
    float mv = (float)mask[b * (long)(NN * NN) + pidx];
    float br = x0[(b * 2 + 0) * (long)(NN * NN) + pidx] * mv;
    float bi = x0[(b * 2 + 1) * (long)(NN * NN) + pidx] * mv;
    U[l][LID(x)] = make_float2(br, bi);
  }
  __syncthreads();
  fft384<1>(U[line], V[line], t);
#pragma unroll
  for (int k = 0; k < 6; ++k) {
    int e = tid + k * 256; int l = e / NN; int x = e % NN;
    float2 u = U[l][LID(x)];
    T[(gl0 + l) * NN + x] = make_float2(u.x * (1.0f / NN), u.y * (1.0f / NN));
  }
}

__global__ __launch_bounds__(256) void k_preB(const float2* __restrict__ T,
                                              float2* __restrict__ r0) {
  __shared__ float2 tile[NN][17];
  __shared__ float2 U[4][LNPAD], V[4][LNPAD];
  int tid = threadIdx.x;
  int xt = blockIdx.x % (NN / 16);
  long b = blockIdx.x / (NN / 16);
  int x0c = xt * 16;
  long sbase = b * (long)(NN * NN);
#pragma unroll
  for (int k = 0; k < 24; ++k) {
    int e = tid + k * 256; int y = e >> 4; int c = e & 15;
    tile[y][c] = T[sbase + (long)y * NN + x0c + c];
  }
  __syncthreads();
  int line = tid >> 6, t = tid & 63;
  for (int g = 0; g < 4; ++g) {
#pragma unroll
    for (int k = 0; k < 6; ++k) {
      int e = tid + k * 256; int l = e / NN; int y = e % NN;
      U[l][LID(y)] = tile[y][4 * g + l];
    }
    __syncthreads();
    fft384<1>(U[line], V[line], t);
#pragma unroll
    for (int k = 0; k < 6; ++k) {
      int e = tid + k * 256; int l = e / NN; int y = e % NN;
      float2 u = U[l][LID(y)];
      tile[y][4 * g + l] = make_float2(u.x * (1.0f / NN), u.y * (1.0f / NN));
    }
    __syncthreads();
  }
#pragma unroll
  for (int k = 0; k < 24; ++k) {
    int e = tid + k * 256; int y = e >> 4; int c = e & 15;
    r0[sbase + (long)y * NN + x0c + c] = tile[y][c];
  }
}

__global__ __launch_bounds__(256) void k_preC(const float* __restrict__ csm,
                                              const float2* __restrict__ r0,
                                              const float* __restrict__ zk,
                                              const float* __restrict__ lamp,
                                              float2* __restrict__ czb) {
  long i = (long)blockIdx.x * 256 + threadIdx.x;
  long b = i / (NN * NN);
  long p = i % (NN * NN);
  float sr = 0.f, si = 0.f;
#pragma unroll
  for (int c = 0; c < CC; ++c) {
    sr += csm[(b * 2 * CC + c) * (long)(NN * NN) + p];
    si -= csm[((b * 2 + 1) * CC + c) * (long)(NN * NN) + p];
  }
  float2 r = r0[i];
  float cstx = sr * r.x - si * r.y;
  float csty = sr * r.y + si * r.x;
  float lamv = lamp[0];
  float oml = 1.0f - lamv;
  float zr = zk[(b * 2 + 0) * (long)(NN * NN) + p];
  float zi = zk[(b * 2 + 1) * (long)(NN * NN) + p];
  czb[i] = make_float2(oml * cstx + lamv * zr, oml * csty + lamv * zi);
}

extern "C" void kernel_launch(void* const* d_in, const int* in_sizes, int n_in,
                              void* d_out, int out_size, void* d_ws, size_t ws_size,
                              hipStream_t stream) {
  const float* zk  = (const float*)d_in[0];
  const float* x0  = (const float*)d_in[1];
  const float* csm = (const float*)d_in[2];
  const float* lam = (const float*)d_in[3];
  const int*   msk = (const int*)d_in[4];
  float* out = (float*)d_out;

  // ws layout (float2 units): W1 [B*C*N*N] | y | x | cz | maskPT(uchar)
  size_t img = (size_t)BB * NN * NN;
  float2* W1   = (float2*)d_ws;
  float2* ybuf = W1 + (size_t)BB * CC * NN * NN;
  float2* xbuf = ybuf + img;
  float2* czb  = xbuf + img;
  unsigned char* maskPT = (unsigned char*)(czb + img);
  float2* T  = W1;        // precompute scratch overlays W1
  float2* r0 = W1 + img;

  double tcur = 1.0;
  float betas[NITER];
  for (int i = 0; i < NITER; ++i) {
    double tn = (1.0 + sqrt(1.0 + 4.0 * tcur * tcur)) * 0.5;
    betas[i] = (float)((tcur - 1.0) / tn);
    tcur = tn;
  }

  k_mpre<<<(BB * NN * NN) / 256, 256, 0, stream>>>(msk, maskPT);
  k_preA<<<BB * NN / 4, 256, 0, stream>>>(x0, msk, T);
  k_preB<<<BB * (NN / 16), 256, 0, stream>>>(T, r0);
  k_preC<<<(BB * NN * NN) / 256, 256, 0, stream>>>(csm, r0, zk, lam, czb);
  // iteration 1 (y0 = 0): x1 = prox(cz)
  k_e<<<(BB * NN * NN) / 256, 256, 0, stream>>>(czb, xbuf, ybuf);
  // iterations 2..20: forward, mask round-trip, adjoint+update
  for (int i = 1; i < NITER; ++i) {
    k_p1<<<BB * CC * NN / 4, 256, 0, stream>>>(ybuf, csm, W1);
    k_p2<<<BB * CC * (NN / 8), 256, 0, stream>>>(W1, maskPT);
    k_p3<<<BB * NN, 256, 0, stream>>>(W1, csm, czb, lam, xbuf, ybuf, out,
                                      betas[i], (i == NITER - 1) ? 1 : 0);
  }
}